// Round 1
// baseline (1247.471 us; speedup 1.0000x reference)
//
#include <hip/hip_runtime.h>
#include <hip/hip_bf16.h>
#include <cstdint>
#include <cstddef>

#define NGRAPH 64
#define NPG0   1024
#define NNODE  65536     // NGRAPH*NPG0
#define NEDGE  524288
#define EPG    8192      // NEDGE/NGRAPH
#define DIM    128

// ---------------- gather x = emb[node_idx] ----------------
__global__ __launch_bounds__(256) void k_gather(const float* __restrict__ emb,
    const int* __restrict__ nid, float* __restrict__ x)
{
  int tid = blockIdx.x * 256 + threadIdx.x;
  int i = tid >> 5, lane = tid & 31;
  int row = nid[i];
  ((float4*)(x + (size_t)i * DIM))[lane] =
      ((const float4*)(emb + (size_t)row * DIM))[lane];
}

// ---------------- copy edges to mutable ws ----------------
__global__ __launch_bounds__(256) void k_edges_init(const int* __restrict__ ei,
    int* __restrict__ src, int* __restrict__ dst)
{
  int e = blockIdx.x * 256 + threadIdx.x;
  src[e] = ei[e];
  dst[e] = ei[NEDGE + e];
}

// ---------------- 1/||pool_w|| ----------------
__global__ __launch_bounds__(64) void k_norm(const float* __restrict__ pw,
    float* __restrict__ inv_norm)
{
  int t = threadIdx.x;
  float a = pw[t], b = pw[t + 64];
  float v = a * a + b * b;
  for (int off = 32; off; off >>= 1) v += __shfl_xor(v, off);
  if (t == 0) *inv_norm = 1.0f / sqrtf(v);
}

// ---------------- transpose the 4 128x128 weight mats once ----------------
__global__ __launch_bounds__(256) void k_transpose4(
    const float* __restrict__ a, const float* __restrict__ b,
    const float* __restrict__ c, const float* __restrict__ d,
    float* __restrict__ oa, float* __restrict__ ob,
    float* __restrict__ oc, float* __restrict__ od)
{
  int idx = blockIdx.x * 256 + threadIdx.x;  // 16384 total
  int k = idx >> 7, m = idx & 127;
  int s = m * DIM + k;
  oa[idx] = a[s]; ob[idx] = b[s]; oc[idx] = c[s]; od[idx] = d[s];
}

// ---------------- per-graph-quarter CSR-in-LDS neighbor mean prep ----------
// writes s_out (sum of x[src] over valid in-edges) and c_out (in-degree)
__global__ __launch_bounds__(256) void k_aggregate(
    const int* __restrict__ src, const int* __restrict__ dst,
    const float* __restrict__ x, float* __restrict__ s_out,
    float* __restrict__ c_out, int npg)
{
  __shared__ int cnt[256];
  __shared__ int sc[256];
  __shared__ int cur[256];
  __shared__ int elist[EPG];
  const int t  = threadIdx.x;
  const int gb = blockIdx.x >> 2;
  const int qb = blockIdx.x & 3;
  const int nodes_q = (npg + 3) >> 2;
  const int v0 = qb * nodes_q;
  const int nq = min(npg - v0, nodes_q);
  const int nodeBase = gb * npg;
  const int e0 = gb * EPG;
  cnt[t] = 0;
  __syncthreads();
  for (int e = e0 + t; e < e0 + EPG; e += 256) {
    int sv = src[e];
    if (sv >= 0) {
      int dl = dst[e] - nodeBase - v0;
      if (dl >= 0 && dl < nq) atomicAdd(&cnt[dl], 1);
    }
  }
  __syncthreads();
  int cv = (t < nq) ? cnt[t] : 0;
  sc[t] = cv;
  __syncthreads();
  for (int d = 1; d < 256; d <<= 1) {
    int add = (t >= d) ? sc[t - d] : 0;
    __syncthreads();
    sc[t] += add;
    __syncthreads();
  }
  cur[t] = sc[t] - cv;
  __syncthreads();
  for (int e = e0 + t; e < e0 + EPG; e += 256) {
    int sv = src[e];
    if (sv >= 0) {
      int dl = dst[e] - nodeBase - v0;
      if (dl >= 0 && dl < nq) {
        int pos = atomicAdd(&cur[dl], 1);
        elist[pos] = sv;   // global current id of source
      }
    }
  }
  __syncthreads();
  const int lane = t & 31, grp = t >> 5;
  for (int v = grp; v < nq; v += 8) {
    int cn = cnt[v];
    int beg = sc[v] - cn;
    float4 acc = {0.f, 0.f, 0.f, 0.f};
    for (int e2 = 0; e2 < cn; ++e2) {
      int svg = elist[beg + e2];
      float4 xv = ((const float4*)(x + (size_t)svg * DIM))[lane];
      acc.x += xv.x; acc.y += xv.y; acc.z += xv.z; acc.w += xv.w;
    }
    int vg = nodeBase + v0 + v;
    ((float4*)(s_out + (size_t)vg * DIM))[lane] = acc;
    if (lane == 0) c_out[vg] = (float)cn;
  }
}

// ---------------- h = relu(mean@wl.T + bl + x@wr.T), in-place over s -------
__global__ __launch_bounds__(256) void k_gemm(
    const float* __restrict__ x, float* __restrict__ s, const float* __restrict__ c,
    const float* __restrict__ wlT, const float* __restrict__ wrT,
    const float* __restrict__ bl)
{
  __shared__ float W[128 * 128];
  const int t = threadIdx.x;
  const int row = blockIdx.x * 64 + (t >> 2);
  const int g = t & 3;
  int cb[8];
  #pragma unroll
  for (int j4 = 0; j4 < 8; ++j4) cb[j4] = g * 32 + ((4 * j4 + g * 8) & 31);
  float acc[32];
  #pragma unroll
  for (int j = 0; j < 32; ++j) acc[j] = 0.f;

  for (int idx = t; idx < 128 * 128; idx += 256) W[idx] = wlT[idx];
  __syncthreads();

  const float invc = 1.0f / fmaxf(c[row], 1.0f);
  const float4* s4 = (const float4*)(s + (size_t)row * DIM);
  const float4* x4 = (const float4*)(x + (size_t)row * DIM);

  for (int k4 = 0; k4 < 32; ++k4) {
    float4 sv = s4[k4];
    float mv[4] = { sv.x * invc, sv.y * invc, sv.z * invc, sv.w * invc };
    #pragma unroll
    for (int kk = 0; kk < 4; ++kk) {
      const float* Wrow = W + (4 * k4 + kk) * 128;
      #pragma unroll
      for (int j4 = 0; j4 < 8; ++j4) {
        float4 wv = *(const float4*)(Wrow + cb[j4]);
        acc[4*j4+0] += mv[kk] * wv.x;
        acc[4*j4+1] += mv[kk] * wv.y;
        acc[4*j4+2] += mv[kk] * wv.z;
        acc[4*j4+3] += mv[kk] * wv.w;
      }
    }
  }
  __syncthreads();
  for (int idx = t; idx < 128 * 128; idx += 256) W[idx] = wrT[idx];
  __syncthreads();
  for (int k4 = 0; k4 < 32; ++k4) {
    float4 xv = x4[k4];
    float mv[4] = { xv.x, xv.y, xv.z, xv.w };
    #pragma unroll
    for (int kk = 0; kk < 4; ++kk) {
      const float* Wrow = W + (4 * k4 + kk) * 128;
      #pragma unroll
      for (int j4 = 0; j4 < 8; ++j4) {
        float4 wv = *(const float4*)(Wrow + cb[j4]);
        acc[4*j4+0] += mv[kk] * wv.x;
        acc[4*j4+1] += mv[kk] * wv.y;
        acc[4*j4+2] += mv[kk] * wv.z;
        acc[4*j4+3] += mv[kk] * wv.w;
      }
    }
  }
  float* orow = s + (size_t)row * DIM;   // safe: all s reads of this block done
  #pragma unroll
  for (int j4 = 0; j4 < 8; ++j4) {
    int cbase = cb[j4];
    float4 o;
    o.x = fmaxf(acc[4*j4+0] + bl[cbase+0], 0.f);
    o.y = fmaxf(acc[4*j4+1] + bl[cbase+1], 0.f);
    o.z = fmaxf(acc[4*j4+2] + bl[cbase+2], 0.f);
    o.w = fmaxf(acc[4*j4+3] + bl[cbase+3], 0.f);
    *(float4*)(orow + cbase) = o;
  }
}

// ---------------- raw scores = h . pool_w ----------------
__global__ __launch_bounds__(256) void k_scores(const float* __restrict__ h,
    const float* __restrict__ pw, float* __restrict__ score)
{
  int tid = blockIdx.x * 256 + threadIdx.x;
  int node = tid >> 5, lane = tid & 31;
  float4 hv = ((const float4*)(h + (size_t)node * DIM))[lane];
  float4 wv = ((const float4*)pw)[lane];
  float p = hv.x*wv.x + hv.y*wv.y + hv.z*wv.z + hv.w*wv.w;
  for (int off = 16; off; off >>= 1) p += __shfl_xor(p, off);
  if (lane == 0) score[node] = p;
}

// ---------------- per-graph bitonic top-k ----------------
__global__ __launch_bounds__(1024) void k_topk(const float* __restrict__ score,
    const float* __restrict__ inv_norm_p, int npg, int k,
    int* __restrict__ new_id, int* __restrict__ sel_pos, float* __restrict__ sel_scale)
{
  __shared__ float key[1024];
  __shared__ int   idx[1024];
  const int t = threadIdx.x;
  const int b = blockIdx.x;
  const int base = b * npg;
  key[t] = (t < npg) ? score[base + t] : -3.402823466e38f;
  idx[t] = t;
  if (t < npg) new_id[base + t] = -1;
  __syncthreads();
  for (int size = 2; size <= 1024; size <<= 1) {
    for (int stride = size >> 1; stride > 0; stride >>= 1) {
      int p = t ^ stride;
      if (p > t) {
        float ka = key[t], kb = key[p];
        int ia = idx[t], ib = idx[p];
        bool a_first = (ka > kb) || (ka == kb && ia < ib);
        bool desc = ((t & size) == 0);
        if (desc ? !a_first : a_first) {
          key[t] = kb; key[p] = ka; idx[t] = ib; idx[p] = ia;
        }
      }
      __syncthreads();
    }
  }
  if (t < k) {
    float inv = *inv_norm_p;
    int local = idx[t];
    new_id[base + local] = b * k + t;
    sel_pos[b * k + t] = base + local;
    sel_scale[b * k + t] = tanhf(key[t] * inv);
  }
}

// ---------------- pooled x = h[sel] * tanh(val) ----------------
__global__ __launch_bounds__(256) void k_pool(const float* __restrict__ h,
    const int* __restrict__ sel_pos, const float* __restrict__ sel_scale,
    float* __restrict__ xo)
{
  int tid = blockIdx.x * 256 + threadIdx.x;
  int j = tid >> 5, lane = tid & 31;
  float scv = sel_scale[j];
  float4 v = ((const float4*)(h + (size_t)sel_pos[j] * DIM))[lane];
  v.x *= scv; v.y *= scv; v.z *= scv; v.w *= scv;
  ((float4*)(xo + (size_t)j * DIM))[lane] = v;
}

// ---------------- readout: per-graph max|mean over k rows ----------------
__global__ __launch_bounds__(128) void k_readout(const float* __restrict__ x, int k,
    float* __restrict__ rd, int add)
{
  int b = blockIdx.x, d = threadIdx.x;
  const float* xb = x + (size_t)b * k * DIM + d;
  float mx = -3.402823466e38f, sm = 0.f;
  for (int r = 0; r < k; ++r) {
    float v = xb[(size_t)r * DIM];
    mx = fmaxf(mx, v);
    sm += v;
  }
  float mean = sm / (float)k;
  if (add) { rd[b*256 + d] += mx; rd[b*256 + 128 + d] += mean; }
  else     { rd[b*256 + d]  = mx; rd[b*256 + 128 + d]  = mean; }
}

// ---------------- relabel edges through new_id ----------------
__global__ __launch_bounds__(256) void k_relabel(const int* __restrict__ new_id,
    int* __restrict__ src, int* __restrict__ dst)
{
  int e = blockIdx.x * 256 + threadIdx.x;
  int sv = src[e];
  if (sv < 0) return;
  int dv = dst[e];
  int ns = new_id[sv], nd = new_id[dv];
  if (ns < 0 || nd < 0) { src[e] = -1; }
  else { src[e] = ns; dst[e] = nd; }
}

// ---------------- MLP part 1: y1g = h@fc1_w.T + b (pre-BN) ----------------
__global__ __launch_bounds__(256) void k_mlp1(const float* __restrict__ rd,
    const float* __restrict__ fc1_w, const float* __restrict__ fc1_b,
    float* __restrict__ y1g)
{
  int gt = blockIdx.x * 256 + threadIdx.x;   // 0..1023
  int m = gt & 127;
  int i0 = (gt >> 7) * 8;
  float acc[8];
  #pragma unroll
  for (int i = 0; i < 8; ++i) acc[i] = 0.f;
  const float* wrow = fc1_w + (size_t)m * 256;
  for (int k = 0; k < 256; ++k) {
    float wv = wrow[k];
    #pragma unroll
    for (int i = 0; i < 8; ++i)
      acc[i] += rd[(i0 + i) * 256 + k] * wv;
  }
  float bb = fc1_b[m];
  #pragma unroll
  for (int i = 0; i < 8; ++i) y1g[(i0 + i) * 128 + m] = acc[i] + bb;
}

// ---------------- MLP part 2: bn1+relu, fc2, bn2+relu, lin+sigmoid --------
__global__ __launch_bounds__(256) void k_mlp2(const float* __restrict__ y1g,
    const float* __restrict__ g1, const float* __restrict__ be1,
    const float* __restrict__ fc2_w, const float* __restrict__ fc2_b,
    const float* __restrict__ g2, const float* __restrict__ be2,
    const float* __restrict__ lin_w, const float* __restrict__ lin_b,
    float* __restrict__ out)
{
  __shared__ float y1[64 * 128];
  __shared__ float y2[64 * 64];
  int t = threadIdx.x;
  for (int o = t; o < 64 * 128; o += 256) y1[o] = y1g[o];
  __syncthreads();
  if (t < 128) {
    float s = 0.f;
    for (int i = 0; i < 64; ++i) s += y1[i * 128 + t];
    float mu = s * 0.015625f;
    float var = 0.f;
    for (int i = 0; i < 64; ++i) { float d = y1[i * 128 + t] - mu; var += d * d; }
    var *= 0.015625f;
    float inv = 1.0f / sqrtf(var + 1e-5f);
    float gg = g1[t], bb = be1[t];
    for (int i = 0; i < 64; ++i)
      y1[i * 128 + t] = fmaxf((y1[i * 128 + t] - mu) * inv * gg + bb, 0.f);
  }
  __syncthreads();
  {
    int m = t & 63, q = t >> 6;
    int i0 = q * 16;
    float acc[16];
    #pragma unroll
    for (int i = 0; i < 16; ++i) acc[i] = 0.f;
    const float* wrow = fc2_w + (size_t)m * 128;
    for (int k = 0; k < 128; ++k) {
      float wv = wrow[k];
      #pragma unroll 4
      for (int i = 0; i < 16; ++i)
        acc[i] += y1[(i0 + i) * 128 + k] * wv;
    }
    float bb = fc2_b[m];
    #pragma unroll
    for (int i = 0; i < 16; ++i) y2[(i0 + i) * 64 + m] = acc[i] + bb;
  }
  __syncthreads();
  if (t < 64) {
    float s = 0.f;
    for (int i = 0; i < 64; ++i) s += y2[i * 64 + t];
    float mu = s * 0.015625f;
    float var = 0.f;
    for (int i = 0; i < 64; ++i) { float d = y2[i * 64 + t] - mu; var += d * d; }
    var *= 0.015625f;
    float inv = 1.0f / sqrtf(var + 1e-5f);
    float gg = g2[t], bb = be2[t];
    for (int i = 0; i < 64; ++i)
      y2[i * 64 + t] = fmaxf((y2[i * 64 + t] - mu) * inv * gg + bb, 0.f);
  }
  __syncthreads();
  if (t < 64) {
    float a = lin_b[0];
    for (int k = 0; k < 64; ++k) a += y2[t * 64 + k] * lin_w[k];
    out[t] = 1.0f / (1.0f + expf(-a));
  }
}

extern "C" void kernel_launch(void* const* d_in, const int* in_sizes, int n_in,
                              void* d_out, int out_size, void* d_ws, size_t ws_size,
                              hipStream_t stream) {
  const int*   node_idx = (const int*)  d_in[0];
  const int*   edge_idx = (const int*)  d_in[1];
  const float* emb      = (const float*)d_in[2];
  const float* w1l      = (const float*)d_in[3];
  const float* b1l      = (const float*)d_in[4];
  const float* w1r      = (const float*)d_in[5];
  const float* pool_w   = (const float*)d_in[6];
  const float* w2l      = (const float*)d_in[7];
  const float* b2l      = (const float*)d_in[8];
  const float* w2r      = (const float*)d_in[9];
  const float* fc1_w    = (const float*)d_in[10];
  const float* fc1_b    = (const float*)d_in[11];
  const float* bn1_g    = (const float*)d_in[12];
  const float* bn1_b    = (const float*)d_in[13];
  const float* fc2_w    = (const float*)d_in[14];
  const float* fc2_b    = (const float*)d_in[15];
  const float* bn2_g    = (const float*)d_in[16];
  const float* bn2_b    = (const float*)d_in[17];
  const float* lin_w    = (const float*)d_in[18];
  const float* lin_b    = (const float*)d_in[19];
  float* out = (float*)d_out;

  char* p = (char*)d_ws;
  auto alloc = [&](size_t bytes) -> void* {
    void* r = (void*)p;
    p += (bytes + 255) & ~(size_t)255;
    return r;
  };
  float* x_cur     = (float*)alloc((size_t)NNODE * DIM * 4);
  float* s_buf     = (float*)alloc((size_t)NNODE * DIM * 4);
  float* c_buf     = (float*)alloc((size_t)NNODE * 4);
  float* score     = (float*)alloc((size_t)NNODE * 4);
  int*   new_id    = (int*)  alloc((size_t)NNODE * 4);
  int*   sel_pos   = (int*)  alloc((size_t)NGRAPH * 820 * 4);
  float* sel_scale = (float*)alloc((size_t)NGRAPH * 820 * 4);
  int*   src_cur   = (int*)  alloc((size_t)NEDGE * 4);
  int*   dst_cur   = (int*)  alloc((size_t)NEDGE * 4);
  float* rd        = (float*)alloc((size_t)NGRAPH * 256 * 4);
  float* wT        = (float*)alloc((size_t)4 * 16384 * 4);
  float* y1g       = (float*)alloc((size_t)64 * 128 * 4);
  float* inv_norm  = (float*)alloc(256);

  float* w1lT = wT;
  float* w1rT = wT + 16384;
  float* w2lT = wT + 32768;
  float* w2rT = wT + 49152;

  k_gather<<<NNODE * 32 / 256, 256, 0, stream>>>(emb, node_idx, x_cur);
  k_edges_init<<<NEDGE / 256, 256, 0, stream>>>(edge_idx, src_cur, dst_cur);
  k_norm<<<1, 64, 0, stream>>>(pool_w, inv_norm);
  k_transpose4<<<64, 256, 0, stream>>>(w1l, w1r, w2l, w2r, w1lT, w1rT, w2lT, w2rT);

  const int Ks[3] = {820, 656, 525};
  int npg = NPG0;
  for (int stage = 0; stage < 3; ++stage) {
    const float* wlT = stage ? w2lT : w1lT;
    const float* wrT = stage ? w2rT : w1rT;
    const float* bl  = stage ? b2l  : b1l;
    int n = NGRAPH * npg;
    int k = Ks[stage];

    k_aggregate<<<NGRAPH * 4, 256, 0, stream>>>(src_cur, dst_cur, x_cur, s_buf, c_buf, npg);
    k_gemm<<<n / 64, 256, 0, stream>>>(x_cur, s_buf, c_buf, wlT, wrT, bl);
    k_scores<<<n / 8, 256, 0, stream>>>(s_buf, pool_w, score);
    k_topk<<<NGRAPH, 1024, 0, stream>>>(score, inv_norm, npg, k, new_id, sel_pos, sel_scale);
    k_pool<<<NGRAPH * k / 8, 256, 0, stream>>>(s_buf, sel_pos, sel_scale, x_cur);
    k_readout<<<NGRAPH, 128, 0, stream>>>(x_cur, k, rd, stage == 0 ? 0 : 1);
    if (stage < 2)
      k_relabel<<<NEDGE / 256, 256, 0, stream>>>(new_id, src_cur, dst_cur);
    npg = k;
  }

  k_mlp1<<<4, 256, 0, stream>>>(rd, fc1_w, fc1_b, y1g);
  k_mlp2<<<1, 256, 0, stream>>>(y1g, bn1_g, bn1_b, fc2_w, fc2_b, bn2_g, bn2_b,
                                lin_w, lin_b, out);
}

// Round 2
// 765.641 us; speedup vs baseline: 1.6293x; 1.6293x over previous
//
#include <hip/hip_runtime.h>
#include <hip/hip_bf16.h>
#include <cstdint>
#include <cstddef>

#define NGRAPH 64
#define NPG0   1024
#define NNODE  65536     // NGRAPH*NPG0
#define NEDGE  524288
#define EPG    8192      // NEDGE/NGRAPH
#define DIM    128
#define RCHUNK 16        // readout partial chunks per graph

// ---------------- gather x = emb[node_idx] ----------------
__global__ __launch_bounds__(256) void k_gather(const float* __restrict__ emb,
    const int* __restrict__ nid, float* __restrict__ x)
{
  int tid = blockIdx.x * 256 + threadIdx.x;
  int i = tid >> 5, lane = tid & 31;
  int row = nid[i];
  ((float4*)(x + (size_t)i * DIM))[lane] =
      ((const float4*)(emb + (size_t)row * DIM))[lane];
}

// ---------------- copy edges to mutable ws ----------------
__global__ __launch_bounds__(256) void k_edges_init(const int* __restrict__ ei,
    int* __restrict__ src, int* __restrict__ dst)
{
  int e = blockIdx.x * 256 + threadIdx.x;
  src[e] = ei[e];
  dst[e] = ei[NEDGE + e];
}

// ---------------- 1/||pool_w|| ----------------
__global__ __launch_bounds__(64) void k_norm(const float* __restrict__ pw,
    float* __restrict__ inv_norm)
{
  int t = threadIdx.x;
  float a = pw[t], b = pw[t + 64];
  float v = a * a + b * b;
  for (int off = 32; off; off >>= 1) v += __shfl_xor(v, off);
  if (t == 0) *inv_norm = 1.0f / sqrtf(v);
}

// ---------------- transpose the 4 128x128 weight mats once ----------------
__global__ __launch_bounds__(256) void k_transpose4(
    const float* __restrict__ a, const float* __restrict__ b,
    const float* __restrict__ c, const float* __restrict__ d,
    float* __restrict__ oa, float* __restrict__ ob,
    float* __restrict__ oc, float* __restrict__ od)
{
  int idx = blockIdx.x * 256 + threadIdx.x;  // 16384 total
  int k = idx >> 7, m = idx & 127;
  int s = m * DIM + k;
  oa[idx] = a[s]; ob[idx] = b[s]; oc[idx] = c[s]; od[idx] = d[s];
}

// ---------------- per-graph-quarter CSR-in-LDS neighbor mean prep ----------
__global__ __launch_bounds__(256) void k_aggregate(
    const int* __restrict__ src, const int* __restrict__ dst,
    const float* __restrict__ x, float* __restrict__ s_out,
    float* __restrict__ c_out, int npg)
{
  __shared__ int cnt[256];
  __shared__ int sc[256];
  __shared__ int cur[256];
  __shared__ int elist[EPG];
  const int t  = threadIdx.x;
  const int gb = blockIdx.x >> 2;
  const int qb = blockIdx.x & 3;
  const int nodes_q = (npg + 3) >> 2;
  const int v0 = qb * nodes_q;
  const int nq = min(npg - v0, nodes_q);
  const int nodeBase = gb * npg;
  const int e0 = gb * EPG;
  cnt[t] = 0;
  __syncthreads();
  for (int e = e0 + t; e < e0 + EPG; e += 256) {
    int sv = src[e];
    if (sv >= 0) {
      int dl = dst[e] - nodeBase - v0;
      if (dl >= 0 && dl < nq) atomicAdd(&cnt[dl], 1);
    }
  }
  __syncthreads();
  int cv = (t < nq) ? cnt[t] : 0;
  sc[t] = cv;
  __syncthreads();
  for (int d = 1; d < 256; d <<= 1) {
    int add = (t >= d) ? sc[t - d] : 0;
    __syncthreads();
    sc[t] += add;
    __syncthreads();
  }
  cur[t] = sc[t] - cv;
  __syncthreads();
  for (int e = e0 + t; e < e0 + EPG; e += 256) {
    int sv = src[e];
    if (sv >= 0) {
      int dl = dst[e] - nodeBase - v0;
      if (dl >= 0 && dl < nq) {
        int pos = atomicAdd(&cur[dl], 1);
        elist[pos] = sv;
      }
    }
  }
  __syncthreads();
  const int lane = t & 31, grp = t >> 5;
  for (int v = grp; v < nq; v += 8) {
    int cn = cnt[v];
    int beg = sc[v] - cn;
    float4 acc = {0.f, 0.f, 0.f, 0.f};
    for (int e2 = 0; e2 < cn; ++e2) {
      int svg = elist[beg + e2];
      float4 xv = ((const float4*)(x + (size_t)svg * DIM))[lane];
      acc.x += xv.x; acc.y += xv.y; acc.z += xv.z; acc.w += xv.w;
    }
    int vg = nodeBase + v0 + v;
    ((float4*)(s_out + (size_t)vg * DIM))[lane] = acc;
    if (lane == 0) c_out[vg] = (float)cn;
  }
}

// ---------------- h = relu(mean@wl.T + bl + x@wr.T), in-place over s -------
__global__ __launch_bounds__(256) void k_gemm(
    const float* __restrict__ x, float* __restrict__ s, const float* __restrict__ c,
    const float* __restrict__ wlT, const float* __restrict__ wrT,
    const float* __restrict__ bl)
{
  __shared__ float W[128 * 128];
  const int t = threadIdx.x;
  const int row = blockIdx.x * 64 + (t >> 2);
  const int g = t & 3;
  int cb[8];
  #pragma unroll
  for (int j4 = 0; j4 < 8; ++j4) cb[j4] = g * 32 + ((4 * j4 + g * 8) & 31);
  float acc[32];
  #pragma unroll
  for (int j = 0; j < 32; ++j) acc[j] = 0.f;

  for (int idx = t; idx < 128 * 128; idx += 256) W[idx] = wlT[idx];
  __syncthreads();

  const float invc = 1.0f / fmaxf(c[row], 1.0f);
  const float4* s4 = (const float4*)(s + (size_t)row * DIM);
  const float4* x4 = (const float4*)(x + (size_t)row * DIM);

  for (int k4 = 0; k4 < 32; ++k4) {
    float4 sv = s4[k4];
    float mv[4] = { sv.x * invc, sv.y * invc, sv.z * invc, sv.w * invc };
    #pragma unroll
    for (int kk = 0; kk < 4; ++kk) {
      const float* Wrow = W + (4 * k4 + kk) * 128;
      #pragma unroll
      for (int j4 = 0; j4 < 8; ++j4) {
        float4 wv = *(const float4*)(Wrow + cb[j4]);
        acc[4*j4+0] += mv[kk] * wv.x;
        acc[4*j4+1] += mv[kk] * wv.y;
        acc[4*j4+2] += mv[kk] * wv.z;
        acc[4*j4+3] += mv[kk] * wv.w;
      }
    }
  }
  __syncthreads();
  for (int idx = t; idx < 128 * 128; idx += 256) W[idx] = wrT[idx];
  __syncthreads();
  for (int k4 = 0; k4 < 32; ++k4) {
    float4 xv = x4[k4];
    float mv[4] = { xv.x, xv.y, xv.z, xv.w };
    #pragma unroll
    for (int kk = 0; kk < 4; ++kk) {
      const float* Wrow = W + (4 * k4 + kk) * 128;
      #pragma unroll
      for (int j4 = 0; j4 < 8; ++j4) {
        float4 wv = *(const float4*)(Wrow + cb[j4]);
        acc[4*j4+0] += mv[kk] * wv.x;
        acc[4*j4+1] += mv[kk] * wv.y;
        acc[4*j4+2] += mv[kk] * wv.z;
        acc[4*j4+3] += mv[kk] * wv.w;
      }
    }
  }
  float* orow = s + (size_t)row * DIM;
  #pragma unroll
  for (int j4 = 0; j4 < 8; ++j4) {
    int cbase = cb[j4];
    float4 o;
    o.x = fmaxf(acc[4*j4+0] + bl[cbase+0], 0.f);
    o.y = fmaxf(acc[4*j4+1] + bl[cbase+1], 0.f);
    o.z = fmaxf(acc[4*j4+2] + bl[cbase+2], 0.f);
    o.w = fmaxf(acc[4*j4+3] + bl[cbase+3], 0.f);
    *(float4*)(orow + cbase) = o;
  }
}

// ---------------- raw scores = h . pool_w ----------------
__global__ __launch_bounds__(256) void k_scores(const float* __restrict__ h,
    const float* __restrict__ pw, float* __restrict__ score)
{
  int tid = blockIdx.x * 256 + threadIdx.x;
  int node = tid >> 5, lane = tid & 31;
  float4 hv = ((const float4*)(h + (size_t)node * DIM))[lane];
  float4 wv = ((const float4*)pw)[lane];
  float p = hv.x*wv.x + hv.y*wv.y + hv.z*wv.z + hv.w*wv.w;
  for (int off = 16; off; off >>= 1) p += __shfl_xor(p, off);
  if (lane == 0) score[node] = p;
}

// ---------------- per-graph bitonic top-k ----------------
__global__ __launch_bounds__(1024) void k_topk(const float* __restrict__ score,
    const float* __restrict__ inv_norm_p, int npg, int k,
    int* __restrict__ new_id, int* __restrict__ sel_pos, float* __restrict__ sel_scale)
{
  __shared__ float key[1024];
  __shared__ int   idx[1024];
  const int t = threadIdx.x;
  const int b = blockIdx.x;
  const int base = b * npg;
  key[t] = (t < npg) ? score[base + t] : -3.402823466e38f;
  idx[t] = t;
  if (t < npg) new_id[base + t] = -1;
  __syncthreads();
  for (int size = 2; size <= 1024; size <<= 1) {
    for (int stride = size >> 1; stride > 0; stride >>= 1) {
      int p = t ^ stride;
      if (p > t) {
        float ka = key[t], kb = key[p];
        int ia = idx[t], ib = idx[p];
        bool a_first = (ka > kb) || (ka == kb && ia < ib);
        bool desc = ((t & size) == 0);
        if (desc ? !a_first : a_first) {
          key[t] = kb; key[p] = ka; idx[t] = ib; idx[p] = ia;
        }
      }
      __syncthreads();
    }
  }
  if (t < k) {
    float inv = *inv_norm_p;
    int local = idx[t];
    new_id[base + local] = b * k + t;
    sel_pos[b * k + t] = base + local;
    sel_scale[b * k + t] = tanhf(key[t] * inv);
  }
}

// ---------------- pooled x = h[sel] * tanh(val) ----------------
__global__ __launch_bounds__(256) void k_pool(const float* __restrict__ h,
    const int* __restrict__ sel_pos, const float* __restrict__ sel_scale,
    float* __restrict__ xo)
{
  int tid = blockIdx.x * 256 + threadIdx.x;
  int j = tid >> 5, lane = tid & 31;
  float scv = sel_scale[j];
  float4 v = ((const float4*)(h + (size_t)sel_pos[j] * DIM))[lane];
  v.x *= scv; v.y *= scv; v.z *= scv; v.w *= scv;
  ((float4*)(xo + (size_t)j * DIM))[lane] = v;
}

// ---------------- readout stage A: per-(graph,chunk) partial max/sum ------
__global__ __launch_bounds__(256) void k_readout_part(const float* __restrict__ x,
    int k, float* __restrict__ pmax, float* __restrict__ psum)
{
  __shared__ float smx[256], ssm[256];
  const int b  = blockIdx.x >> 4;        // graph
  const int ch = blockIdx.x & (RCHUNK - 1);
  const int rpc = (k + RCHUNK - 1) / RCHUNK;
  const int r0 = ch * rpc;
  const int r1 = min(k, r0 + rpc);
  const int d   = threadIdx.x & 127;
  const int sub = threadIdx.x >> 7;      // 0/1
  const float* xb = x + (size_t)b * k * DIM;
  float mx = -3.402823466e38f, sm = 0.f;
  for (int r = r0 + sub; r < r1; r += 2) {
    float v = xb[(size_t)r * DIM + d];
    mx = fmaxf(mx, v);
    sm += v;
  }
  smx[threadIdx.x] = mx; ssm[threadIdx.x] = sm;
  __syncthreads();
  if (sub == 0) {
    mx = fmaxf(mx, smx[d + 128]);
    sm += ssm[d + 128];
    int o = (b * RCHUNK + ch) * 128 + d;
    pmax[o] = mx; psum[o] = sm;
  }
}

// ---------------- readout stage B: combine partials, accumulate rd --------
__global__ __launch_bounds__(128) void k_readout_final(const float* __restrict__ pmax,
    const float* __restrict__ psum, int k, float* __restrict__ rd, int add)
{
  int b = blockIdx.x, d = threadIdx.x;
  float mx = -3.402823466e38f, sm = 0.f;
  #pragma unroll
  for (int c = 0; c < RCHUNK; ++c) {
    int o = (b * RCHUNK + c) * 128 + d;
    mx = fmaxf(mx, pmax[o]);
    sm += psum[o];
  }
  float mean = sm / (float)k;
  if (add) { rd[b*256 + d] += mx; rd[b*256 + 128 + d] += mean; }
  else     { rd[b*256 + d]  = mx; rd[b*256 + 128 + d]  = mean; }
}

// ---------------- relabel edges through new_id ----------------
__global__ __launch_bounds__(256) void k_relabel(const int* __restrict__ new_id,
    int* __restrict__ src, int* __restrict__ dst)
{
  int e = blockIdx.x * 256 + threadIdx.x;
  int sv = src[e];
  if (sv < 0) return;
  int dv = dst[e];
  int ns = new_id[sv], nd = new_id[dv];
  if (ns < 0 || nd < 0) { src[e] = -1; }
  else { src[e] = ns; dst[e] = nd; }
}

// ---------------- MLP part 1: y1g = h@fc1_w.T + b (pre-BN) ----------------
__global__ __launch_bounds__(256) void k_mlp1(const float* __restrict__ rd,
    const float* __restrict__ fc1_w, const float* __restrict__ fc1_b,
    float* __restrict__ y1g)
{
  int gt = blockIdx.x * 256 + threadIdx.x;   // 0..1023
  int m = gt & 127;
  int i0 = (gt >> 7) * 8;
  float acc[8];
  #pragma unroll
  for (int i = 0; i < 8; ++i) acc[i] = 0.f;
  const float* wrow = fc1_w + (size_t)m * 256;
  for (int k = 0; k < 256; ++k) {
    float wv = wrow[k];
    #pragma unroll
    for (int i = 0; i < 8; ++i)
      acc[i] += rd[(i0 + i) * 256 + k] * wv;
  }
  float bb = fc1_b[m];
  #pragma unroll
  for (int i = 0; i < 8; ++i) y1g[(i0 + i) * 128 + m] = acc[i] + bb;
}

// ---------------- MLP part 2: bn1+relu, fc2, bn2+relu, lin+sigmoid --------
__global__ __launch_bounds__(256) void k_mlp2(const float* __restrict__ y1g,
    const float* __restrict__ g1, const float* __restrict__ be1,
    const float* __restrict__ fc2_w, const float* __restrict__ fc2_b,
    const float* __restrict__ g2, const float* __restrict__ be2,
    const float* __restrict__ lin_w, const float* __restrict__ lin_b,
    float* __restrict__ out)
{
  __shared__ float y1[64 * 128];
  __shared__ float y2[64 * 64];
  int t = threadIdx.x;
  for (int o = t; o < 64 * 128; o += 256) y1[o] = y1g[o];
  __syncthreads();
  if (t < 128) {
    float s = 0.f;
    for (int i = 0; i < 64; ++i) s += y1[i * 128 + t];
    float mu = s * 0.015625f;
    float var = 0.f;
    for (int i = 0; i < 64; ++i) { float d = y1[i * 128 + t] - mu; var += d * d; }
    var *= 0.015625f;
    float inv = 1.0f / sqrtf(var + 1e-5f);
    float gg = g1[t], bb = be1[t];
    for (int i = 0; i < 64; ++i)
      y1[i * 128 + t] = fmaxf((y1[i * 128 + t] - mu) * inv * gg + bb, 0.f);
  }
  __syncthreads();
  {
    int m = t & 63, q = t >> 6;
    int i0 = q * 16;
    float acc[16];
    #pragma unroll
    for (int i = 0; i < 16; ++i) acc[i] = 0.f;
    const float* wrow = fc2_w + (size_t)m * 128;
    for (int k = 0; k < 128; ++k) {
      float wv = wrow[k];
      #pragma unroll 4
      for (int i = 0; i < 16; ++i)
        acc[i] += y1[(i0 + i) * 128 + k] * wv;
    }
    float bb = fc2_b[m];
    #pragma unroll
    for (int i = 0; i < 16; ++i) y2[(i0 + i) * 64 + m] = acc[i] + bb;
  }
  __syncthreads();
  if (t < 64) {
    float s = 0.f;
    for (int i = 0; i < 64; ++i) s += y2[i * 64 + t];
    float mu = s * 0.015625f;
    float var = 0.f;
    for (int i = 0; i < 64; ++i) { float d = y2[i * 64 + t] - mu; var += d * d; }
    var *= 0.015625f;
    float inv = 1.0f / sqrtf(var + 1e-5f);
    float gg = g2[t], bb = be2[t];
    for (int i = 0; i < 64; ++i)
      y2[i * 64 + t] = fmaxf((y2[i * 64 + t] - mu) * inv * gg + bb, 0.f);
  }
  __syncthreads();
  if (t < 64) {
    float a = lin_b[0];
    for (int k = 0; k < 64; ++k) a += y2[t * 64 + k] * lin_w[k];
    out[t] = 1.0f / (1.0f + expf(-a));
  }
}

extern "C" void kernel_launch(void* const* d_in, const int* in_sizes, int n_in,
                              void* d_out, int out_size, void* d_ws, size_t ws_size,
                              hipStream_t stream) {
  const int*   node_idx = (const int*)  d_in[0];
  const int*   edge_idx = (const int*)  d_in[1];
  const float* emb      = (const float*)d_in[2];
  const float* w1l      = (const float*)d_in[3];
  const float* b1l      = (const float*)d_in[4];
  const float* w1r      = (const float*)d_in[5];
  const float* pool_w   = (const float*)d_in[6];
  const float* w2l      = (const float*)d_in[7];
  const float* b2l      = (const float*)d_in[8];
  const float* w2r      = (const float*)d_in[9];
  const float* fc1_w    = (const float*)d_in[10];
  const float* fc1_b    = (const float*)d_in[11];
  const float* bn1_g    = (const float*)d_in[12];
  const float* bn1_b    = (const float*)d_in[13];
  const float* fc2_w    = (const float*)d_in[14];
  const float* fc2_b    = (const float*)d_in[15];
  const float* bn2_g    = (const float*)d_in[16];
  const float* bn2_b    = (const float*)d_in[17];
  const float* lin_w    = (const float*)d_in[18];
  const float* lin_b    = (const float*)d_in[19];
  float* out = (float*)d_out;

  char* p = (char*)d_ws;
  auto alloc = [&](size_t bytes) -> void* {
    void* r = (void*)p;
    p += (bytes + 255) & ~(size_t)255;
    return r;
  };
  float* x_cur     = (float*)alloc((size_t)NNODE * DIM * 4);
  float* s_buf     = (float*)alloc((size_t)NNODE * DIM * 4);
  float* c_buf     = (float*)alloc((size_t)NNODE * 4);
  float* score     = (float*)alloc((size_t)NNODE * 4);
  int*   new_id    = (int*)  alloc((size_t)NNODE * 4);
  int*   sel_pos   = (int*)  alloc((size_t)NGRAPH * 820 * 4);
  float* sel_scale = (float*)alloc((size_t)NGRAPH * 820 * 4);
  int*   src_cur   = (int*)  alloc((size_t)NEDGE * 4);
  int*   dst_cur   = (int*)  alloc((size_t)NEDGE * 4);
  float* rd        = (float*)alloc((size_t)NGRAPH * 256 * 4);
  float* wT        = (float*)alloc((size_t)4 * 16384 * 4);
  float* y1g       = (float*)alloc((size_t)64 * 128 * 4);
  float* pmax      = (float*)alloc((size_t)NGRAPH * RCHUNK * 128 * 4);
  float* psum      = (float*)alloc((size_t)NGRAPH * RCHUNK * 128 * 4);
  float* inv_norm  = (float*)alloc(256);

  float* w1lT = wT;
  float* w1rT = wT + 16384;
  float* w2lT = wT + 32768;
  float* w2rT = wT + 49152;

  k_gather<<<NNODE * 32 / 256, 256, 0, stream>>>(emb, node_idx, x_cur);
  k_edges_init<<<NEDGE / 256, 256, 0, stream>>>(edge_idx, src_cur, dst_cur);
  k_norm<<<1, 64, 0, stream>>>(pool_w, inv_norm);
  k_transpose4<<<64, 256, 0, stream>>>(w1l, w1r, w2l, w2r, w1lT, w1rT, w2lT, w2rT);

  const int Ks[3] = {820, 656, 525};
  int npg = NPG0;
  for (int stage = 0; stage < 3; ++stage) {
    const float* wlT = stage ? w2lT : w1lT;
    const float* wrT = stage ? w2rT : w1rT;
    const float* bl  = stage ? b2l  : b1l;
    int n = NGRAPH * npg;
    int k = Ks[stage];

    k_aggregate<<<NGRAPH * 4, 256, 0, stream>>>(src_cur, dst_cur, x_cur, s_buf, c_buf, npg);
    k_gemm<<<n / 64, 256, 0, stream>>>(x_cur, s_buf, c_buf, wlT, wrT, bl);
    k_scores<<<n / 8, 256, 0, stream>>>(s_buf, pool_w, score);
    k_topk<<<NGRAPH, 1024, 0, stream>>>(score, inv_norm, npg, k, new_id, sel_pos, sel_scale);
    k_pool<<<NGRAPH * k / 8, 256, 0, stream>>>(s_buf, sel_pos, sel_scale, x_cur);
    k_readout_part<<<NGRAPH * RCHUNK, 256, 0, stream>>>(x_cur, k, pmax, psum);
    k_readout_final<<<NGRAPH, 128, 0, stream>>>(pmax, psum, k, rd, stage == 0 ? 0 : 1);
    if (stage < 2)
      k_relabel<<<NEDGE / 256, 256, 0, stream>>>(new_id, src_cur, dst_cur);
    npg = k;
  }

  k_mlp1<<<4, 256, 0, stream>>>(rd, fc1_w, fc1_b, y1g);
  k_mlp2<<<1, 256, 0, stream>>>(y1g, bn1_g, bn1_b, fc2_w, fc2_b, bn2_g, bn2_b,
                                lin_w, lin_b, out);
}

// Round 3
// 674.922 us; speedup vs baseline: 1.8483x; 1.1344x over previous
//
#include <hip/hip_runtime.h>
#include <hip/hip_bf16.h>
#include <cstdint>
#include <cstddef>

#define NGRAPH 64
#define NPG0   1024
#define NNODE  65536     // NGRAPH*NPG0
#define NEDGE  524288
#define EPG    8192      // NEDGE/NGRAPH
#define DIM    128
#define RCHUNK 16        // readout partial chunks per graph

// ---------------- gather x = emb[node_idx] ----------------
__global__ __launch_bounds__(256) void k_gather(const float* __restrict__ emb,
    const int* __restrict__ nid, float* __restrict__ x)
{
  int tid = blockIdx.x * 256 + threadIdx.x;
  int i = tid >> 5, lane = tid & 31;
  int row = nid[i];
  ((float4*)(x + (size_t)i * DIM))[lane] =
      ((const float4*)(emb + (size_t)row * DIM))[lane];
}

// ---------------- copy edges to mutable ws ----------------
__global__ __launch_bounds__(256) void k_edges_init(const int* __restrict__ ei,
    int* __restrict__ src, int* __restrict__ dst)
{
  int e = blockIdx.x * 256 + threadIdx.x;
  src[e] = ei[e];
  dst[e] = ei[NEDGE + e];
}

// ---------------- 1/||pool_w|| ----------------
__global__ __launch_bounds__(64) void k_norm(const float* __restrict__ pw,
    float* __restrict__ inv_norm)
{
  int t = threadIdx.x;
  float a = pw[t], b = pw[t + 64];
  float v = a * a + b * b;
  for (int off = 32; off; off >>= 1) v += __shfl_xor(v, off);
  if (t == 0) *inv_norm = 1.0f / sqrtf(v);
}

// ---------------- transpose the 4 128x128 weight mats once ----------------
__global__ __launch_bounds__(256) void k_transpose4(
    const float* __restrict__ a, const float* __restrict__ b,
    const float* __restrict__ c, const float* __restrict__ d,
    float* __restrict__ oa, float* __restrict__ ob,
    float* __restrict__ oc, float* __restrict__ od)
{
  int idx = blockIdx.x * 256 + threadIdx.x;  // 16384 total
  int k = idx >> 7, m = idx & 127;
  int s = m * DIM + k;
  oa[idx] = a[s]; ob[idx] = b[s]; oc[idx] = c[s]; od[idx] = d[s];
}

// ---------------- per-graph CSR-in-LDS neighbor mean prep -----------------
// ONE block per graph (keeps the graph's 512KB slice on one XCD's L2)
__global__ __launch_bounds__(1024) void k_aggregate(
    const int* __restrict__ src, const int* __restrict__ dst,
    const float* __restrict__ x, float* __restrict__ s_out,
    float* __restrict__ c_out, int npg)
{
  __shared__ int cnt[1024];
  __shared__ int sc[1024];
  __shared__ int cur[1024];
  __shared__ int elist[EPG];
  const int t = threadIdx.x;
  const int g = blockIdx.x;
  const int nodeBase = g * npg;
  const int e0 = g * EPG;
  cnt[t] = 0;
  __syncthreads();
  for (int e = e0 + t; e < e0 + EPG; e += 1024) {
    int sv = src[e];
    if (sv >= 0) atomicAdd(&cnt[dst[e] - nodeBase], 1);
  }
  __syncthreads();
  int cv = cnt[t];
  sc[t] = cv;
  __syncthreads();
  for (int d = 1; d < 1024; d <<= 1) {
    int add = (t >= d) ? sc[t - d] : 0;
    __syncthreads();
    sc[t] += add;
    __syncthreads();
  }
  cur[t] = sc[t] - cv;
  __syncthreads();
  for (int e = e0 + t; e < e0 + EPG; e += 1024) {
    int sv = src[e];
    if (sv >= 0) {
      int pos = atomicAdd(&cur[dst[e] - nodeBase], 1);
      elist[pos] = sv;
    }
  }
  __syncthreads();
  const int lane = t & 31, grp = t >> 5;   // 32 groups of 32 lanes
  for (int v = grp; v < npg; v += 32) {
    int cn = cnt[v];
    int beg = sc[v] - cn;
    float4 acc = {0.f, 0.f, 0.f, 0.f};
    for (int e2 = 0; e2 < cn; ++e2) {
      int svg = elist[beg + e2];
      float4 xv = ((const float4*)(x + (size_t)svg * DIM))[lane];
      acc.x += xv.x; acc.y += xv.y; acc.z += xv.z; acc.w += xv.w;
    }
    int vg = nodeBase + v;
    ((float4*)(s_out + (size_t)vg * DIM))[lane] = acc;
    if (lane == 0) c_out[vg] = (float)cn;
  }
}

// ---------------- h = relu(mean@wl.T + bl + x@wr.T), in-place over s -------
__global__ __launch_bounds__(256) void k_gemm(
    const float* __restrict__ x, float* __restrict__ s, const float* __restrict__ c,
    const float* __restrict__ wlT, const float* __restrict__ wrT,
    const float* __restrict__ bl)
{
  __shared__ float W[128 * 128];
  const int t = threadIdx.x;
  const int row = blockIdx.x * 64 + (t >> 2);
  const int g = t & 3;
  int cb[8];
  #pragma unroll
  for (int j4 = 0; j4 < 8; ++j4) cb[j4] = g * 32 + ((4 * j4 + g * 8) & 31);
  float acc[32];
  #pragma unroll
  for (int j = 0; j < 32; ++j) acc[j] = 0.f;

  for (int idx = t; idx < 128 * 128; idx += 256) W[idx] = wlT[idx];
  __syncthreads();

  const float invc = 1.0f / fmaxf(c[row], 1.0f);
  const float4* s4 = (const float4*)(s + (size_t)row * DIM);
  const float4* x4 = (const float4*)(x + (size_t)row * DIM);

  for (int k4 = 0; k4 < 32; ++k4) {
    float4 sv = s4[k4];
    float mv[4] = { sv.x * invc, sv.y * invc, sv.z * invc, sv.w * invc };
    #pragma unroll
    for (int kk = 0; kk < 4; ++kk) {
      const float* Wrow = W + (4 * k4 + kk) * 128;
      #pragma unroll
      for (int j4 = 0; j4 < 8; ++j4) {
        float4 wv = *(const float4*)(Wrow + cb[j4]);
        acc[4*j4+0] += mv[kk] * wv.x;
        acc[4*j4+1] += mv[kk] * wv.y;
        acc[4*j4+2] += mv[kk] * wv.z;
        acc[4*j4+3] += mv[kk] * wv.w;
      }
    }
  }
  __syncthreads();
  for (int idx = t; idx < 128 * 128; idx += 256) W[idx] = wrT[idx];
  __syncthreads();
  for (int k4 = 0; k4 < 32; ++k4) {
    float4 xv = x4[k4];
    float mv[4] = { xv.x, xv.y, xv.z, xv.w };
    #pragma unroll
    for (int kk = 0; kk < 4; ++kk) {
      const float* Wrow = W + (4 * k4 + kk) * 128;
      #pragma unroll
      for (int j4 = 0; j4 < 8; ++j4) {
        float4 wv = *(const float4*)(Wrow + cb[j4]);
        acc[4*j4+0] += mv[kk] * wv.x;
        acc[4*j4+1] += mv[kk] * wv.y;
        acc[4*j4+2] += mv[kk] * wv.z;
        acc[4*j4+3] += mv[kk] * wv.w;
      }
    }
  }
  float* orow = s + (size_t)row * DIM;
  #pragma unroll
  for (int j4 = 0; j4 < 8; ++j4) {
    int cbase = cb[j4];
    float4 o;
    o.x = fmaxf(acc[4*j4+0] + bl[cbase+0], 0.f);
    o.y = fmaxf(acc[4*j4+1] + bl[cbase+1], 0.f);
    o.z = fmaxf(acc[4*j4+2] + bl[cbase+2], 0.f);
    o.w = fmaxf(acc[4*j4+3] + bl[cbase+3], 0.f);
    *(float4*)(orow + cbase) = o;
  }
}

// ---------------- raw scores = h . pool_w ----------------
__global__ __launch_bounds__(256) void k_scores(const float* __restrict__ h,
    const float* __restrict__ pw, float* __restrict__ score)
{
  int tid = blockIdx.x * 256 + threadIdx.x;
  int node = tid >> 5, lane = tid & 31;
  float4 hv = ((const float4*)(h + (size_t)node * DIM))[lane];
  float4 wv = ((const float4*)pw)[lane];
  float p = hv.x*wv.x + hv.y*wv.y + hv.z*wv.z + hv.w*wv.w;
  for (int off = 16; off; off >>= 1) p += __shfl_xor(p, off);
  if (lane == 0) score[node] = p;
}

// ---------------- per-graph bitonic top-k ----------------
__global__ __launch_bounds__(1024) void k_topk(const float* __restrict__ score,
    const float* __restrict__ inv_norm_p, int npg, int k,
    int* __restrict__ new_id, int* __restrict__ sel_pos, float* __restrict__ sel_scale)
{
  __shared__ float key[1024];
  __shared__ int   idx[1024];
  const int t = threadIdx.x;
  const int b = blockIdx.x;
  const int base = b * npg;
  key[t] = (t < npg) ? score[base + t] : -3.402823466e38f;
  idx[t] = t;
  if (t < npg) new_id[base + t] = -1;
  __syncthreads();
  for (int size = 2; size <= 1024; size <<= 1) {
    for (int stride = size >> 1; stride > 0; stride >>= 1) {
      int p = t ^ stride;
      if (p > t) {
        float ka = key[t], kb = key[p];
        int ia = idx[t], ib = idx[p];
        bool a_first = (ka > kb) || (ka == kb && ia < ib);
        bool desc = ((t & size) == 0);
        if (desc ? !a_first : a_first) {
          key[t] = kb; key[p] = ka; idx[t] = ib; idx[p] = ia;
        }
      }
      __syncthreads();
    }
  }
  if (t < k) {
    float inv = *inv_norm_p;
    int local = idx[t];
    new_id[base + local] = b * k + t;
    sel_pos[b * k + t] = base + local;
    sel_scale[b * k + t] = tanhf(key[t] * inv);
  }
}

// ---------------- pooled x = h[sel] * tanh(val) ----------------
__global__ __launch_bounds__(256) void k_pool(const float* __restrict__ h,
    const int* __restrict__ sel_pos, const float* __restrict__ sel_scale,
    float* __restrict__ xo)
{
  int tid = blockIdx.x * 256 + threadIdx.x;
  int j = tid >> 5, lane = tid & 31;
  float scv = sel_scale[j];
  float4 v = ((const float4*)(h + (size_t)sel_pos[j] * DIM))[lane];
  v.x *= scv; v.y *= scv; v.z *= scv; v.w *= scv;
  ((float4*)(xo + (size_t)j * DIM))[lane] = v;
}

// ---------------- readout stage A: per-(graph,chunk) partial max/sum ------
__global__ __launch_bounds__(256) void k_readout_part(const float* __restrict__ x,
    int k, float* __restrict__ pmax, float* __restrict__ psum)
{
  __shared__ float smx[256], ssm[256];
  const int b  = blockIdx.x >> 4;        // graph
  const int ch = blockIdx.x & (RCHUNK - 1);
  const int rpc = (k + RCHUNK - 1) / RCHUNK;
  const int r0 = ch * rpc;
  const int r1 = min(k, r0 + rpc);
  const int d   = threadIdx.x & 127;
  const int sub = threadIdx.x >> 7;      // 0/1
  const float* xb = x + (size_t)b * k * DIM;
  float mx = -3.402823466e38f, sm = 0.f;
  for (int r = r0 + sub; r < r1; r += 2) {
    float v = xb[(size_t)r * DIM + d];
    mx = fmaxf(mx, v);
    sm += v;
  }
  smx[threadIdx.x] = mx; ssm[threadIdx.x] = sm;
  __syncthreads();
  if (sub == 0) {
    mx = fmaxf(mx, smx[d + 128]);
    sm += ssm[d + 128];
    int o = (b * RCHUNK + ch) * 128 + d;
    pmax[o] = mx; psum[o] = sm;
  }
}

// ------- readout stage B: combine partials, accumulate TRANSPOSED rdT -----
// rdT[k][g]: k in [0,128) = max part, [128,256) = mean part
__global__ __launch_bounds__(128) void k_readout_final(const float* __restrict__ pmax,
    const float* __restrict__ psum, int k, float* __restrict__ rdT, int add)
{
  int b = blockIdx.x, d = threadIdx.x;
  float mx = -3.402823466e38f, sm = 0.f;
  #pragma unroll
  for (int c = 0; c < RCHUNK; ++c) {
    int o = (b * RCHUNK + c) * 128 + d;
    mx = fmaxf(mx, pmax[o]);
    sm += psum[o];
  }
  float mean = sm / (float)k;
  int omx = d * 64 + b;
  int omn = (128 + d) * 64 + b;
  if (add) { rdT[omx] += mx; rdT[omn] += mean; }
  else     { rdT[omx]  = mx; rdT[omn]  = mean; }
}

// ---------------- relabel edges through new_id ----------------
__global__ __launch_bounds__(256) void k_relabel(const int* __restrict__ new_id,
    int* __restrict__ src, int* __restrict__ dst)
{
  int e = blockIdx.x * 256 + threadIdx.x;
  int sv = src[e];
  if (sv < 0) return;
  int dv = dst[e];
  int ns = new_id[sv], nd = new_id[dv];
  if (ns < 0 || nd < 0) { src[e] = -1; }
  else { src[e] = ns; dst[e] = nd; }
}

// ---------------- fused MLP: lane = graph, wave = feature group -----------
// 1 block x 1024 threads (16 waves). BN reductions are intra-wave shuffles.
__global__ __launch_bounds__(1024) void k_mlp(const float* __restrict__ rdT,
    const float* __restrict__ fc1_w, const float* __restrict__ fc1_b,
    const float* __restrict__ g1, const float* __restrict__ be1,
    const float* __restrict__ fc2_w, const float* __restrict__ fc2_b,
    const float* __restrict__ g2, const float* __restrict__ be2,
    const float* __restrict__ lin_w, const float* __restrict__ lin_b,
    float* __restrict__ out)
{
  __shared__ float y1T[128 * 64];   // [feature][graph]
  __shared__ float part[16 * 64];
  const int t = threadIdx.x;
  const int g = t & 63;             // graph = lane
  const int w = t >> 6;             // wave 0..15

  // ---- phase 1: y1[g][f] for f = w*8..w*8+7, k over 256 ----
  float acc[8];
  #pragma unroll
  for (int j = 0; j < 8; ++j) acc[j] = 0.f;
  const float* wr[8];
  #pragma unroll
  for (int j = 0; j < 8; ++j) wr[j] = fc1_w + (size_t)(w * 8 + j) * 256;
  for (int k = 0; k < 256; ++k) {
    float rv = rdT[k * 64 + g];
    #pragma unroll
    for (int j = 0; j < 8; ++j) acc[j] += rv * wr[j][k];
  }
  #pragma unroll
  for (int j = 0; j < 8; ++j) {
    int f = w * 8 + j;
    float y = acc[j] + fc1_b[f];
    // BN over graphs (lanes)
    float s = y, s2 = y * y;
    #pragma unroll
    for (int off = 32; off; off >>= 1) {
      s  += __shfl_xor(s,  off);
      s2 += __shfl_xor(s2, off);
    }
    float mu = s * 0.015625f;
    float var = s2 * 0.015625f - mu * mu;
    float inv = 1.0f / sqrtf(var + 1e-5f);
    float yn = fmaxf((y - mu) * inv * g1[f] + be1[f], 0.f);
    y1T[f * 64 + g] = yn;
  }
  __syncthreads();

  // ---- phase 2: y2[g][m] for m = w*4..w*4+3, k over 128 ----
  float acc2[4];
  #pragma unroll
  for (int j = 0; j < 4; ++j) acc2[j] = 0.f;
  const float* wr2[4];
  #pragma unroll
  for (int j = 0; j < 4; ++j) wr2[j] = fc2_w + (size_t)(w * 4 + j) * 128;
  for (int k = 0; k < 128; ++k) {
    float yv = y1T[k * 64 + g];
    #pragma unroll
    for (int j = 0; j < 4; ++j) acc2[j] += yv * wr2[j][k];
  }
  float y2n[4];
  #pragma unroll
  for (int j = 0; j < 4; ++j) {
    int m = w * 4 + j;
    float y = acc2[j] + fc2_b[m];
    float s = y, s2 = y * y;
    #pragma unroll
    for (int off = 32; off; off >>= 1) {
      s  += __shfl_xor(s,  off);
      s2 += __shfl_xor(s2, off);
    }
    float mu = s * 0.015625f;
    float var = s2 * 0.015625f - mu * mu;
    float inv = 1.0f / sqrtf(var + 1e-5f);
    y2n[j] = fmaxf((y - mu) * inv * g2[m] + be2[m], 0.f);
  }

  // ---- phase 3: partial dot with lin_w, reduce across waves ----
  float pp = 0.f;
  #pragma unroll
  for (int j = 0; j < 4; ++j) pp += y2n[j] * lin_w[w * 4 + j];
  part[w * 64 + g] = pp;
  __syncthreads();
  if (w == 0) {
    float a = lin_b[0];
    #pragma unroll
    for (int c = 0; c < 16; ++c) a += part[c * 64 + g];
    out[g] = 1.0f / (1.0f + expf(-a));
  }
}

extern "C" void kernel_launch(void* const* d_in, const int* in_sizes, int n_in,
                              void* d_out, int out_size, void* d_ws, size_t ws_size,
                              hipStream_t stream) {
  const int*   node_idx = (const int*)  d_in[0];
  const int*   edge_idx = (const int*)  d_in[1];
  const float* emb      = (const float*)d_in[2];
  const float* w1l      = (const float*)d_in[3];
  const float* b1l      = (const float*)d_in[4];
  const float* w1r      = (const float*)d_in[5];
  const float* pool_w   = (const float*)d_in[6];
  const float* w2l      = (const float*)d_in[7];
  const float* b2l      = (const float*)d_in[8];
  const float* w2r      = (const float*)d_in[9];
  const float* fc1_w    = (const float*)d_in[10];
  const float* fc1_b    = (const float*)d_in[11];
  const float* bn1_g    = (const float*)d_in[12];
  const float* bn1_b    = (const float*)d_in[13];
  const float* fc2_w    = (const float*)d_in[14];
  const float* fc2_b    = (const float*)d_in[15];
  const float* bn2_g    = (const float*)d_in[16];
  const float* bn2_b    = (const float*)d_in[17];
  const float* lin_w    = (const float*)d_in[18];
  const float* lin_b    = (const float*)d_in[19];
  float* out = (float*)d_out;

  char* p = (char*)d_ws;
  auto alloc = [&](size_t bytes) -> void* {
    void* r = (void*)p;
    p += (bytes + 255) & ~(size_t)255;
    return r;
  };
  float* x_cur     = (float*)alloc((size_t)NNODE * DIM * 4);
  float* s_buf     = (float*)alloc((size_t)NNODE * DIM * 4);
  float* c_buf     = (float*)alloc((size_t)NNODE * 4);
  float* score     = (float*)alloc((size_t)NNODE * 4);
  int*   new_id    = (int*)  alloc((size_t)NNODE * 4);
  int*   sel_pos   = (int*)  alloc((size_t)NGRAPH * 820 * 4);
  float* sel_scale = (float*)alloc((size_t)NGRAPH * 820 * 4);
  int*   src_cur   = (int*)  alloc((size_t)NEDGE * 4);
  int*   dst_cur   = (int*)  alloc((size_t)NEDGE * 4);
  float* rdT       = (float*)alloc((size_t)256 * 64 * 4);
  float* wT        = (float*)alloc((size_t)4 * 16384 * 4);
  float* pmax      = (float*)alloc((size_t)NGRAPH * RCHUNK * 128 * 4);
  float* psum      = (float*)alloc((size_t)NGRAPH * RCHUNK * 128 * 4);
  float* inv_norm  = (float*)alloc(256);

  float* w1lT = wT;
  float* w1rT = wT + 16384;
  float* w2lT = wT + 32768;
  float* w2rT = wT + 49152;

  k_gather<<<NNODE * 32 / 256, 256, 0, stream>>>(emb, node_idx, x_cur);
  k_edges_init<<<NEDGE / 256, 256, 0, stream>>>(edge_idx, src_cur, dst_cur);
  k_norm<<<1, 64, 0, stream>>>(pool_w, inv_norm);
  k_transpose4<<<64, 256, 0, stream>>>(w1l, w1r, w2l, w2r, w1lT, w1rT, w2lT, w2rT);

  const int Ks[3] = {820, 656, 525};
  int npg = NPG0;
  for (int stage = 0; stage < 3; ++stage) {
    const float* wlT = stage ? w2lT : w1lT;
    const float* wrT = stage ? w2rT : w1rT;
    const float* bl  = stage ? b2l  : b1l;
    int n = NGRAPH * npg;
    int k = Ks[stage];

    k_aggregate<<<NGRAPH, 1024, 0, stream>>>(src_cur, dst_cur, x_cur, s_buf, c_buf, npg);
    k_gemm<<<n / 64, 256, 0, stream>>>(x_cur, s_buf, c_buf, wlT, wrT, bl);
    k_scores<<<n / 8, 256, 0, stream>>>(s_buf, pool_w, score);
    k_topk<<<NGRAPH, 1024, 0, stream>>>(score, inv_norm, npg, k, new_id, sel_pos, sel_scale);
    k_pool<<<NGRAPH * k / 8, 256, 0, stream>>>(s_buf, sel_pos, sel_scale, x_cur);
    k_readout_part<<<NGRAPH * RCHUNK, 256, 0, stream>>>(x_cur, k, pmax, psum);
    k_readout_final<<<NGRAPH, 128, 0, stream>>>(pmax, psum, k, rdT, stage == 0 ? 0 : 1);
    if (stage < 2)
      k_relabel<<<NEDGE / 256, 256, 0, stream>>>(new_id, src_cur, dst_cur);
    npg = k;
  }

  k_mlp<<<1, 1024, 0, stream>>>(rdT, fc1_w, fc1_b, bn1_g, bn1_b,
                                fc2_w, fc2_b, bn2_g, bn2_b, lin_w, lin_b, out);
}

// Round 4
// 508.599 us; speedup vs baseline: 2.4528x; 1.3270x over previous
//
#include <hip/hip_runtime.h>
#include <hip/hip_bf16.h>
#include <cstdint>
#include <cstddef>

#define NGRAPH 64
#define NPG0   1024
#define NNODE  65536     // NGRAPH*NPG0
#define NEDGE  524288
#define EPG    8192      // NEDGE/NGRAPH
#define DIM    128
#define RCHUNK 16        // readout partial chunks per graph

typedef __attribute__((ext_vector_type(8))) short short8v;   // 8 bf16
typedef __attribute__((ext_vector_type(4))) float f32x4;

__device__ __forceinline__ unsigned bf16rne(float f) {
  unsigned u = __float_as_uint(f);
  return (u + 0x7FFFu + ((u >> 16) & 1u)) >> 16;
}

// ---------------- gather x = emb[node_idx] ----------------
__global__ __launch_bounds__(256) void k_gather(const float* __restrict__ emb,
    const int* __restrict__ nid, float* __restrict__ x)
{
  int tid = blockIdx.x * 256 + threadIdx.x;
  int i = tid >> 5, lane = tid & 31;
  int row = nid[i];
  ((float4*)(x + (size_t)i * DIM))[lane] =
      ((const float4*)(emb + (size_t)row * DIM))[lane];
}

// ---------------- copy edges to mutable ws ----------------
__global__ __launch_bounds__(256) void k_edges_init(const int* __restrict__ ei,
    int* __restrict__ src, int* __restrict__ dst)
{
  int e = blockIdx.x * 256 + threadIdx.x;
  src[e] = ei[e];
  dst[e] = ei[NEDGE + e];
}

// ---------------- 1/||pool_w|| ----------------
__global__ __launch_bounds__(64) void k_norm(const float* __restrict__ pw,
    float* __restrict__ inv_norm)
{
  int t = threadIdx.x;
  float a = pw[t], b = pw[t + 64];
  float v = a * a + b * b;
  for (int off = 32; off; off >>= 1) v += __shfl_xor(v, off);
  if (t == 0) *inv_norm = 1.0f / sqrtf(v);
}

// ------- pre-swizzle weights into MFMA B-fragment layout, bf16 hi/lo ------
// frag flat index: ((kk*8+nt)*64 + lane)*8 + j  ->  W[k][n],
//   k = kk*32 + (lane>>4)*8 + j  (k<128 -> wl[n][k], else wr[n][k-128])
//   n = nt*16 + (lane&15)
__global__ __launch_bounds__(256) void k_prep_wfrag(
    const float* __restrict__ w1l, const float* __restrict__ w1r,
    const float* __restrict__ w2l, const float* __restrict__ w2r,
    short* __restrict__ whiF, short* __restrict__ wloF)
{
  int id = blockIdx.x * 256 + threadIdx.x;    // 0..65535 (2 sets x 32768)
  int set = id >> 15;
  int r = id & 32767;
  int j  = r & 7;
  int l  = (r >> 3) & 63;
  int nt = (r >> 9) & 7;
  int kk = r >> 12;
  int k = kk * 32 + ((l >> 4) & 3) * 8 + j;
  int n = nt * 16 + (l & 15);
  const float* wl = set ? w2l : w1l;
  const float* wr = set ? w2r : w1r;
  float w = (k < 128) ? wl[n * 128 + k] : wr[n * 128 + (k - 128)];
  unsigned hb = bf16rne(w);
  float hif = __uint_as_float(hb << 16);
  unsigned lb = bf16rne(w - hif);
  whiF[id] = (short)hb;
  wloF[id] = (short)lb;
}

// ---------------- per-graph CSR-in-LDS neighbor mean prep -----------------
__global__ __launch_bounds__(1024) void k_aggregate(
    const int* __restrict__ src, const int* __restrict__ dst,
    const float* __restrict__ x, float* __restrict__ s_out,
    float* __restrict__ c_out, int npg)
{
  __shared__ int cnt[1024];
  __shared__ int sc[1024];
  __shared__ int cur[1024];
  __shared__ int elist[EPG];
  const int t = threadIdx.x;
  const int g = blockIdx.x;
  const int nodeBase = g * npg;
  const int e0 = g * EPG;
  cnt[t] = 0;
  __syncthreads();
  for (int e = e0 + t; e < e0 + EPG; e += 1024) {
    int sv = src[e];
    if (sv >= 0) atomicAdd(&cnt[dst[e] - nodeBase], 1);
  }
  __syncthreads();
  int cv = cnt[t];
  sc[t] = cv;
  __syncthreads();
  for (int d = 1; d < 1024; d <<= 1) {
    int add = (t >= d) ? sc[t - d] : 0;
    __syncthreads();
    sc[t] += add;
    __syncthreads();
  }
  cur[t] = sc[t] - cv;
  __syncthreads();
  for (int e = e0 + t; e < e0 + EPG; e += 1024) {
    int sv = src[e];
    if (sv >= 0) {
      int pos = atomicAdd(&cur[dst[e] - nodeBase], 1);
      elist[pos] = sv;
    }
  }
  __syncthreads();
  const int lane = t & 31, grp = t >> 5;
  for (int v = grp; v < npg; v += 32) {
    int cn = cnt[v];
    int beg = sc[v] - cn;
    float4 acc = {0.f, 0.f, 0.f, 0.f};
    for (int e2 = 0; e2 < cn; ++e2) {
      int svg = elist[beg + e2];
      float4 xv = ((const float4*)(x + (size_t)svg * DIM))[lane];
      acc.x += xv.x; acc.y += xv.y; acc.z += xv.z; acc.w += xv.w;
    }
    int vg = nodeBase + v;
    ((float4*)(s_out + (size_t)vg * DIM))[lane] = acc;
    if (lane == 0) c_out[vg] = (float)cn;
  }
}

// ------- MFMA SAGE layer: h = relu([s*invc | x] @ W + bl), fused score ----
// 64 rows/block, 4 waves x 16 rows; in-place over s; also writes score.
__global__ __launch_bounds__(256) void k_gemm_mfma(
    const float* __restrict__ x, float* __restrict__ s, const float* __restrict__ c,
    const short* __restrict__ whiF, const short* __restrict__ wloF,
    const float* __restrict__ bl, const float* __restrict__ pw,
    float* __restrict__ score)
{
  const int t = threadIdx.x;
  const int wv = t >> 6, l = t & 63;
  const int rowbase = blockIdx.x * 64 + wv * 16;
  const int lrow = l & 15, lk = l >> 4;      // lk 0..3
  const int row = rowbase + lrow;
  const float invc = 1.0f / fmaxf(c[row], 1.0f);
  f32x4 acc[8];
  #pragma unroll
  for (int nt = 0; nt < 8; ++nt) acc[nt] = (f32x4){0.f, 0.f, 0.f, 0.f};
  const float* srow = s + (size_t)row * DIM + lk * 8;
  const float* xrow = x + (size_t)row * DIM + lk * 8;
  const short8v* bh = (const short8v*)whiF;
  const short8v* bo = (const short8v*)wloF;

  #pragma unroll
  for (int kk = 0; kk < 8; ++kk) {
    const float* ap = (kk < 4) ? (srow + kk * 32) : (xrow + (kk - 4) * 32);
    float4 a0 = *(const float4*)ap;
    float4 a1 = *(const float4*)(ap + 4);
    float scl = (kk < 4) ? invc : 1.0f;
    float av[8] = { a0.x * scl, a0.y * scl, a0.z * scl, a0.w * scl,
                    a1.x * scl, a1.y * scl, a1.z * scl, a1.w * scl };
    short8v ahi, alo;
    #pragma unroll
    for (int j = 0; j < 8; ++j) {
      unsigned hb = bf16rne(av[j]);
      float hif = __uint_as_float(hb << 16);
      ahi[j] = (short)hb;
      alo[j] = (short)bf16rne(av[j] - hif);
    }
    #pragma unroll
    for (int nt = 0; nt < 8; ++nt) {
      int fi = (kk * 8 + nt) * 64 + l;
      short8v bhi = bh[fi];
      short8v blo = bo[fi];
      acc[nt] = __builtin_amdgcn_mfma_f32_16x16x32_bf16(ahi, bhi, acc[nt], 0, 0, 0);
      acc[nt] = __builtin_amdgcn_mfma_f32_16x16x32_bf16(alo, bhi, acc[nt], 0, 0, 0);
      acc[nt] = __builtin_amdgcn_mfma_f32_16x16x32_bf16(ahi, blo, acc[nt], 0, 0, 0);
    }
  }

  // epilogue: bias + relu + in-place store + fused pool-score partials
  float sp0 = 0.f, sp1 = 0.f, sp2 = 0.f, sp3 = 0.f;
  const int mb = rowbase + lk * 4;
  #pragma unroll
  for (int nt = 0; nt < 8; ++nt) {
    int col = nt * 16 + lrow;
    float bb = bl[col], pv = pw[col];
    float h0 = fmaxf(acc[nt][0] + bb, 0.f);
    float h1 = fmaxf(acc[nt][1] + bb, 0.f);
    float h2 = fmaxf(acc[nt][2] + bb, 0.f);
    float h3 = fmaxf(acc[nt][3] + bb, 0.f);
    s[(size_t)(mb + 0) * DIM + col] = h0;
    s[(size_t)(mb + 1) * DIM + col] = h1;
    s[(size_t)(mb + 2) * DIM + col] = h2;
    s[(size_t)(mb + 3) * DIM + col] = h3;
    sp0 += h0 * pv; sp1 += h1 * pv; sp2 += h2 * pv; sp3 += h3 * pv;
  }
  #pragma unroll
  for (int off = 1; off <= 8; off <<= 1) {
    sp0 += __shfl_xor(sp0, off);
    sp1 += __shfl_xor(sp1, off);
    sp2 += __shfl_xor(sp2, off);
    sp3 += __shfl_xor(sp3, off);
  }
  if (lrow == 0) {
    score[mb + 0] = sp0;
    score[mb + 1] = sp1;
    score[mb + 2] = sp2;
    score[mb + 3] = sp3;
  }
}

// ---------------- per-graph bitonic top-k ----------------
__global__ __launch_bounds__(1024) void k_topk(const float* __restrict__ score,
    const float* __restrict__ inv_norm_p, int npg, int k,
    int* __restrict__ new_id, int* __restrict__ sel_pos, float* __restrict__ sel_scale)
{
  __shared__ float key[1024];
  __shared__ int   idx[1024];
  const int t = threadIdx.x;
  const int b = blockIdx.x;
  const int base = b * npg;
  key[t] = (t < npg) ? score[base + t] : -3.402823466e38f;
  idx[t] = t;
  if (t < npg) new_id[base + t] = -1;
  __syncthreads();
  for (int size = 2; size <= 1024; size <<= 1) {
    for (int stride = size >> 1; stride > 0; stride >>= 1) {
      int p = t ^ stride;
      if (p > t) {
        float ka = key[t], kb = key[p];
        int ia = idx[t], ib = idx[p];
        bool a_first = (ka > kb) || (ka == kb && ia < ib);
        bool desc = ((t & size) == 0);
        if (desc ? !a_first : a_first) {
          key[t] = kb; key[p] = ka; idx[t] = ib; idx[p] = ia;
        }
      }
      __syncthreads();
    }
  }
  if (t < k) {
    float inv = *inv_norm_p;
    int local = idx[t];
    new_id[base + local] = b * k + t;
    sel_pos[b * k + t] = base + local;
    sel_scale[b * k + t] = tanhf(key[t] * inv);
  }
}

// ---------------- pooled x = h[sel] * tanh(val) ----------------
__global__ __launch_bounds__(256) void k_pool(const float* __restrict__ h,
    const int* __restrict__ sel_pos, const float* __restrict__ sel_scale,
    float* __restrict__ xo)
{
  int tid = blockIdx.x * 256 + threadIdx.x;
  int j = tid >> 5, lane = tid & 31;
  float scv = sel_scale[j];
  float4 v = ((const float4*)(h + (size_t)sel_pos[j] * DIM))[lane];
  v.x *= scv; v.y *= scv; v.z *= scv; v.w *= scv;
  ((float4*)(xo + (size_t)j * DIM))[lane] = v;
}

// ---------------- readout stage A: per-(graph,chunk) partial max/sum ------
__global__ __launch_bounds__(256) void k_readout_part(const float* __restrict__ x,
    int k, float* __restrict__ pmax, float* __restrict__ psum)
{
  __shared__ float smx[256], ssm[256];
  const int b  = blockIdx.x >> 4;        // graph
  const int ch = blockIdx.x & (RCHUNK - 1);
  const int rpc = (k + RCHUNK - 1) / RCHUNK;
  const int r0 = ch * rpc;
  const int r1 = min(k, r0 + rpc);
  const int d   = threadIdx.x & 127;
  const int sub = threadIdx.x >> 7;      // 0/1
  const float* xb = x + (size_t)b * k * DIM;
  float mx = -3.402823466e38f, sm = 0.f;
  for (int r = r0 + sub; r < r1; r += 2) {
    float v = xb[(size_t)r * DIM + d];
    mx = fmaxf(mx, v);
    sm += v;
  }
  smx[threadIdx.x] = mx; ssm[threadIdx.x] = sm;
  __syncthreads();
  if (sub == 0) {
    mx = fmaxf(mx, smx[d + 128]);
    sm += ssm[d + 128];
    int o = (b * RCHUNK + ch) * 128 + d;
    pmax[o] = mx; psum[o] = sm;
  }
}

// ------- readout stage B: combine partials, accumulate TRANSPOSED rdT -----
__global__ __launch_bounds__(128) void k_readout_final(const float* __restrict__ pmax,
    const float* __restrict__ psum, int k, float* __restrict__ rdT, int add)
{
  int b = blockIdx.x, d = threadIdx.x;
  float mx = -3.402823466e38f, sm = 0.f;
  #pragma unroll
  for (int c = 0; c < RCHUNK; ++c) {
    int o = (b * RCHUNK + c) * 128 + d;
    mx = fmaxf(mx, pmax[o]);
    sm += psum[o];
  }
  float mean = sm / (float)k;
  int omx = d * 64 + b;
  int omn = (128 + d) * 64 + b;
  if (add) { rdT[omx] += mx; rdT[omn] += mean; }
  else     { rdT[omx]  = mx; rdT[omn]  = mean; }
}

// ---------------- relabel edges through new_id ----------------
__global__ __launch_bounds__(256) void k_relabel(const int* __restrict__ new_id,
    int* __restrict__ src, int* __restrict__ dst)
{
  int e = blockIdx.x * 256 + threadIdx.x;
  int sv = src[e];
  if (sv < 0) return;
  int dv = dst[e];
  int ns = new_id[sv], nd = new_id[dv];
  if (ns < 0 || nd < 0) { src[e] = -1; }
  else { src[e] = ns; dst[e] = nd; }
}

// ---------------- fused MLP: lane = graph, wave = feature group -----------
__global__ __launch_bounds__(1024) void k_mlp(const float* __restrict__ rdT,
    const float* __restrict__ fc1_w, const float* __restrict__ fc1_b,
    const float* __restrict__ g1, const float* __restrict__ be1,
    const float* __restrict__ fc2_w, const float* __restrict__ fc2_b,
    const float* __restrict__ g2, const float* __restrict__ be2,
    const float* __restrict__ lin_w, const float* __restrict__ lin_b,
    float* __restrict__ out)
{
  __shared__ float y1T[128 * 64];   // [feature][graph]
  __shared__ float part[16 * 64];
  const int t = threadIdx.x;
  const int g = t & 63;             // graph = lane
  const int w = t >> 6;             // wave 0..15

  float acc[8];
  #pragma unroll
  for (int j = 0; j < 8; ++j) acc[j] = 0.f;
  const float* wr[8];
  #pragma unroll
  for (int j = 0; j < 8; ++j) wr[j] = fc1_w + (size_t)(w * 8 + j) * 256;
  for (int k = 0; k < 256; ++k) {
    float rv = rdT[k * 64 + g];
    #pragma unroll
    for (int j = 0; j < 8; ++j) acc[j] += rv * wr[j][k];
  }
  #pragma unroll
  for (int j = 0; j < 8; ++j) {
    int f = w * 8 + j;
    float y = acc[j] + fc1_b[f];
    float s = y, s2 = y * y;
    #pragma unroll
    for (int off = 32; off; off >>= 1) {
      s  += __shfl_xor(s,  off);
      s2 += __shfl_xor(s2, off);
    }
    float mu = s * 0.015625f;
    float var = s2 * 0.015625f - mu * mu;
    float inv = 1.0f / sqrtf(var + 1e-5f);
    float yn = fmaxf((y - mu) * inv * g1[f] + be1[f], 0.f);
    y1T[f * 64 + g] = yn;
  }
  __syncthreads();

  float acc2[4];
  #pragma unroll
  for (int j = 0; j < 4; ++j) acc2[j] = 0.f;
  const float* wr2[4];
  #pragma unroll
  for (int j = 0; j < 4; ++j) wr2[j] = fc2_w + (size_t)(w * 4 + j) * 128;
  for (int k = 0; k < 128; ++k) {
    float yv = y1T[k * 64 + g];
    #pragma unroll
    for (int j = 0; j < 4; ++j) acc2[j] += yv * wr2[j][k];
  }
  float y2n[4];
  #pragma unroll
  for (int j = 0; j < 4; ++j) {
    int m = w * 4 + j;
    float y = acc2[j] + fc2_b[m];
    float s = y, s2 = y * y;
    #pragma unroll
    for (int off = 32; off; off >>= 1) {
      s  += __shfl_xor(s,  off);
      s2 += __shfl_xor(s2, off);
    }
    float mu = s * 0.015625f;
    float var = s2 * 0.015625f - mu * mu;
    float inv = 1.0f / sqrtf(var + 1e-5f);
    y2n[j] = fmaxf((y - mu) * inv * g2[m] + be2[m], 0.f);
  }

  float pp = 0.f;
  #pragma unroll
  for (int j = 0; j < 4; ++j) pp += y2n[j] * lin_w[w * 4 + j];
  part[w * 64 + g] = pp;
  __syncthreads();
  if (w == 0) {
    float a = lin_b[0];
    #pragma unroll
    for (int c = 0; c < 16; ++c) a += part[c * 64 + g];
    out[g] = 1.0f / (1.0f + expf(-a));
  }
}

extern "C" void kernel_launch(void* const* d_in, const int* in_sizes, int n_in,
                              void* d_out, int out_size, void* d_ws, size_t ws_size,
                              hipStream_t stream) {
  const int*   node_idx = (const int*)  d_in[0];
  const int*   edge_idx = (const int*)  d_in[1];
  const float* emb      = (const float*)d_in[2];
  const float* w1l      = (const float*)d_in[3];
  const float* b1l      = (const float*)d_in[4];
  const float* w1r      = (const float*)d_in[5];
  const float* pool_w   = (const float*)d_in[6];
  const float* w2l      = (const float*)d_in[7];
  const float* b2l      = (const float*)d_in[8];
  const float* w2r      = (const float*)d_in[9];
  const float* fc1_w    = (const float*)d_in[10];
  const float* fc1_b    = (const float*)d_in[11];
  const float* bn1_g    = (const float*)d_in[12];
  const float* bn1_b    = (const float*)d_in[13];
  const float* fc2_w    = (const float*)d_in[14];
  const float* fc2_b    = (const float*)d_in[15];
  const float* bn2_g    = (const float*)d_in[16];
  const float* bn2_b    = (const float*)d_in[17];
  const float* lin_w    = (const float*)d_in[18];
  const float* lin_b    = (const float*)d_in[19];
  float* out = (float*)d_out;

  char* p = (char*)d_ws;
  auto alloc = [&](size_t bytes) -> void* {
    void* r = (void*)p;
    p += (bytes + 255) & ~(size_t)255;
    return r;
  };
  float* x_cur     = (float*)alloc((size_t)NNODE * DIM * 4);
  float* s_buf     = (float*)alloc((size_t)NNODE * DIM * 4);
  float* c_buf     = (float*)alloc((size_t)NNODE * 4);
  float* score     = (float*)alloc((size_t)NNODE * 4);
  int*   new_id    = (int*)  alloc((size_t)NNODE * 4);
  int*   sel_pos   = (int*)  alloc((size_t)NGRAPH * 820 * 4);
  float* sel_scale = (float*)alloc((size_t)NGRAPH * 820 * 4);
  int*   src_cur   = (int*)  alloc((size_t)NEDGE * 4);
  int*   dst_cur   = (int*)  alloc((size_t)NEDGE * 4);
  float* rdT       = (float*)alloc((size_t)256 * 64 * 4);
  short* whiF      = (short*)alloc((size_t)2 * 32768 * 2);
  short* wloF      = (short*)alloc((size_t)2 * 32768 * 2);
  float* pmax      = (float*)alloc((size_t)NGRAPH * RCHUNK * 128 * 4);
  float* psum      = (float*)alloc((size_t)NGRAPH * RCHUNK * 128 * 4);
  float* inv_norm  = (float*)alloc(256);

  k_gather<<<NNODE * 32 / 256, 256, 0, stream>>>(emb, node_idx, x_cur);
  k_edges_init<<<NEDGE / 256, 256, 0, stream>>>(edge_idx, src_cur, dst_cur);
  k_norm<<<1, 64, 0, stream>>>(pool_w, inv_norm);
  k_prep_wfrag<<<256, 256, 0, stream>>>(w1l, w1r, w2l, w2r, whiF, wloF);

  const int Ks[3] = {820, 656, 525};
  int npg = NPG0;
  for (int stage = 0; stage < 3; ++stage) {
    const short* whi_s = whiF + (stage ? 32768 : 0);
    const short* wlo_s = wloF + (stage ? 32768 : 0);
    const float* bl    = stage ? b2l : b1l;
    int n = NGRAPH * npg;
    int k = Ks[stage];

    k_aggregate<<<NGRAPH, 1024, 0, stream>>>(src_cur, dst_cur, x_cur, s_buf, c_buf, npg);
    k_gemm_mfma<<<n / 64, 256, 0, stream>>>(x_cur, s_buf, c_buf, whi_s, wlo_s,
                                            bl, pool_w, score);
    k_topk<<<NGRAPH, 1024, 0, stream>>>(score, inv_norm, npg, k, new_id, sel_pos, sel_scale);
    k_pool<<<NGRAPH * k / 8, 256, 0, stream>>>(s_buf, sel_pos, sel_scale, x_cur);
    k_readout_part<<<NGRAPH * RCHUNK, 256, 0, stream>>>(x_cur, k, pmax, psum);
    k_readout_final<<<NGRAPH, 128, 0, stream>>>(pmax, psum, k, rdT, stage == 0 ? 0 : 1);
    if (stage < 2)
      k_relabel<<<NEDGE / 256, 256, 0, stream>>>(new_id, src_cur, dst_cur);
    npg = k;
  }

  k_mlp<<<1, 1024, 0, stream>>>(rdT, fc1_w, fc1_b, bn1_g, bn1_b,
                                fc2_w, fc2_b, bn2_g, bn2_b, lin_w, lin_b, out);
}

// Round 5
// 374.954 us; speedup vs baseline: 3.3270x; 1.3564x over previous
//
#include <hip/hip_runtime.h>
#include <hip/hip_bf16.h>
#include <cstdint>
#include <cstddef>

#define NGRAPH 64
#define NPG0   1024
#define NNODE  65536     // NGRAPH*NPG0
#define NEDGE  524288
#define EPG    8192      // NEDGE/NGRAPH
#define DIM    128
#define RCHUNK 16        // readout partial chunks per graph

typedef __attribute__((ext_vector_type(8))) short short8v;   // 8 bf16
typedef __attribute__((ext_vector_type(4))) float f32x4;

__device__ __forceinline__ unsigned bf16rne(float f) {
  unsigned u = __float_as_uint(f);
  return (u + 0x7FFFu + ((u >> 16) & 1u)) >> 16;
}

// ---------------- gather x = emb[node_idx] ----------------
__global__ __launch_bounds__(256) void k_gather(const float* __restrict__ emb,
    const int* __restrict__ nid, float* __restrict__ x)
{
  int tid = blockIdx.x * 256 + threadIdx.x;
  int i = tid >> 5, lane = tid & 31;
  int row = nid[i];
  ((float4*)(x + (size_t)i * DIM))[lane] =
      ((const float4*)(emb + (size_t)row * DIM))[lane];
}

// ---------------- copy edges to mutable ws ----------------
__global__ __launch_bounds__(256) void k_edges_init(const int* __restrict__ ei,
    int* __restrict__ src, int* __restrict__ dst)
{
  int e = blockIdx.x * 256 + threadIdx.x;
  src[e] = ei[e];
  dst[e] = ei[NEDGE + e];
}

// ---------------- 1/||pool_w|| ----------------
__global__ __launch_bounds__(64) void k_norm(const float* __restrict__ pw,
    float* __restrict__ inv_norm)
{
  int t = threadIdx.x;
  float a = pw[t], b = pw[t + 64];
  float v = a * a + b * b;
  for (int off = 32; off; off >>= 1) v += __shfl_xor(v, off);
  if (t == 0) *inv_norm = 1.0f / sqrtf(v);
}

// ------- pre-swizzle weights into MFMA B-fragment layout, bf16 hi/lo ------
__global__ __launch_bounds__(256) void k_prep_wfrag(
    const float* __restrict__ w1l, const float* __restrict__ w1r,
    const float* __restrict__ w2l, const float* __restrict__ w2r,
    short* __restrict__ whiF, short* __restrict__ wloF)
{
  int id = blockIdx.x * 256 + threadIdx.x;    // 0..65535 (2 sets x 32768)
  int set = id >> 15;
  int r = id & 32767;
  int j  = r & 7;
  int l  = (r >> 3) & 63;
  int nt = (r >> 9) & 7;
  int kk = r >> 12;
  int k = kk * 32 + ((l >> 4) & 3) * 8 + j;
  int n = nt * 16 + (l & 15);
  const float* wl = set ? w2l : w1l;
  const float* wr = set ? w2r : w1r;
  float w = (k < 128) ? wl[n * 128 + k] : wr[n * 128 + (k - 128)];
  unsigned hb = bf16rne(w);
  float hif = __uint_as_float(hb << 16);
  unsigned lb = bf16rne(w - hif);
  whiF[id] = (short)hb;
  wloF[id] = (short)lb;
}

// ---------------- per-graph CSR build (to global), counts, offsets --------
__global__ __launch_bounds__(1024) void k_csr(
    const int* __restrict__ src, const int* __restrict__ dst, int npg,
    int* __restrict__ off_g, int* __restrict__ elist_g, float* __restrict__ c_out)
{
  __shared__ int cnt[1024];
  __shared__ int cur[1024];
  __shared__ int wsum[16];
  const int t = threadIdx.x, g = blockIdx.x;
  const int nodeBase = g * npg;
  const int e0 = g * EPG;
  cnt[t] = 0;
  __syncthreads();
  for (int e = e0 + t; e < e0 + EPG; e += 1024) {
    int sv = src[e];
    if (sv >= 0) atomicAdd(&cnt[dst[e] - nodeBase], 1);
  }
  __syncthreads();
  const int lane = t & 63, w = t >> 6;
  int cv = (t < npg) ? cnt[t] : 0;
  // intra-wave inclusive scan
  int x = cv;
  #pragma unroll
  for (int off = 1; off < 64; off <<= 1) {
    int y = __shfl_up(x, off);
    if (lane >= off) x += y;
  }
  if (lane == 63) wsum[w] = x;
  __syncthreads();
  if (t < 16) {
    int v = wsum[t];
    #pragma unroll
    for (int off = 1; off < 16; off <<= 1) {
      int y = __shfl_up(v, off);
      if (t >= off) v += y;
    }
    wsum[t] = v;
  }
  __syncthreads();
  int incl = x + (w ? wsum[w - 1] : 0);
  int excl = incl - cv;
  cur[t] = excl;
  int* offp = off_g + g * 1025;
  offp[t] = excl;
  if (t == 1023) offp[1024] = incl;
  if (t < npg) c_out[nodeBase + t] = (float)cv;
  __syncthreads();
  int* elp = elist_g + g * EPG;
  for (int e = e0 + t; e < e0 + EPG; e += 1024) {
    int sv = src[e];
    if (sv >= 0) {
      int pos = atomicAdd(&cur[dst[e] - nodeBase], 1);
      elp[pos] = sv;
    }
  }
}

// ------- gather+sum: 4 blocks per graph, each owns a feature quarter ------
// blockIdx = qf*64 + g  (all 4 blocks of graph g share blockIdx%8 -> XCD)
__global__ __launch_bounds__(1024) void k_gather_agg(
    const int* __restrict__ off_g, const int* __restrict__ elist_g,
    const float* __restrict__ x, float* __restrict__ s_out, int npg)
{
  const int g  = blockIdx.x & 63;
  const int qf = blockIdx.x >> 6;        // 0..3
  const int t = threadIdx.x;
  const int gr = t >> 3;                 // 128 groups
  const int lane8 = t & 7;
  const int fo = qf * 8 + lane8;         // float4 index within row
  const int npgr = (npg + 127) >> 7;
  const int nodeBase = g * npg;
  const int* off = off_g + g * 1025;
  const int* el  = elist_g + g * EPG;
  int v0 = gr * npgr;
  int v1 = min(npg, v0 + npgr);
  for (int v = v0; v < v1; ++v) {
    int e   = off[v];
    int end = off[v + 1];
    float4 acc = {0.f, 0.f, 0.f, 0.f};
    for (; e + 1 < end; e += 2) {
      int s0 = el[e], s1 = el[e + 1];
      float4 a = ((const float4*)(x + (size_t)s0 * DIM))[fo];
      float4 b = ((const float4*)(x + (size_t)s1 * DIM))[fo];
      acc.x += a.x + b.x; acc.y += a.y + b.y;
      acc.z += a.z + b.z; acc.w += a.w + b.w;
    }
    if (e < end) {
      float4 a = ((const float4*)(x + (size_t)el[e] * DIM))[fo];
      acc.x += a.x; acc.y += a.y; acc.z += a.z; acc.w += a.w;
    }
    ((float4*)(s_out + (size_t)(nodeBase + v) * DIM))[fo] = acc;
  }
}

// ------- MFMA SAGE layer: h = relu([s*invc | x] @ W + bl), fused score ----
__global__ __launch_bounds__(256) void k_gemm_mfma(
    const float* __restrict__ x, float* __restrict__ s, const float* __restrict__ c,
    const short* __restrict__ whiF, const short* __restrict__ wloF,
    const float* __restrict__ bl, const float* __restrict__ pw,
    float* __restrict__ score)
{
  const int t = threadIdx.x;
  const int wv = t >> 6, l = t & 63;
  const int rowbase = blockIdx.x * 64 + wv * 16;
  const int lrow = l & 15, lk = l >> 4;      // lk 0..3
  const int row = rowbase + lrow;
  const float invc = 1.0f / fmaxf(c[row], 1.0f);
  f32x4 acc[8];
  #pragma unroll
  for (int nt = 0; nt < 8; ++nt) acc[nt] = (f32x4){0.f, 0.f, 0.f, 0.f};
  const float* srow = s + (size_t)row * DIM + lk * 8;
  const float* xrow = x + (size_t)row * DIM + lk * 8;
  const short8v* bh = (const short8v*)whiF;
  const short8v* bo = (const short8v*)wloF;

  #pragma unroll
  for (int kk = 0; kk < 8; ++kk) {
    const float* ap = (kk < 4) ? (srow + kk * 32) : (xrow + (kk - 4) * 32);
    float4 a0 = *(const float4*)ap;
    float4 a1 = *(const float4*)(ap + 4);
    float scl = (kk < 4) ? invc : 1.0f;
    float av[8] = { a0.x * scl, a0.y * scl, a0.z * scl, a0.w * scl,
                    a1.x * scl, a1.y * scl, a1.z * scl, a1.w * scl };
    short8v ahi, alo;
    #pragma unroll
    for (int j = 0; j < 8; ++j) {
      unsigned hb = bf16rne(av[j]);
      float hif = __uint_as_float(hb << 16);
      ahi[j] = (short)hb;
      alo[j] = (short)bf16rne(av[j] - hif);
    }
    #pragma unroll
    for (int nt = 0; nt < 8; ++nt) {
      int fi = (kk * 8 + nt) * 64 + l;
      short8v bhi = bh[fi];
      short8v blo = bo[fi];
      acc[nt] = __builtin_amdgcn_mfma_f32_16x16x32_bf16(ahi, bhi, acc[nt], 0, 0, 0);
      acc[nt] = __builtin_amdgcn_mfma_f32_16x16x32_bf16(alo, bhi, acc[nt], 0, 0, 0);
      acc[nt] = __builtin_amdgcn_mfma_f32_16x16x32_bf16(ahi, blo, acc[nt], 0, 0, 0);
    }
  }

  float sp0 = 0.f, sp1 = 0.f, sp2 = 0.f, sp3 = 0.f;
  const int mb = rowbase + lk * 4;
  #pragma unroll
  for (int nt = 0; nt < 8; ++nt) {
    int col = nt * 16 + lrow;
    float bb = bl[col], pv = pw[col];
    float h0 = fmaxf(acc[nt][0] + bb, 0.f);
    float h1 = fmaxf(acc[nt][1] + bb, 0.f);
    float h2 = fmaxf(acc[nt][2] + bb, 0.f);
    float h3 = fmaxf(acc[nt][3] + bb, 0.f);
    s[(size_t)(mb + 0) * DIM + col] = h0;
    s[(size_t)(mb + 1) * DIM + col] = h1;
    s[(size_t)(mb + 2) * DIM + col] = h2;
    s[(size_t)(mb + 3) * DIM + col] = h3;
    sp0 += h0 * pv; sp1 += h1 * pv; sp2 += h2 * pv; sp3 += h3 * pv;
  }
  #pragma unroll
  for (int off = 1; off <= 8; off <<= 1) {
    sp0 += __shfl_xor(sp0, off);
    sp1 += __shfl_xor(sp1, off);
    sp2 += __shfl_xor(sp2, off);
    sp3 += __shfl_xor(sp3, off);
  }
  if (lrow == 0) {
    score[mb + 0] = sp0;
    score[mb + 1] = sp1;
    score[mb + 2] = sp2;
    score[mb + 3] = sp3;
  }
}

// ---------------- per-graph bitonic top-k ----------------
__global__ __launch_bounds__(1024) void k_topk(const float* __restrict__ score,
    const float* __restrict__ inv_norm_p, int npg, int k,
    int* __restrict__ new_id, int* __restrict__ sel_pos, float* __restrict__ sel_scale)
{
  __shared__ float key[1024];
  __shared__ int   idx[1024];
  const int t = threadIdx.x;
  const int b = blockIdx.x;
  const int base = b * npg;
  key[t] = (t < npg) ? score[base + t] : -3.402823466e38f;
  idx[t] = t;
  if (t < npg) new_id[base + t] = -1;
  __syncthreads();
  for (int size = 2; size <= 1024; size <<= 1) {
    for (int stride = size >> 1; stride > 0; stride >>= 1) {
      int p = t ^ stride;
      if (p > t) {
        float ka = key[t], kb = key[p];
        int ia = idx[t], ib = idx[p];
        bool a_first = (ka > kb) || (ka == kb && ia < ib);
        bool desc = ((t & size) == 0);
        if (desc ? !a_first : a_first) {
          key[t] = kb; key[p] = ka; idx[t] = ib; idx[p] = ia;
        }
      }
      __syncthreads();
    }
  }
  if (t < k) {
    float inv = *inv_norm_p;
    int local = idx[t];
    new_id[base + local] = b * k + t;
    sel_pos[b * k + t] = base + local;
    sel_scale[b * k + t] = tanhf(key[t] * inv);
  }
}

// ---------------- pooled x = h[sel] * tanh(val) ----------------
__global__ __launch_bounds__(256) void k_pool(const float* __restrict__ h,
    const int* __restrict__ sel_pos, const float* __restrict__ sel_scale,
    float* __restrict__ xo)
{
  int tid = blockIdx.x * 256 + threadIdx.x;
  int j = tid >> 5, lane = tid & 31;
  float scv = sel_scale[j];
  float4 v = ((const float4*)(h + (size_t)sel_pos[j] * DIM))[lane];
  v.x *= scv; v.y *= scv; v.z *= scv; v.w *= scv;
  ((float4*)(xo + (size_t)j * DIM))[lane] = v;
}

// ---------------- readout stage A: per-(graph,chunk) partial max/sum ------
__global__ __launch_bounds__(256) void k_readout_part(const float* __restrict__ x,
    int k, float* __restrict__ pmax, float* __restrict__ psum)
{
  __shared__ float smx[256], ssm[256];
  const int b  = blockIdx.x >> 4;        // graph
  const int ch = blockIdx.x & (RCHUNK - 1);
  const int rpc = (k + RCHUNK - 1) / RCHUNK;
  const int r0 = ch * rpc;
  const int r1 = min(k, r0 + rpc);
  const int d   = threadIdx.x & 127;
  const int sub = threadIdx.x >> 7;      // 0/1
  const float* xb = x + (size_t)b * k * DIM;
  float mx = -3.402823466e38f, sm = 0.f;
  for (int r = r0 + sub; r < r1; r += 2) {
    float v = xb[(size_t)r * DIM + d];
    mx = fmaxf(mx, v);
    sm += v;
  }
  smx[threadIdx.x] = mx; ssm[threadIdx.x] = sm;
  __syncthreads();
  if (sub == 0) {
    mx = fmaxf(mx, smx[d + 128]);
    sm += ssm[d + 128];
    int o = (b * RCHUNK + ch) * 128 + d;
    pmax[o] = mx; psum[o] = sm;
  }
}

// ------- readout stage B: combine partials, accumulate TRANSPOSED rdT -----
__global__ __launch_bounds__(128) void k_readout_final(const float* __restrict__ pmax,
    const float* __restrict__ psum, int k, float* __restrict__ rdT, int add)
{
  int b = blockIdx.x, d = threadIdx.x;
  float mx = -3.402823466e38f, sm = 0.f;
  #pragma unroll
  for (int c = 0; c < RCHUNK; ++c) {
    int o = (b * RCHUNK + c) * 128 + d;
    mx = fmaxf(mx, pmax[o]);
    sm += psum[o];
  }
  float mean = sm / (float)k;
  int omx = d * 64 + b;
  int omn = (128 + d) * 64 + b;
  if (add) { rdT[omx] += mx; rdT[omn] += mean; }
  else     { rdT[omx]  = mx; rdT[omn]  = mean; }
}

// ---------------- relabel edges through new_id ----------------
__global__ __launch_bounds__(256) void k_relabel(const int* __restrict__ new_id,
    int* __restrict__ src, int* __restrict__ dst)
{
  int e = blockIdx.x * 256 + threadIdx.x;
  int sv = src[e];
  if (sv < 0) return;
  int dv = dst[e];
  int ns = new_id[sv], nd = new_id[dv];
  if (ns < 0 || nd < 0) { src[e] = -1; }
  else { src[e] = ns; dst[e] = nd; }
}

// ------- MLP fc1 + BN1 + relu: 16 blocks, lane=graph, wave=feature --------
__global__ __launch_bounds__(512) void k_mlp_fc1(const float* __restrict__ rdT,
    const float* __restrict__ fc1_w, const float* __restrict__ fc1_b,
    const float* __restrict__ g1, const float* __restrict__ be1,
    float* __restrict__ y1n)
{
  __shared__ float W[8 * 256];       // 8 KB
  __shared__ float R[256 * 64];      // 64 KB
  const int t = threadIdx.x, b = blockIdx.x;
  ((float4*)W)[t] = ((const float4*)(fc1_w + (size_t)b * 8 * 256))[t];
  #pragma unroll
  for (int i = 0; i < 8; ++i)
    ((float4*)R)[t + i * 512] = ((const float4*)rdT)[t + i * 512];
  __syncthreads();
  const int g = t & 63, w = t >> 6;  // 8 waves, one feature each
  const float* wrow = W + w * 256;
  float acc = 0.f;
  #pragma unroll 4
  for (int k = 0; k < 256; ++k) acc += R[k * 64 + g] * wrow[k];
  int f = b * 8 + w;
  float y = acc + fc1_b[f];
  float s = y, s2 = y * y;
  #pragma unroll
  for (int off = 32; off; off >>= 1) {
    s  += __shfl_xor(s,  off);
    s2 += __shfl_xor(s2, off);
  }
  float mu = s * 0.015625f;
  float var = s2 * 0.015625f - mu * mu;
  float inv = 1.0f / sqrtf(var + 1e-5f);
  y1n[f * 64 + g] = fmaxf((y - mu) * inv * g1[f] + be1[f], 0.f);
}

// ------- MLP rest: fc2 + BN2 + relu + lin + sigmoid (1 block) -------------
__global__ __launch_bounds__(1024) void k_mlp_rest(const float* __restrict__ y1n,
    const float* __restrict__ fc2_w, const float* __restrict__ fc2_b,
    const float* __restrict__ g2, const float* __restrict__ be2,
    const float* __restrict__ lin_w, const float* __restrict__ lin_b,
    float* __restrict__ out)
{
  __shared__ float W2[64 * 128];     // 32 KB
  __shared__ float Y[128 * 64];      // 32 KB
  __shared__ float part[16 * 64];    // 4 KB
  const int t = threadIdx.x;
  #pragma unroll
  for (int i = 0; i < 2; ++i) {
    ((float4*)W2)[t + i * 1024] = ((const float4*)fc2_w)[t + i * 1024];
    ((float4*)Y) [t + i * 1024] = ((const float4*)y1n)[t + i * 1024];
  }
  __syncthreads();
  const int g = t & 63, w = t >> 6;  // 16 waves x 4 features
  float acc2[4] = {0.f, 0.f, 0.f, 0.f};
  const float* w20 = W2 + (w * 4 + 0) * 128;
  const float* w21 = W2 + (w * 4 + 1) * 128;
  const float* w22 = W2 + (w * 4 + 2) * 128;
  const float* w23 = W2 + (w * 4 + 3) * 128;
  #pragma unroll 4
  for (int k = 0; k < 128; ++k) {
    float yv = Y[k * 64 + g];
    acc2[0] += yv * w20[k];
    acc2[1] += yv * w21[k];
    acc2[2] += yv * w22[k];
    acc2[3] += yv * w23[k];
  }
  float pp = 0.f;
  #pragma unroll
  for (int j = 0; j < 4; ++j) {
    int m = w * 4 + j;
    float y = acc2[j] + fc2_b[m];
    float s = y, s2 = y * y;
    #pragma unroll
    for (int off = 32; off; off >>= 1) {
      s  += __shfl_xor(s,  off);
      s2 += __shfl_xor(s2, off);
    }
    float mu = s * 0.015625f;
    float var = s2 * 0.015625f - mu * mu;
    float inv = 1.0f / sqrtf(var + 1e-5f);
    float yn = fmaxf((y - mu) * inv * g2[m] + be2[m], 0.f);
    pp += yn * lin_w[m];
  }
  part[w * 64 + g] = pp;
  __syncthreads();
  if (w == 0) {
    float a = lin_b[0];
    #pragma unroll
    for (int c = 0; c < 16; ++c) a += part[c * 64 + g];
    out[g] = 1.0f / (1.0f + expf(-a));
  }
}

extern "C" void kernel_launch(void* const* d_in, const int* in_sizes, int n_in,
                              void* d_out, int out_size, void* d_ws, size_t ws_size,
                              hipStream_t stream) {
  const int*   node_idx = (const int*)  d_in[0];
  const int*   edge_idx = (const int*)  d_in[1];
  const float* emb      = (const float*)d_in[2];
  const float* w1l      = (const float*)d_in[3];
  const float* b1l      = (const float*)d_in[4];
  const float* w1r      = (const float*)d_in[5];
  const float* pool_w   = (const float*)d_in[6];
  const float* w2l      = (const float*)d_in[7];
  const float* b2l      = (const float*)d_in[8];
  const float* w2r      = (const float*)d_in[9];
  const float* fc1_w    = (const float*)d_in[10];
  const float* fc1_b    = (const float*)d_in[11];
  const float* bn1_g    = (const float*)d_in[12];
  const float* bn1_b    = (const float*)d_in[13];
  const float* fc2_w    = (const float*)d_in[14];
  const float* fc2_b    = (const float*)d_in[15];
  const float* bn2_g    = (const float*)d_in[16];
  const float* bn2_b    = (const float*)d_in[17];
  const float* lin_w    = (const float*)d_in[18];
  const float* lin_b    = (const float*)d_in[19];
  float* out = (float*)d_out;

  char* p = (char*)d_ws;
  auto alloc = [&](size_t bytes) -> void* {
    void* r = (void*)p;
    p += (bytes + 255) & ~(size_t)255;
    return r;
  };
  float* x_cur     = (float*)alloc((size_t)NNODE * DIM * 4);
  float* s_buf     = (float*)alloc((size_t)NNODE * DIM * 4);
  float* c_buf     = (float*)alloc((size_t)NNODE * 4);
  float* score     = (float*)alloc((size_t)NNODE * 4);
  int*   new_id    = (int*)  alloc((size_t)NNODE * 4);
  int*   sel_pos   = (int*)  alloc((size_t)NGRAPH * 820 * 4);
  float* sel_scale = (float*)alloc((size_t)NGRAPH * 820 * 4);
  int*   src_cur   = (int*)  alloc((size_t)NEDGE * 4);
  int*   dst_cur   = (int*)  alloc((size_t)NEDGE * 4);
  int*   off_g     = (int*)  alloc((size_t)NGRAPH * 1025 * 4);
  int*   elist_g   = (int*)  alloc((size_t)NGRAPH * EPG * 4);
  float* rdT       = (float*)alloc((size_t)256 * 64 * 4);
  short* whiF      = (short*)alloc((size_t)2 * 32768 * 2);
  short* wloF      = (short*)alloc((size_t)2 * 32768 * 2);
  float* y1n       = (float*)alloc((size_t)128 * 64 * 4);
  float* pmax      = (float*)alloc((size_t)NGRAPH * RCHUNK * 128 * 4);
  float* psum      = (float*)alloc((size_t)NGRAPH * RCHUNK * 128 * 4);
  float* inv_norm  = (float*)alloc(256);

  k_gather<<<NNODE * 32 / 256, 256, 0, stream>>>(emb, node_idx, x_cur);
  k_edges_init<<<NEDGE / 256, 256, 0, stream>>>(edge_idx, src_cur, dst_cur);
  k_norm<<<1, 64, 0, stream>>>(pool_w, inv_norm);
  k_prep_wfrag<<<256, 256, 0, stream>>>(w1l, w1r, w2l, w2r, whiF, wloF);

  const int Ks[3] = {820, 656, 525};
  int npg = NPG0;
  for (int stage = 0; stage < 3; ++stage) {
    const short* whi_s = whiF + (stage ? 32768 : 0);
    const short* wlo_s = wloF + (stage ? 32768 : 0);
    const float* bl    = stage ? b2l : b1l;
    int n = NGRAPH * npg;
    int k = Ks[stage];

    k_csr<<<NGRAPH, 1024, 0, stream>>>(src_cur, dst_cur, npg, off_g, elist_g, c_buf);
    k_gather_agg<<<4 * NGRAPH, 1024, 0, stream>>>(off_g, elist_g, x_cur, s_buf, npg);
    k_gemm_mfma<<<n / 64, 256, 0, stream>>>(x_cur, s_buf, c_buf, whi_s, wlo_s,
                                            bl, pool_w, score);
    k_topk<<<NGRAPH, 1024, 0, stream>>>(score, inv_norm, npg, k, new_id, sel_pos, sel_scale);
    k_pool<<<NGRAPH * k / 8, 256, 0, stream>>>(s_buf, sel_pos, sel_scale, x_cur);
    k_readout_part<<<NGRAPH * RCHUNK, 256, 0, stream>>>(x_cur, k, pmax, psum);
    k_readout_final<<<NGRAPH, 128, 0, stream>>>(pmax, psum, k, rdT, stage == 0 ? 0 : 1);
    if (stage < 2)
      k_relabel<<<NEDGE / 256, 256, 0, stream>>>(new_id, src_cur, dst_cur);
    npg = k;
  }

  k_mlp_fc1<<<16, 512, 0, stream>>>(rdT, fc1_w, fc1_b, bn1_g, bn1_b, y1n);
  k_mlp_rest<<<1, 1024, 0, stream>>>(y1n, fc2_w, fc2_b, bn2_g, bn2_b,
                                     lin_w, lin_b, out);
}

// Round 6
// 338.460 us; speedup vs baseline: 3.6857x; 1.1078x over previous
//
#include <hip/hip_runtime.h>
#include <hip/hip_bf16.h>
#include <cstdint>
#include <cstddef>

#define NGRAPH 64
#define NPG0   1024
#define NNODE  65536     // NGRAPH*NPG0
#define NEDGE  524288
#define EPG    8192      // NEDGE/NGRAPH
#define DIM    128
#define RCHUNK 16        // readout partial chunks per graph

typedef __attribute__((ext_vector_type(8))) short short8v;   // 8 bf16
typedef __attribute__((ext_vector_type(4))) float f32x4;

__device__ __forceinline__ unsigned bf16rne(float f) {
  unsigned u = __float_as_uint(f);
  return (u + 0x7FFFu + ((u >> 16) & 1u)) >> 16;
}

// ---------------- gather x = emb[node_idx] ----------------
__global__ __launch_bounds__(256) void k_gather(const float* __restrict__ emb,
    const int* __restrict__ nid, float* __restrict__ x)
{
  int tid = blockIdx.x * 256 + threadIdx.x;
  int i = tid >> 5, lane = tid & 31;
  int row = nid[i];
  ((float4*)(x + (size_t)i * DIM))[lane] =
      ((const float4*)(emb + (size_t)row * DIM))[lane];
}

// ---------------- 1/||pool_w|| ----------------
__global__ __launch_bounds__(64) void k_norm(const float* __restrict__ pw,
    float* __restrict__ inv_norm)
{
  int t = threadIdx.x;
  float a = pw[t], b = pw[t + 64];
  float v = a * a + b * b;
  for (int off = 32; off; off >>= 1) v += __shfl_xor(v, off);
  if (t == 0) *inv_norm = 1.0f / sqrtf(v);
}

// ------- pre-swizzle weights into MFMA B-fragment layout, bf16 hi/lo ------
__global__ __launch_bounds__(256) void k_prep_wfrag(
    const float* __restrict__ w1l, const float* __restrict__ w1r,
    const float* __restrict__ w2l, const float* __restrict__ w2r,
    short* __restrict__ whiF, short* __restrict__ wloF)
{
  int id = blockIdx.x * 256 + threadIdx.x;    // 0..65535 (2 sets x 32768)
  int set = id >> 15;
  int r = id & 32767;
  int j  = r & 7;
  int l  = (r >> 3) & 63;
  int nt = (r >> 9) & 7;
  int kk = r >> 12;
  int k = kk * 32 + ((l >> 4) & 3) * 8 + j;
  int n = nt * 16 + (l & 15);
  const float* wl = set ? w2l : w1l;
  const float* wr = set ? w2r : w1r;
  float w = (k < 128) ? wl[n * 128 + k] : wr[n * 128 + (k - 128)];
  unsigned hb = bf16rne(w);
  float hif = __uint_as_float(hb << 16);
  unsigned lb = bf16rne(w - hif);
  whiF[id] = (short)hb;
  wloF[id] = (short)lb;
}

// ---------------- stage-0 CSR build straight from edge_idx ----------------
__global__ __launch_bounds__(1024) void k_csr0(const int* __restrict__ ei,
    int* __restrict__ off_g, int* __restrict__ elist_g, float* __restrict__ c_out)
{
  __shared__ int cnt[1024];
  __shared__ int cur[1024];
  __shared__ int wsum[16];
  const int t = threadIdx.x, g = blockIdx.x;
  const int nodeBase = g * NPG0;
  const int e0 = g * EPG;
  cnt[t] = 0;
  __syncthreads();
  int sv8[8], dl8[8];
  #pragma unroll
  for (int i = 0; i < 8; ++i) {
    int e = e0 + t + i * 1024;
    sv8[i] = ei[e];
    dl8[i] = ei[NEDGE + e] - nodeBase;
    atomicAdd(&cnt[dl8[i]], 1);
  }
  __syncthreads();
  const int lane = t & 63, w = t >> 6;
  int cv = cnt[t];
  int x = cv;
  #pragma unroll
  for (int off = 1; off < 64; off <<= 1) {
    int y = __shfl_up(x, off);
    if (lane >= off) x += y;
  }
  if (lane == 63) wsum[w] = x;
  __syncthreads();
  if (t < 16) {
    int v = wsum[t];
    #pragma unroll
    for (int off2 = 1; off2 < 16; off2 <<= 1) {
      int y = __shfl_up(v, off2);
      if (t >= off2) v += y;
    }
    wsum[t] = v;
  }
  __syncthreads();
  int incl = x + (w ? wsum[w - 1] : 0);
  int excl = incl - cv;
  cur[t] = excl;
  int* offp = off_g + g * 1025;
  offp[t] = excl;
  if (t == 1023) offp[1024] = incl;
  c_out[nodeBase + t] = (float)cv;
  __syncthreads();
  int* elp = elist_g + g * EPG;
  #pragma unroll
  for (int i = 0; i < 8; ++i) {
    int pos = atomicAdd(&cur[dl8[i]], 1);
    elp[pos] = sv8[i];
  }
}

// ------- gather+sum: 16 blocks/graph (feature quarter x node quarter) -----
// blockIdx = s*64 + g  (all blocks of graph g share blockIdx%8 -> same XCD)
__global__ __launch_bounds__(256) void k_gather_agg(
    const int* __restrict__ off_g, const int* __restrict__ elist_g,
    const float* __restrict__ x, float* __restrict__ s_out, int npg)
{
  const int g  = blockIdx.x & 63;
  const int sb = blockIdx.x >> 6;        // 0..15
  const int qf = sb & 3;                 // feature quarter
  const int qn = sb >> 2;                // node quarter
  const int t = threadIdx.x;
  const int gr = t >> 3;                 // 32 groups
  const int lane8 = t & 7;
  const int fo = qf * 8 + lane8;         // float4 index within row
  const int nq4 = (npg + 3) >> 2;
  const int vbase = qn * nq4;
  const int vend = min(npg, vbase + nq4);
  const int nodeBase = g * npg;
  const int* off = off_g + g * 1025;
  const int* el  = elist_g + g * EPG;
  const int nq = vend - vbase;
  const int per = (nq + 31) >> 5;
  int v0 = vbase + gr * per;
  int v1 = min(vend, v0 + per);
  for (int v = v0; v < v1; ++v) {
    int e   = off[v];
    int end = off[v + 1];
    float4 acc = {0.f, 0.f, 0.f, 0.f};
    for (; e + 4 <= end; e += 4) {
      int s0 = el[e], s1 = el[e + 1], s2 = el[e + 2], s3 = el[e + 3];
      float4 a = ((const float4*)(x + (size_t)s0 * DIM))[fo];
      float4 b = ((const float4*)(x + (size_t)s1 * DIM))[fo];
      float4 c4 = ((const float4*)(x + (size_t)s2 * DIM))[fo];
      float4 d4 = ((const float4*)(x + (size_t)s3 * DIM))[fo];
      acc.x += (a.x + b.x) + (c4.x + d4.x);
      acc.y += (a.y + b.y) + (c4.y + d4.y);
      acc.z += (a.z + b.z) + (c4.z + d4.z);
      acc.w += (a.w + b.w) + (c4.w + d4.w);
    }
    for (; e < end; ++e) {
      float4 a = ((const float4*)(x + (size_t)el[e] * DIM))[fo];
      acc.x += a.x; acc.y += a.y; acc.z += a.z; acc.w += a.w;
    }
    ((float4*)(s_out + (size_t)(nodeBase + v) * DIM))[fo] = acc;
  }
}

// ------- MFMA SAGE layer: h = relu([s*invc | x] @ W + bl), fused score ----
__global__ __launch_bounds__(256) void k_gemm_mfma(
    const float* __restrict__ x, float* __restrict__ s, const float* __restrict__ c,
    const short* __restrict__ whiF, const short* __restrict__ wloF,
    const float* __restrict__ bl, const float* __restrict__ pw,
    float* __restrict__ score)
{
  const int t = threadIdx.x;
  const int wv = t >> 6, l = t & 63;
  const int rowbase = blockIdx.x * 64 + wv * 16;
  const int lrow = l & 15, lk = l >> 4;      // lk 0..3
  const int row = rowbase + lrow;
  const float invc = 1.0f / fmaxf(c[row], 1.0f);
  f32x4 acc[8];
  #pragma unroll
  for (int nt = 0; nt < 8; ++nt) acc[nt] = (f32x4){0.f, 0.f, 0.f, 0.f};
  const float* srow = s + (size_t)row * DIM + lk * 8;
  const float* xrow = x + (size_t)row * DIM + lk * 8;
  const short8v* bh = (const short8v*)whiF;
  const short8v* bo = (const short8v*)wloF;

  #pragma unroll
  for (int kk = 0; kk < 8; ++kk) {
    const float* ap = (kk < 4) ? (srow + kk * 32) : (xrow + (kk - 4) * 32);
    float4 a0 = *(const float4*)ap;
    float4 a1 = *(const float4*)(ap + 4);
    float scl = (kk < 4) ? invc : 1.0f;
    float av[8] = { a0.x * scl, a0.y * scl, a0.z * scl, a0.w * scl,
                    a1.x * scl, a1.y * scl, a1.z * scl, a1.w * scl };
    short8v ahi, alo;
    #pragma unroll
    for (int j = 0; j < 8; ++j) {
      unsigned hb = bf16rne(av[j]);
      float hif = __uint_as_float(hb << 16);
      ahi[j] = (short)hb;
      alo[j] = (short)bf16rne(av[j] - hif);
    }
    #pragma unroll
    for (int nt = 0; nt < 8; ++nt) {
      int fi = (kk * 8 + nt) * 64 + l;
      short8v bhi = bh[fi];
      short8v blo = bo[fi];
      acc[nt] = __builtin_amdgcn_mfma_f32_16x16x32_bf16(ahi, bhi, acc[nt], 0, 0, 0);
      acc[nt] = __builtin_amdgcn_mfma_f32_16x16x32_bf16(alo, bhi, acc[nt], 0, 0, 0);
      acc[nt] = __builtin_amdgcn_mfma_f32_16x16x32_bf16(ahi, blo, acc[nt], 0, 0, 0);
    }
  }

  float sp0 = 0.f, sp1 = 0.f, sp2 = 0.f, sp3 = 0.f;
  const int mb = rowbase + lk * 4;
  #pragma unroll
  for (int nt = 0; nt < 8; ++nt) {
    int col = nt * 16 + lrow;
    float bb = bl[col], pv = pw[col];
    float h0 = fmaxf(acc[nt][0] + bb, 0.f);
    float h1 = fmaxf(acc[nt][1] + bb, 0.f);
    float h2 = fmaxf(acc[nt][2] + bb, 0.f);
    float h3 = fmaxf(acc[nt][3] + bb, 0.f);
    s[(size_t)(mb + 0) * DIM + col] = h0;
    s[(size_t)(mb + 1) * DIM + col] = h1;
    s[(size_t)(mb + 2) * DIM + col] = h2;
    s[(size_t)(mb + 3) * DIM + col] = h3;
    sp0 += h0 * pv; sp1 += h1 * pv; sp2 += h2 * pv; sp3 += h3 * pv;
  }
  #pragma unroll
  for (int off = 1; off <= 8; off <<= 1) {
    sp0 += __shfl_xor(sp0, off);
    sp1 += __shfl_xor(sp1, off);
    sp2 += __shfl_xor(sp2, off);
    sp3 += __shfl_xor(sp3, off);
  }
  if (lrow == 0) {
    score[mb + 0] = sp0;
    score[mb + 1] = sp1;
    score[mb + 2] = sp2;
    score[mb + 3] = sp3;
  }
}

// ------- fused: bitonic top-k + relabel edges + build next-stage CSR ------
__global__ __launch_bounds__(1024) void k_topk_fused(
    const float* __restrict__ score, const float* __restrict__ inv_norm_p,
    int npg, int k, int* __restrict__ sel_pos, float* __restrict__ sel_scale,
    int build_next, int write_eout,
    const int* __restrict__ ein_src, const int* __restrict__ ein_dst,
    int* __restrict__ eout_src, int* __restrict__ eout_dst,
    int* __restrict__ off_g, int* __restrict__ elist_g, float* __restrict__ c_out)
{
  __shared__ float key[1024];
  __shared__ int   idxs[1024];
  __shared__ int   nid[1024];
  __shared__ int   cnt[1024];
  __shared__ int   cur[1024];
  __shared__ int   wsum[16];
  const int t = threadIdx.x, g = blockIdx.x;
  const int base = g * npg;
  key[t] = (t < npg) ? score[base + t] : -3.402823466e38f;
  idxs[t] = t;
  nid[t] = -1;
  cnt[t] = 0;
  __syncthreads();
  for (int size = 2; size <= 1024; size <<= 1) {
    for (int stride = size >> 1; stride > 0; stride >>= 1) {
      int p = t ^ stride;
      if (p > t) {
        float ka = key[t], kb = key[p];
        int ia = idxs[t], ib = idxs[p];
        bool a_first = (ka > kb) || (ka == kb && ia < ib);
        bool desc = ((t & size) == 0);
        if (desc ? !a_first : a_first) {
          key[t] = kb; key[p] = ka; idxs[t] = ib; idxs[p] = ia;
        }
      }
      __syncthreads();
    }
  }
  if (t < k) {
    float inv = *inv_norm_p;
    int local = idxs[t];
    nid[local] = t;
    sel_pos[g * k + t] = base + local;
    sel_scale[g * k + t] = tanhf(key[t] * inv);
  }
  if (!build_next) return;
  __syncthreads();
  const int e0 = g * EPG;
  const int newBase = g * k;
  int lns[8], lnd[8];
  #pragma unroll
  for (int i = 0; i < 8; ++i) {
    int e = e0 + t + i * 1024;
    int sv = ein_src[e];
    int ns = -1, nd = -1;
    if (sv >= 0) {
      int dv = ein_dst[e];
      ns = nid[sv - base];
      nd = nid[dv - base];
      if (ns < 0 || nd < 0) ns = -1;
    }
    lns[i] = ns; lnd[i] = nd;
    if (write_eout) {
      eout_src[e] = (ns >= 0) ? (newBase + ns) : -1;
      eout_dst[e] = (ns >= 0) ? (newBase + nd) : -1;
    }
    if (ns >= 0) atomicAdd(&cnt[nd], 1);
  }
  __syncthreads();
  const int lane = t & 63, w = t >> 6;
  int cv = cnt[t];
  int x = cv;
  #pragma unroll
  for (int off = 1; off < 64; off <<= 1) {
    int y = __shfl_up(x, off);
    if (lane >= off) x += y;
  }
  if (lane == 63) wsum[w] = x;
  __syncthreads();
  if (t < 16) {
    int v = wsum[t];
    #pragma unroll
    for (int off2 = 1; off2 < 16; off2 <<= 1) {
      int y = __shfl_up(v, off2);
      if (t >= off2) v += y;
    }
    wsum[t] = v;
  }
  __syncthreads();
  int incl = x + (w ? wsum[w - 1] : 0);
  int excl = incl - cv;
  cur[t] = excl;
  off_g[g * 1025 + t] = excl;      // t>=k all hold total, so off[k] is correct
  if (t < k) c_out[newBase + t] = (float)cv;
  __syncthreads();
  int* elp = elist_g + g * EPG;
  #pragma unroll
  for (int i = 0; i < 8; ++i) {
    if (lns[i] >= 0) {
      int pos = atomicAdd(&cur[lnd[i]], 1);
      elp[pos] = newBase + lns[i];
    }
  }
}

// ------- fused pool + readout partial: block = (graph, chunk) -------------
__global__ __launch_bounds__(256) void k_pool_part(const float* __restrict__ h,
    const int* __restrict__ sel_pos, const float* __restrict__ sel_scale, int k,
    float* __restrict__ xo, float* __restrict__ pmax, float* __restrict__ psum)
{
  __shared__ float smx[256], ssm[256];
  const int b  = blockIdx.x >> 4;
  const int ch = blockIdx.x & (RCHUNK - 1);
  const int rpc = (k + RCHUNK - 1) / RCHUNK;
  const int r0 = ch * rpc;
  const int r1 = min(k, r0 + rpc);
  const int d   = threadIdx.x & 127;
  const int sub = threadIdx.x >> 7;
  float mx = -3.402823466e38f, sm = 0.f;
  for (int r = r0 + sub; r < r1; r += 2) {
    int j = b * k + r;
    float scv = sel_scale[j];
    float v = h[(size_t)sel_pos[j] * DIM + d] * scv;
    xo[(size_t)j * DIM + d] = v;
    mx = fmaxf(mx, v);
    sm += v;
  }
  smx[threadIdx.x] = mx; ssm[threadIdx.x] = sm;
  __syncthreads();
  if (sub == 0) {
    mx = fmaxf(mx, smx[d + 128]);
    sm += ssm[d + 128];
    int o = (b * RCHUNK + ch) * 128 + d;
    pmax[o] = mx; psum[o] = sm;
  }
}

// ------- readout stage B: combine partials, accumulate TRANSPOSED rdT -----
__global__ __launch_bounds__(128) void k_readout_final(const float* __restrict__ pmax,
    const float* __restrict__ psum, int k, float* __restrict__ rdT, int add)
{
  int b = blockIdx.x, d = threadIdx.x;
  float mx = -3.402823466e38f, sm = 0.f;
  #pragma unroll
  for (int c = 0; c < RCHUNK; ++c) {
    int o = (b * RCHUNK + c) * 128 + d;
    mx = fmaxf(mx, pmax[o]);
    sm += psum[o];
  }
  float mean = sm / (float)k;
  int omx = d * 64 + b;
  int omn = (128 + d) * 64 + b;
  if (add) { rdT[omx] += mx; rdT[omn] += mean; }
  else     { rdT[omx]  = mx; rdT[omn]  = mean; }
}

// ------- MLP fc1 + BN1 + relu: 16 blocks, lane=graph, wave=feature --------
__global__ __launch_bounds__(512) void k_mlp_fc1(const float* __restrict__ rdT,
    const float* __restrict__ fc1_w, const float* __restrict__ fc1_b,
    const float* __restrict__ g1, const float* __restrict__ be1,
    float* __restrict__ y1n)
{
  __shared__ float W[8 * 256];       // 8 KB
  __shared__ float R[256 * 64];      // 64 KB
  const int t = threadIdx.x, b = blockIdx.x;
  ((float4*)W)[t] = ((const float4*)(fc1_w + (size_t)b * 8 * 256))[t];
  #pragma unroll
  for (int i = 0; i < 8; ++i)
    ((float4*)R)[t + i * 512] = ((const float4*)rdT)[t + i * 512];
  __syncthreads();
  const int g = t & 63, w = t >> 6;  // 8 waves, one feature each
  const float* wrow = W + w * 256;
  float acc = 0.f;
  #pragma unroll 4
  for (int k = 0; k < 256; ++k) acc += R[k * 64 + g] * wrow[k];
  int f = b * 8 + w;
  float y = acc + fc1_b[f];
  float s = y, s2 = y * y;
  #pragma unroll
  for (int off = 32; off; off >>= 1) {
    s  += __shfl_xor(s,  off);
    s2 += __shfl_xor(s2, off);
  }
  float mu = s * 0.015625f;
  float var = s2 * 0.015625f - mu * mu;
  float inv = 1.0f / sqrtf(var + 1e-5f);
  y1n[f * 64 + g] = fmaxf((y - mu) * inv * g1[f] + be1[f], 0.f);
}

// ------- MLP rest: fc2 + BN2 + relu + lin + sigmoid (1 block) -------------
__global__ __launch_bounds__(1024) void k_mlp_rest(const float* __restrict__ y1n,
    const float* __restrict__ fc2_w, const float* __restrict__ fc2_b,
    const float* __restrict__ g2, const float* __restrict__ be2,
    const float* __restrict__ lin_w, const float* __restrict__ lin_b,
    float* __restrict__ out)
{
  __shared__ float W2[64 * 128];     // 32 KB
  __shared__ float Y[128 * 64];      // 32 KB
  __shared__ float part[16 * 64];    // 4 KB
  const int t = threadIdx.x;
  #pragma unroll
  for (int i = 0; i < 2; ++i) {
    ((float4*)W2)[t + i * 1024] = ((const float4*)fc2_w)[t + i * 1024];
    ((float4*)Y) [t + i * 1024] = ((const float4*)y1n)[t + i * 1024];
  }
  __syncthreads();
  const int g = t & 63, w = t >> 6;  // 16 waves x 4 features
  float acc2[4] = {0.f, 0.f, 0.f, 0.f};
  const float* w20 = W2 + (w * 4 + 0) * 128;
  const float* w21 = W2 + (w * 4 + 1) * 128;
  const float* w22 = W2 + (w * 4 + 2) * 128;
  const float* w23 = W2 + (w * 4 + 3) * 128;
  #pragma unroll 4
  for (int k = 0; k < 128; ++k) {
    float yv = Y[k * 64 + g];
    acc2[0] += yv * w20[k];
    acc2[1] += yv * w21[k];
    acc2[2] += yv * w22[k];
    acc2[3] += yv * w23[k];
  }
  float pp = 0.f;
  #pragma unroll
  for (int j = 0; j < 4; ++j) {
    int m = w * 4 + j;
    float y = acc2[j] + fc2_b[m];
    float s = y, s2 = y * y;
    #pragma unroll
    for (int off = 32; off; off >>= 1) {
      s  += __shfl_xor(s,  off);
      s2 += __shfl_xor(s2, off);
    }
    float mu = s * 0.015625f;
    float var = s2 * 0.015625f - mu * mu;
    float inv = 1.0f / sqrtf(var + 1e-5f);
    float yn = fmaxf((y - mu) * inv * g2[m] + be2[m], 0.f);
    pp += yn * lin_w[m];
  }
  part[w * 64 + g] = pp;
  __syncthreads();
  if (w == 0) {
    float a = lin_b[0];
    #pragma unroll
    for (int c = 0; c < 16; ++c) a += part[c * 64 + g];
    out[g] = 1.0f / (1.0f + expf(-a));
  }
}

extern "C" void kernel_launch(void* const* d_in, const int* in_sizes, int n_in,
                              void* d_out, int out_size, void* d_ws, size_t ws_size,
                              hipStream_t stream) {
  const int*   node_idx = (const int*)  d_in[0];
  const int*   edge_idx = (const int*)  d_in[1];
  const float* emb      = (const float*)d_in[2];
  const float* w1l      = (const float*)d_in[3];
  const float* b1l      = (const float*)d_in[4];
  const float* w1r      = (const float*)d_in[5];
  const float* pool_w   = (const float*)d_in[6];
  const float* w2l      = (const float*)d_in[7];
  const float* b2l      = (const float*)d_in[8];
  const float* w2r      = (const float*)d_in[9];
  const float* fc1_w    = (const float*)d_in[10];
  const float* fc1_b    = (const float*)d_in[11];
  const float* bn1_g    = (const float*)d_in[12];
  const float* bn1_b    = (const float*)d_in[13];
  const float* fc2_w    = (const float*)d_in[14];
  const float* fc2_b    = (const float*)d_in[15];
  const float* bn2_g    = (const float*)d_in[16];
  const float* bn2_b    = (const float*)d_in[17];
  const float* lin_w    = (const float*)d_in[18];
  const float* lin_b    = (const float*)d_in[19];
  float* out = (float*)d_out;

  char* p = (char*)d_ws;
  auto alloc = [&](size_t bytes) -> void* {
    void* r = (void*)p;
    p += (bytes + 255) & ~(size_t)255;
    return r;
  };
  float* x_cur     = (float*)alloc((size_t)NNODE * DIM * 4);
  float* s_buf     = (float*)alloc((size_t)NNODE * DIM * 4);
  float* c_buf     = (float*)alloc((size_t)NNODE * 4);
  float* score     = (float*)alloc((size_t)NNODE * 4);
  int*   sel_pos   = (int*)  alloc((size_t)NGRAPH * 820 * 4);
  float* sel_scale = (float*)alloc((size_t)NGRAPH * 820 * 4);
  int*   src_cur   = (int*)  alloc((size_t)NEDGE * 4);
  int*   dst_cur   = (int*)  alloc((size_t)NEDGE * 4);
  int*   off_g     = (int*)  alloc((size_t)NGRAPH * 1025 * 4);
  int*   elist_g   = (int*)  alloc((size_t)NGRAPH * EPG * 4);
  float* rdT       = (float*)alloc((size_t)256 * 64 * 4);
  short* whiF      = (short*)alloc((size_t)2 * 32768 * 2);
  short* wloF      = (short*)alloc((size_t)2 * 32768 * 2);
  float* y1n       = (float*)alloc((size_t)128 * 64 * 4);
  float* pmax      = (float*)alloc((size_t)NGRAPH * RCHUNK * 128 * 4);
  float* psum      = (float*)alloc((size_t)NGRAPH * RCHUNK * 128 * 4);
  float* inv_norm  = (float*)alloc(256);

  k_gather<<<NNODE * 32 / 256, 256, 0, stream>>>(emb, node_idx, x_cur);
  k_norm<<<1, 64, 0, stream>>>(pool_w, inv_norm);
  k_prep_wfrag<<<256, 256, 0, stream>>>(w1l, w1r, w2l, w2r, whiF, wloF);
  k_csr0<<<NGRAPH, 1024, 0, stream>>>(edge_idx, off_g, elist_g, c_buf);

  const int Ks[3] = {820, 656, 525};
  int npg = NPG0;
  for (int stage = 0; stage < 3; ++stage) {
    const short* whi_s = whiF + (stage ? 32768 : 0);
    const short* wlo_s = wloF + (stage ? 32768 : 0);
    const float* bl    = stage ? b2l : b1l;
    int n = NGRAPH * npg;
    int k = Ks[stage];

    k_gather_agg<<<16 * NGRAPH, 256, 0, stream>>>(off_g, elist_g, x_cur, s_buf, npg);
    k_gemm_mfma<<<n / 64, 256, 0, stream>>>(x_cur, s_buf, c_buf, whi_s, wlo_s,
                                            bl, pool_w, score);
    const int* ein_s = (stage == 0) ? edge_idx          : src_cur;
    const int* ein_d = (stage == 0) ? (edge_idx + NEDGE) : dst_cur;
    k_topk_fused<<<NGRAPH, 1024, 0, stream>>>(score, inv_norm, npg, k,
        sel_pos, sel_scale,
        (stage < 2) ? 1 : 0, (stage == 0) ? 1 : 0,
        ein_s, ein_d, src_cur, dst_cur,
        off_g, elist_g, c_buf);
    k_pool_part<<<NGRAPH * RCHUNK, 256, 0, stream>>>(s_buf, sel_pos, sel_scale, k,
                                                     x_cur, pmax, psum);
    k_readout_final<<<NGRAPH, 128, 0, stream>>>(pmax, psum, k, rdT, stage == 0 ? 0 : 1);
    npg = k;
  }

  k_mlp_fc1<<<16, 512, 0, stream>>>(rdT, fc1_w, fc1_b, bn1_g, bn1_b, y1n);
  k_mlp_rest<<<1, 1024, 0, stream>>>(y1n, fc2_w, fc2_b, bn2_g, bn2_b,
                                     lin_w, lin_b, out);
}

// Round 7
// 320.783 us; speedup vs baseline: 3.8888x; 1.0551x over previous
//
#include <hip/hip_runtime.h>
#include <hip/hip_bf16.h>
#include <cstdint>
#include <cstddef>

#define NGRAPH 64
#define NPG0   1024
#define NNODE  65536     // NGRAPH*NPG0
#define NEDGE  524288
#define EPG    8192      // NEDGE/NGRAPH
#define DIM    128
#define RCHUNK 16        // readout partial chunks per graph

typedef __attribute__((ext_vector_type(8))) short short8v;   // 8 bf16
typedef __attribute__((ext_vector_type(4))) float f32x4;

__device__ __forceinline__ unsigned bf16rne(float f) {
  unsigned u = __float_as_uint(f);
  return (u + 0x7FFFu + ((u >> 16) & 1u)) >> 16;
}

// ---------------- gather x = emb[node_idx] ----------------
__global__ __launch_bounds__(256) void k_gather(const float* __restrict__ emb,
    const int* __restrict__ nid, float* __restrict__ x)
{
  int tid = blockIdx.x * 256 + threadIdx.x;
  int i = tid >> 5, lane = tid & 31;
  int row = nid[i];
  ((float4*)(x + (size_t)i * DIM))[lane] =
      ((const float4*)(emb + (size_t)row * DIM))[lane];
}

// ---------------- 1/||pool_w|| ----------------
__global__ __launch_bounds__(64) void k_norm(const float* __restrict__ pw,
    float* __restrict__ inv_norm)
{
  int t = threadIdx.x;
  float a = pw[t], b = pw[t + 64];
  float v = a * a + b * b;
  for (int off = 32; off; off >>= 1) v += __shfl_xor(v, off);
  if (t == 0) *inv_norm = 1.0f / sqrtf(v);
}

// ------- pre-swizzle weights into MFMA B-fragment layout, bf16 hi/lo ------
__global__ __launch_bounds__(256) void k_prep_wfrag(
    const float* __restrict__ w1l, const float* __restrict__ w1r,
    const float* __restrict__ w2l, const float* __restrict__ w2r,
    short* __restrict__ whiF, short* __restrict__ wloF)
{
  int id = blockIdx.x * 256 + threadIdx.x;    // 0..65535 (2 sets x 32768)
  int set = id >> 15;
  int r = id & 32767;
  int j  = r & 7;
  int l  = (r >> 3) & 63;
  int nt = (r >> 9) & 7;
  int kk = r >> 12;
  int k = kk * 32 + ((l >> 4) & 3) * 8 + j;
  int n = nt * 16 + (l & 15);
  const float* wl = set ? w2l : w1l;
  const float* wr = set ? w2r : w1r;
  float w = (k < 128) ? wl[n * 128 + k] : wr[n * 128 + (k - 128)];
  unsigned hb = bf16rne(w);
  float hif = __uint_as_float(hb << 16);
  unsigned lb = bf16rne(w - hif);
  whiF[id] = (short)hb;
  wloF[id] = (short)lb;
}

// ---------------- stage-0 CSR build straight from edge_idx ----------------
__global__ __launch_bounds__(1024) void k_csr0(const int* __restrict__ ei,
    int* __restrict__ off_g, int* __restrict__ elist_g, float* __restrict__ c_out)
{
  __shared__ int cnt[1024];
  __shared__ int cur[1024];
  __shared__ int wsum[16];
  const int t = threadIdx.x, g = blockIdx.x;
  const int nodeBase = g * NPG0;
  const int e0 = g * EPG;
  cnt[t] = 0;
  __syncthreads();
  int sv8[8], dl8[8];
  #pragma unroll
  for (int i = 0; i < 8; ++i) {
    int e = e0 + t + i * 1024;
    sv8[i] = ei[e];
    dl8[i] = ei[NEDGE + e] - nodeBase;
    atomicAdd(&cnt[dl8[i]], 1);
  }
  __syncthreads();
  const int lane = t & 63, w = t >> 6;
  int cv = cnt[t];
  int x = cv;
  #pragma unroll
  for (int off = 1; off < 64; off <<= 1) {
    int y = __shfl_up(x, off);
    if (lane >= off) x += y;
  }
  if (lane == 63) wsum[w] = x;
  __syncthreads();
  if (t < 16) {
    int v = wsum[t];
    #pragma unroll
    for (int off2 = 1; off2 < 16; off2 <<= 1) {
      int y = __shfl_up(v, off2);
      if (t >= off2) v += y;
    }
    wsum[t] = v;
  }
  __syncthreads();
  int incl = x + (w ? wsum[w - 1] : 0);
  int excl = incl - cv;
  cur[t] = excl;
  int* offp = off_g + g * 1025;
  offp[t] = excl;
  if (t == 1023) offp[1024] = incl;
  c_out[nodeBase + t] = (float)cv;
  __syncthreads();
  int* elp = elist_g + g * EPG;
  #pragma unroll
  for (int i = 0; i < 8; ++i) {
    int pos = atomicAdd(&cur[dl8[i]], 1);
    elp[pos] = sv8[i];
  }
}

// ------- gather+sum: 32 blocks/graph (feature quarter x node eighth) ------
// blockIdx = s*64 + g  (all blocks of graph g share blockIdx%8 -> same XCD)
__global__ __launch_bounds__(256) void k_gather_agg(
    const int* __restrict__ off_g, const int* __restrict__ elist_g,
    const float* __restrict__ x, float* __restrict__ s_out, int npg)
{
  const int g  = blockIdx.x & 63;
  const int sb = blockIdx.x >> 6;        // 0..31
  const int qf = sb & 3;                 // feature quarter
  const int qn = sb >> 2;                // node eighth
  const int t = threadIdx.x;
  const int gr = t >> 3;                 // 32 groups
  const int lane8 = t & 7;
  const int fo = qf * 8 + lane8;         // float4 index within row
  const int nq8 = (npg + 7) >> 3;
  const int vbase = qn * nq8;
  const int vend = min(npg, vbase + nq8);
  const int nodeBase = g * npg;
  const int* off = off_g + g * 1025;
  const int* el  = elist_g + g * EPG;
  const int nq = vend - vbase;
  const int per = (nq + 31) >> 5;
  int v0 = vbase + gr * per;
  int v1 = min(vend, v0 + per);
  for (int v = v0; v < v1; ++v) {
    int e   = off[v];
    int end = off[v + 1];
    float4 acc = {0.f, 0.f, 0.f, 0.f};
    for (; e + 8 <= end; e += 8) {
      int s0 = el[e],     s1 = el[e + 1], s2 = el[e + 2], s3 = el[e + 3];
      int s4 = el[e + 4], s5 = el[e + 5], s6 = el[e + 6], s7 = el[e + 7];
      float4 a0 = ((const float4*)(x + (size_t)s0 * DIM))[fo];
      float4 a1 = ((const float4*)(x + (size_t)s1 * DIM))[fo];
      float4 a2 = ((const float4*)(x + (size_t)s2 * DIM))[fo];
      float4 a3 = ((const float4*)(x + (size_t)s3 * DIM))[fo];
      float4 a4 = ((const float4*)(x + (size_t)s4 * DIM))[fo];
      float4 a5 = ((const float4*)(x + (size_t)s5 * DIM))[fo];
      float4 a6 = ((const float4*)(x + (size_t)s6 * DIM))[fo];
      float4 a7 = ((const float4*)(x + (size_t)s7 * DIM))[fo];
      acc.x += ((a0.x + a1.x) + (a2.x + a3.x)) + ((a4.x + a5.x) + (a6.x + a7.x));
      acc.y += ((a0.y + a1.y) + (a2.y + a3.y)) + ((a4.y + a5.y) + (a6.y + a7.y));
      acc.z += ((a0.z + a1.z) + (a2.z + a3.z)) + ((a4.z + a5.z) + (a6.z + a7.z));
      acc.w += ((a0.w + a1.w) + (a2.w + a3.w)) + ((a4.w + a5.w) + (a6.w + a7.w));
    }
    for (; e + 2 <= end; e += 2) {
      int s0 = el[e], s1 = el[e + 1];
      float4 a0 = ((const float4*)(x + (size_t)s0 * DIM))[fo];
      float4 a1 = ((const float4*)(x + (size_t)s1 * DIM))[fo];
      acc.x += a0.x + a1.x; acc.y += a0.y + a1.y;
      acc.z += a0.z + a1.z; acc.w += a0.w + a1.w;
    }
    if (e < end) {
      float4 a = ((const float4*)(x + (size_t)el[e] * DIM))[fo];
      acc.x += a.x; acc.y += a.y; acc.z += a.z; acc.w += a.w;
    }
    ((float4*)(s_out + (size_t)(nodeBase + v) * DIM))[fo] = acc;
  }
}

// ------- MFMA SAGE layer: h = relu([s*invc | x] @ W + bl), fused score ----
__global__ __launch_bounds__(256) void k_gemm_mfma(
    const float* __restrict__ x, float* __restrict__ s, const float* __restrict__ c,
    const short* __restrict__ whiF, const short* __restrict__ wloF,
    const float* __restrict__ bl, const float* __restrict__ pw,
    float* __restrict__ score)
{
  const int t = threadIdx.x;
  const int wv = t >> 6, l = t & 63;
  const int rowbase = blockIdx.x * 64 + wv * 16;
  const int lrow = l & 15, lk = l >> 4;      // lk 0..3
  const int row = rowbase + lrow;
  const float invc = 1.0f / fmaxf(c[row], 1.0f);
  f32x4 acc[8];
  #pragma unroll
  for (int nt = 0; nt < 8; ++nt) acc[nt] = (f32x4){0.f, 0.f, 0.f, 0.f};
  const float* srow = s + (size_t)row * DIM + lk * 8;
  const float* xrow = x + (size_t)row * DIM + lk * 8;
  const short8v* bh = (const short8v*)whiF;
  const short8v* bo = (const short8v*)wloF;

  #pragma unroll
  for (int kk = 0; kk < 8; ++kk) {
    const float* ap = (kk < 4) ? (srow + kk * 32) : (xrow + (kk - 4) * 32);
    float4 a0 = *(const float4*)ap;
    float4 a1 = *(const float4*)(ap + 4);
    float scl = (kk < 4) ? invc : 1.0f;
    float av[8] = { a0.x * scl, a0.y * scl, a0.z * scl, a0.w * scl,
                    a1.x * scl, a1.y * scl, a1.z * scl, a1.w * scl };
    short8v ahi, alo;
    #pragma unroll
    for (int j = 0; j < 8; ++j) {
      unsigned hb = bf16rne(av[j]);
      float hif = __uint_as_float(hb << 16);
      ahi[j] = (short)hb;
      alo[j] = (short)bf16rne(av[j] - hif);
    }
    #pragma unroll
    for (int nt = 0; nt < 8; ++nt) {
      int fi = (kk * 8 + nt) * 64 + l;
      short8v bhi = bh[fi];
      short8v blo = bo[fi];
      acc[nt] = __builtin_amdgcn_mfma_f32_16x16x32_bf16(ahi, bhi, acc[nt], 0, 0, 0);
      acc[nt] = __builtin_amdgcn_mfma_f32_16x16x32_bf16(alo, bhi, acc[nt], 0, 0, 0);
      acc[nt] = __builtin_amdgcn_mfma_f32_16x16x32_bf16(ahi, blo, acc[nt], 0, 0, 0);
    }
  }

  float sp0 = 0.f, sp1 = 0.f, sp2 = 0.f, sp3 = 0.f;
  const int mb = rowbase + lk * 4;
  #pragma unroll
  for (int nt = 0; nt < 8; ++nt) {
    int col = nt * 16 + lrow;
    float bb = bl[col], pv = pw[col];
    float h0 = fmaxf(acc[nt][0] + bb, 0.f);
    float h1 = fmaxf(acc[nt][1] + bb, 0.f);
    float h2 = fmaxf(acc[nt][2] + bb, 0.f);
    float h3 = fmaxf(acc[nt][3] + bb, 0.f);
    s[(size_t)(mb + 0) * DIM + col] = h0;
    s[(size_t)(mb + 1) * DIM + col] = h1;
    s[(size_t)(mb + 2) * DIM + col] = h2;
    s[(size_t)(mb + 3) * DIM + col] = h3;
    sp0 += h0 * pv; sp1 += h1 * pv; sp2 += h2 * pv; sp3 += h3 * pv;
  }
  #pragma unroll
  for (int off = 1; off <= 8; off <<= 1) {
    sp0 += __shfl_xor(sp0, off);
    sp1 += __shfl_xor(sp1, off);
    sp2 += __shfl_xor(sp2, off);
    sp3 += __shfl_xor(sp3, off);
  }
  if (lrow == 0) {
    score[mb + 0] = sp0;
    score[mb + 1] = sp1;
    score[mb + 2] = sp2;
    score[mb + 3] = sp3;
  }
}

// ------- fused: bitonic top-k + relabel edges + build next-stage CSR ------
__global__ __launch_bounds__(1024) void k_topk_fused(
    const float* __restrict__ score, const float* __restrict__ inv_norm_p,
    int npg, int k, int* __restrict__ sel_pos, float* __restrict__ sel_scale,
    int build_next, int write_eout,
    const int* __restrict__ ein_src, const int* __restrict__ ein_dst,
    int* __restrict__ eout_src, int* __restrict__ eout_dst,
    int* __restrict__ off_g, int* __restrict__ elist_g, float* __restrict__ c_out)
{
  __shared__ float key[1024];
  __shared__ int   idxs[1024];
  __shared__ int   nid[1024];
  __shared__ int   cnt[1024];
  __shared__ int   cur[1024];
  __shared__ int   wsum[16];
  const int t = threadIdx.x, g = blockIdx.x;
  const int base = g * npg;
  key[t] = (t < npg) ? score[base + t] : -3.402823466e38f;
  idxs[t] = t;
  nid[t] = -1;
  cnt[t] = 0;
  __syncthreads();
  for (int size = 2; size <= 1024; size <<= 1) {
    for (int stride = size >> 1; stride > 0; stride >>= 1) {
      int p = t ^ stride;
      if (p > t) {
        float ka = key[t], kb = key[p];
        int ia = idxs[t], ib = idxs[p];
        bool a_first = (ka > kb) || (ka == kb && ia < ib);
        bool desc = ((t & size) == 0);
        if (desc ? !a_first : a_first) {
          key[t] = kb; key[p] = ka; idxs[t] = ib; idxs[p] = ia;
        }
      }
      __syncthreads();
    }
  }
  if (t < k) {
    float inv = *inv_norm_p;
    int local = idxs[t];
    nid[local] = t;
    sel_pos[g * k + t] = base + local;
    sel_scale[g * k + t] = tanhf(key[t] * inv);
  }
  if (!build_next) return;
  __syncthreads();
  const int e0 = g * EPG;
  const int newBase = g * k;
  int lns[8], lnd[8];
  #pragma unroll
  for (int i = 0; i < 8; ++i) {
    int e = e0 + t + i * 1024;
    int sv = ein_src[e];
    int ns = -1, nd = -1;
    if (sv >= 0) {
      int dv = ein_dst[e];
      ns = nid[sv - base];
      nd = nid[dv - base];
      if (ns < 0 || nd < 0) ns = -1;
    }
    lns[i] = ns; lnd[i] = nd;
    if (write_eout) {
      eout_src[e] = (ns >= 0) ? (newBase + ns) : -1;
      eout_dst[e] = (ns >= 0) ? (newBase + nd) : -1;
    }
    if (ns >= 0) atomicAdd(&cnt[nd], 1);
  }
  __syncthreads();
  const int lane = t & 63, w = t >> 6;
  int cv = cnt[t];
  int x = cv;
  #pragma unroll
  for (int off = 1; off < 64; off <<= 1) {
    int y = __shfl_up(x, off);
    if (lane >= off) x += y;
  }
  if (lane == 63) wsum[w] = x;
  __syncthreads();
  if (t < 16) {
    int v = wsum[t];
    #pragma unroll
    for (int off2 = 1; off2 < 16; off2 <<= 1) {
      int y = __shfl_up(v, off2);
      if (t >= off2) v += y;
    }
    wsum[t] = v;
  }
  __syncthreads();
  int incl = x + (w ? wsum[w - 1] : 0);
  int excl = incl - cv;
  cur[t] = excl;
  off_g[g * 1025 + t] = excl;      // t>=k all hold total, so off[k] is correct
  if (t < k) c_out[newBase + t] = (float)cv;
  __syncthreads();
  int* elp = elist_g + g * EPG;
  #pragma unroll
  for (int i = 0; i < 8; ++i) {
    if (lns[i] >= 0) {
      int pos = atomicAdd(&cur[lnd[i]], 1);
      elp[pos] = newBase + lns[i];
    }
  }
}

// ------- fused pool + readout partial (float4 rows): block=(graph,chunk) --
__global__ __launch_bounds__(256) void k_pool_part(const float* __restrict__ h,
    const int* __restrict__ sel_pos, const float* __restrict__ sel_scale, int k,
    float* __restrict__ xo, float* __restrict__ pmax, float* __restrict__ psum)
{
  __shared__ float4 smx[256], ssm[256];
  const int b  = blockIdx.x >> 4;
  const int ch = blockIdx.x & (RCHUNK - 1);
  const int rpc = (k + RCHUNK - 1) / RCHUNK;
  const int r0 = ch * rpc;
  const int r1 = min(k, r0 + rpc);
  const int d4  = threadIdx.x & 31;      // float4 index in row
  const int sub = threadIdx.x >> 5;      // 8 rows in flight
  const float NEG = -3.402823466e38f;
  float4 mx = {NEG, NEG, NEG, NEG};
  float4 sm = {0.f, 0.f, 0.f, 0.f};
  for (int r = r0 + sub; r < r1; r += 8) {
    int j = b * k + r;
    float scv = sel_scale[j];
    float4 v = ((const float4*)(h + (size_t)sel_pos[j] * DIM))[d4];
    v.x *= scv; v.y *= scv; v.z *= scv; v.w *= scv;
    ((float4*)(xo + (size_t)j * DIM))[d4] = v;
    mx.x = fmaxf(mx.x, v.x); mx.y = fmaxf(mx.y, v.y);
    mx.z = fmaxf(mx.z, v.z); mx.w = fmaxf(mx.w, v.w);
    sm.x += v.x; sm.y += v.y; sm.z += v.z; sm.w += v.w;
  }
  smx[threadIdx.x] = mx; ssm[threadIdx.x] = sm;
  __syncthreads();
  if (sub < 4) {  // reduce 8 -> 1 via tree in LDS (3 steps)
    #pragma unroll
    for (int step = 4; step >= 1; step >>= 1) {
      if (sub < step) {
        float4 m2 = smx[(sub + step) * 32 + d4];
        float4 s2 = ssm[(sub + step) * 32 + d4];
        mx = smx[sub * 32 + d4]; sm = ssm[sub * 32 + d4];
        mx.x = fmaxf(mx.x, m2.x); mx.y = fmaxf(mx.y, m2.y);
        mx.z = fmaxf(mx.z, m2.z); mx.w = fmaxf(mx.w, m2.w);
        sm.x += s2.x; sm.y += s2.y; sm.z += s2.z; sm.w += s2.w;
        smx[sub * 32 + d4] = mx; ssm[sub * 32 + d4] = sm;
      }
      __syncthreads();
    }
  }
  if (sub == 0) {
    int o = (b * RCHUNK + ch) * 32 + d4;
    ((float4*)pmax)[o] = smx[d4];
    ((float4*)psum)[o] = ssm[d4];
  }
}

// ------- readout stage B: combine partials, accumulate TRANSPOSED rdT -----
__global__ __launch_bounds__(128) void k_readout_final(const float* __restrict__ pmax,
    const float* __restrict__ psum, int k, float* __restrict__ rdT, int add)
{
  int b = blockIdx.x, d = threadIdx.x;
  float mx = -3.402823466e38f, sm = 0.f;
  #pragma unroll
  for (int c = 0; c < RCHUNK; ++c) {
    int o = (b * RCHUNK + c) * 128 + d;
    mx = fmaxf(mx, pmax[o]);
    sm += psum[o];
  }
  float mean = sm / (float)k;
  int omx = d * 64 + b;
  int omn = (128 + d) * 64 + b;
  if (add) { rdT[omx] += mx; rdT[omn] += mean; }
  else     { rdT[omx]  = mx; rdT[omn]  = mean; }
}

// ------- MLP fc1 + BN1 + relu: 16 blocks, lane=graph, wave=feature --------
__global__ __launch_bounds__(512) void k_mlp_fc1(const float* __restrict__ rdT,
    const float* __restrict__ fc1_w, const float* __restrict__ fc1_b,
    const float* __restrict__ g1, const float* __restrict__ be1,
    float* __restrict__ y1n)
{
  __shared__ float W[8 * 256];       // 8 KB
  __shared__ float R[256 * 64];      // 64 KB
  const int t = threadIdx.x, b = blockIdx.x;
  ((float4*)W)[t] = ((const float4*)(fc1_w + (size_t)b * 8 * 256))[t];
  #pragma unroll
  for (int i = 0; i < 8; ++i)
    ((float4*)R)[t + i * 512] = ((const float4*)rdT)[t + i * 512];
  __syncthreads();
  const int g = t & 63, w = t >> 6;  // 8 waves, one feature each
  const float* wrow = W + w * 256;
  float acc = 0.f;
  #pragma unroll 4
  for (int k = 0; k < 256; ++k) acc += R[k * 64 + g] * wrow[k];
  int f = b * 8 + w;
  float y = acc + fc1_b[f];
  float s = y, s2 = y * y;
  #pragma unroll
  for (int off = 32; off; off >>= 1) {
    s  += __shfl_xor(s,  off);
    s2 += __shfl_xor(s2, off);
  }
  float mu = s * 0.015625f;
  float var = s2 * 0.015625f - mu * mu;
  float inv = 1.0f / sqrtf(var + 1e-5f);
  y1n[f * 64 + g] = fmaxf((y - mu) * inv * g1[f] + be1[f], 0.f);
}

// ------- MLP rest: fc2 + BN2 + relu + lin + sigmoid (1 block) -------------
__global__ __launch_bounds__(1024) void k_mlp_rest(const float* __restrict__ y1n,
    const float* __restrict__ fc2_w, const float* __restrict__ fc2_b,
    const float* __restrict__ g2, const float* __restrict__ be2,
    const float* __restrict__ lin_w, const float* __restrict__ lin_b,
    float* __restrict__ out)
{
  __shared__ float W2[64 * 128];     // 32 KB
  __shared__ float Y[128 * 64];      // 32 KB
  __shared__ float part[16 * 64];    // 4 KB
  const int t = threadIdx.x;
  #pragma unroll
  for (int i = 0; i < 2; ++i) {
    ((float4*)W2)[t + i * 1024] = ((const float4*)fc2_w)[t + i * 1024];
    ((float4*)Y) [t + i * 1024] = ((const float4*)y1n)[t + i * 1024];
  }
  __syncthreads();
  const int g = t & 63, w = t >> 6;  // 16 waves x 4 features
  float acc2[4] = {0.f, 0.f, 0.f, 0.f};
  const float* w20 = W2 + (w * 4 + 0) * 128;
  const float* w21 = W2 + (w * 4 + 1) * 128;
  const float* w22 = W2 + (w * 4 + 2) * 128;
  const float* w23 = W2 + (w * 4 + 3) * 128;
  #pragma unroll 4
  for (int k = 0; k < 128; ++k) {
    float yv = Y[k * 64 + g];
    acc2[0] += yv * w20[k];
    acc2[1] += yv * w21[k];
    acc2[2] += yv * w22[k];
    acc2[3] += yv * w23[k];
  }
  float pp = 0.f;
  #pragma unroll
  for (int j = 0; j < 4; ++j) {
    int m = w * 4 + j;
    float y = acc2[j] + fc2_b[m];
    float s = y, s2 = y * y;
    #pragma unroll
    for (int off = 32; off; off >>= 1) {
      s  += __shfl_xor(s,  off);
      s2 += __shfl_xor(s2, off);
    }
    float mu = s * 0.015625f;
    float var = s2 * 0.015625f - mu * mu;
    float inv = 1.0f / sqrtf(var + 1e-5f);
    float yn = fmaxf((y - mu) * inv * g2[m] + be2[m], 0.f);
    pp += yn * lin_w[m];
  }
  part[w * 64 + g] = pp;
  __syncthreads();
  if (w == 0) {
    float a = lin_b[0];
    #pragma unroll
    for (int c = 0; c < 16; ++c) a += part[c * 64 + g];
    out[g] = 1.0f / (1.0f + expf(-a));
  }
}

extern "C" void kernel_launch(void* const* d_in, const int* in_sizes, int n_in,
                              void* d_out, int out_size, void* d_ws, size_t ws_size,
                              hipStream_t stream) {
  const int*   node_idx = (const int*)  d_in[0];
  const int*   edge_idx = (const int*)  d_in[1];
  const float* emb      = (const float*)d_in[2];
  const float* w1l      = (const float*)d_in[3];
  const float* b1l      = (const float*)d_in[4];
  const float* w1r      = (const float*)d_in[5];
  const float* pool_w   = (const float*)d_in[6];
  const float* w2l      = (const float*)d_in[7];
  const float* b2l      = (const float*)d_in[8];
  const float* w2r      = (const float*)d_in[9];
  const float* fc1_w    = (const float*)d_in[10];
  const float* fc1_b    = (const float*)d_in[11];
  const float* bn1_g    = (const float*)d_in[12];
  const float* bn1_b    = (const float*)d_in[13];
  const float* fc2_w    = (const float*)d_in[14];
  const float* fc2_b    = (const float*)d_in[15];
  const float* bn2_g    = (const float*)d_in[16];
  const float* bn2_b    = (const float*)d_in[17];
  const float* lin_w    = (const float*)d_in[18];
  const float* lin_b    = (const float*)d_in[19];
  float* out = (float*)d_out;

  char* p = (char*)d_ws;
  auto alloc = [&](size_t bytes) -> void* {
    void* r = (void*)p;
    p += (bytes + 255) & ~(size_t)255;
    return r;
  };
  float* x_cur     = (float*)alloc((size_t)NNODE * DIM * 4);
  float* s_buf     = (float*)alloc((size_t)NNODE * DIM * 4);
  float* c_buf     = (float*)alloc((size_t)NNODE * 4);
  float* score     = (float*)alloc((size_t)NNODE * 4);
  int*   sel_pos   = (int*)  alloc((size_t)NGRAPH * 820 * 4);
  float* sel_scale = (float*)alloc((size_t)NGRAPH * 820 * 4);
  int*   src_cur   = (int*)  alloc((size_t)NEDGE * 4);
  int*   dst_cur   = (int*)  alloc((size_t)NEDGE * 4);
  int*   off_g     = (int*)  alloc((size_t)NGRAPH * 1025 * 4);
  int*   elist_g   = (int*)  alloc((size_t)NGRAPH * EPG * 4);
  float* rdT       = (float*)alloc((size_t)256 * 64 * 4);
  short* whiF      = (short*)alloc((size_t)2 * 32768 * 2);
  short* wloF      = (short*)alloc((size_t)2 * 32768 * 2);
  float* y1n       = (float*)alloc((size_t)128 * 64 * 4);
  float* pmax      = (float*)alloc((size_t)NGRAPH * RCHUNK * 128 * 4);
  float* psum      = (float*)alloc((size_t)NGRAPH * RCHUNK * 128 * 4);
  float* inv_norm  = (float*)alloc(256);

  k_gather<<<NNODE * 32 / 256, 256, 0, stream>>>(emb, node_idx, x_cur);
  k_norm<<<1, 64, 0, stream>>>(pool_w, inv_norm);
  k_prep_wfrag<<<256, 256, 0, stream>>>(w1l, w1r, w2l, w2r, whiF, wloF);
  k_csr0<<<NGRAPH, 1024, 0, stream>>>(edge_idx, off_g, elist_g, c_buf);

  const int Ks[3] = {820, 656, 525};
  int npg = NPG0;
  for (int stage = 0; stage < 3; ++stage) {
    const short* whi_s = whiF + (stage ? 32768 : 0);
    const short* wlo_s = wloF + (stage ? 32768 : 0);
    const float* bl    = stage ? b2l : b1l;
    int n = NGRAPH * npg;
    int k = Ks[stage];

    k_gather_agg<<<32 * NGRAPH, 256, 0, stream>>>(off_g, elist_g, x_cur, s_buf, npg);
    k_gemm_mfma<<<n / 64, 256, 0, stream>>>(x_cur, s_buf, c_buf, whi_s, wlo_s,
                                            bl, pool_w, score);
    const int* ein_s = (stage == 0) ? edge_idx          : src_cur;
    const int* ein_d = (stage == 0) ? (edge_idx + NEDGE) : dst_cur;
    k_topk_fused<<<NGRAPH, 1024, 0, stream>>>(score, inv_norm, npg, k,
        sel_pos, sel_scale,
        (stage < 2) ? 1 : 0, (stage == 0) ? 1 : 0,
        ein_s, ein_d, src_cur, dst_cur,
        off_g, elist_g, c_buf);
    k_pool_part<<<NGRAPH * RCHUNK, 256, 0, stream>>>(s_buf, sel_pos, sel_scale, k,
                                                     x_cur, pmax, psum);
    k_readout_final<<<NGRAPH, 128, 0, stream>>>(pmax, psum, k, rdT, stage == 0 ? 0 : 1);
    npg = k;
  }

  k_mlp_fc1<<<16, 512, 0, stream>>>(rdT, fc1_w, fc1_b, bn1_g, bn1_b, y1n);
  k_mlp_rest<<<1, 1024, 0, stream>>>(y1n, fc2_w, fc2_b, bn2_g, bn2_b,
                                     lin_w, lin_b, out);
}

// Round 8
// 296.742 us; speedup vs baseline: 4.2039x; 1.0810x over previous
//
#include <hip/hip_runtime.h>
#include <hip/hip_bf16.h>
#include <cstdint>
#include <cstddef>

#define NGRAPH 64
#define NPG0   1024
#define NNODE  65536     // NGRAPH*NPG0
#define NEDGE  524288
#define EPG    8192      // NEDGE/NGRAPH
#define DIM    128
#define RCHUNK 16        // readout partial chunks per graph

typedef __attribute__((ext_vector_type(8))) short short8v;   // 8 bf16
typedef __attribute__((ext_vector_type(4))) float f32x4;

__device__ __forceinline__ unsigned bf16rne(float f) {
  unsigned u = __float_as_uint(f);
  return (u + 0x7FFFu + ((u >> 16) & 1u)) >> 16;
}

// ---------------- gather x = emb[node_idx] ----------------
__global__ __launch_bounds__(256) void k_gather(const float* __restrict__ emb,
    const int* __restrict__ nid, float* __restrict__ x)
{
  int tid = blockIdx.x * 256 + threadIdx.x;
  int i = tid >> 5, lane = tid & 31;
  int row = nid[i];
  ((float4*)(x + (size_t)i * DIM))[lane] =
      ((const float4*)(emb + (size_t)row * DIM))[lane];
}

// ---------------- 1/||pool_w|| ----------------
__global__ __launch_bounds__(64) void k_norm(const float* __restrict__ pw,
    float* __restrict__ inv_norm)
{
  int t = threadIdx.x;
  float a = pw[t], b = pw[t + 64];
  float v = a * a + b * b;
  for (int off = 32; off; off >>= 1) v += __shfl_xor(v, off);
  if (t == 0) *inv_norm = 1.0f / sqrtf(v);
}

// ------- pre-swizzle weights into MFMA B-fragment layout, bf16 hi/lo ------
__global__ __launch_bounds__(256) void k_prep_wfrag(
    const float* __restrict__ w1l, const float* __restrict__ w1r,
    const float* __restrict__ w2l, const float* __restrict__ w2r,
    short* __restrict__ whiF, short* __restrict__ wloF)
{
  int id = blockIdx.x * 256 + threadIdx.x;    // 0..65535 (2 sets x 32768)
  int set = id >> 15;
  int r = id & 32767;
  int j  = r & 7;
  int l  = (r >> 3) & 63;
  int nt = (r >> 9) & 7;
  int kk = r >> 12;
  int k = kk * 32 + ((l >> 4) & 3) * 8 + j;
  int n = nt * 16 + (l & 15);
  const float* wl = set ? w2l : w1l;
  const float* wr = set ? w2r : w1r;
  float w = (k < 128) ? wl[n * 128 + k] : wr[n * 128 + (k - 128)];
  unsigned hb = bf16rne(w);
  float hif = __uint_as_float(hb << 16);
  unsigned lb = bf16rne(w - hif);
  whiF[id] = (short)hb;
  wloF[id] = (short)lb;
}

// ---------------- stage-0 CSR build straight from edge_idx ----------------
__global__ __launch_bounds__(1024) void k_csr0(const int* __restrict__ ei,
    int* __restrict__ off_g, int* __restrict__ elist_g, float* __restrict__ c_out)
{
  __shared__ int cnt[1024];
  __shared__ int cur[1024];
  __shared__ int wsum[16];
  const int t = threadIdx.x, g = blockIdx.x;
  const int nodeBase = g * NPG0;
  const int e0 = g * EPG;
  cnt[t] = 0;
  __syncthreads();
  int sv8[8], dl8[8];
  #pragma unroll
  for (int i = 0; i < 8; ++i) {
    int e = e0 + t + i * 1024;
    sv8[i] = ei[e];
    dl8[i] = ei[NEDGE + e] - nodeBase;
    atomicAdd(&cnt[dl8[i]], 1);
  }
  __syncthreads();
  const int lane = t & 63, w = t >> 6;
  int cv = cnt[t];
  int x = cv;
  #pragma unroll
  for (int off = 1; off < 64; off <<= 1) {
    int y = __shfl_up(x, off);
    if (lane >= off) x += y;
  }
  if (lane == 63) wsum[w] = x;
  __syncthreads();
  if (t < 16) {
    int v = wsum[t];
    #pragma unroll
    for (int off2 = 1; off2 < 16; off2 <<= 1) {
      int y = __shfl_up(v, off2);
      if (t >= off2) v += y;
    }
    wsum[t] = v;
  }
  __syncthreads();
  int incl = x + (w ? wsum[w - 1] : 0);
  int excl = incl - cv;
  cur[t] = excl;
  int* offp = off_g + g * 1025;
  offp[t] = excl;
  if (t == 1023) offp[1024] = incl;
  c_out[nodeBase + t] = (float)cv;
  __syncthreads();
  int* elp = elist_g + g * EPG;
  #pragma unroll
  for (int i = 0; i < 8; ++i) {
    int pos = atomicAdd(&cur[dl8[i]], 1);
    elp[pos] = sv8[i];
  }
}

// ------- gather+sum: FULL 512B rows per 32-lane group ---------------------
// 16 blocks/graph (node sixteenth); blockIdx = s*64 + g  (XCD affinity g%8)
// Each 32-lane group owns float4 slot l32 and walks its node range; every
// edge row is fetched ONCE (contiguous 512B), not 4x128B as before.
__global__ __launch_bounds__(256) void k_gather_agg(
    const int* __restrict__ off_g, const int* __restrict__ elist_g,
    const float* __restrict__ x, float* __restrict__ s_out, int npg)
{
  const int g  = blockIdx.x & 63;
  const int sb = blockIdx.x >> 6;        // 0..15 node sixteenth
  const int t = threadIdx.x;
  const int gr = t >> 5;                 // 8 groups of 32 lanes
  const int l32 = t & 31;                // float4 slot within row
  const int nq16 = (npg + 15) >> 4;
  const int vbase = sb * nq16;
  const int vend = min(npg, vbase + nq16);
  const int nodeBase = g * npg;
  const int* off = off_g + g * 1025;
  const int* el  = elist_g + g * EPG;
  const int cnt = vend - vbase;
  const int per = (cnt + 7) >> 3;
  int v0 = vbase + gr * per;
  int v1 = min(vend, v0 + per);
  for (int v = v0; v < v1; ++v) {
    int e   = off[v];
    int end = off[v + 1];
    float4 acc = {0.f, 0.f, 0.f, 0.f};
    for (; e + 4 <= end; e += 4) {
      int s0 = el[e], s1 = el[e + 1], s2 = el[e + 2], s3 = el[e + 3];
      float4 a0 = ((const float4*)(x + (size_t)s0 * DIM))[l32];
      float4 a1 = ((const float4*)(x + (size_t)s1 * DIM))[l32];
      float4 a2 = ((const float4*)(x + (size_t)s2 * DIM))[l32];
      float4 a3 = ((const float4*)(x + (size_t)s3 * DIM))[l32];
      acc.x += (a0.x + a1.x) + (a2.x + a3.x);
      acc.y += (a0.y + a1.y) + (a2.y + a3.y);
      acc.z += (a0.z + a1.z) + (a2.z + a3.z);
      acc.w += (a0.w + a1.w) + (a2.w + a3.w);
    }
    for (; e + 2 <= end; e += 2) {
      int s0 = el[e], s1 = el[e + 1];
      float4 a0 = ((const float4*)(x + (size_t)s0 * DIM))[l32];
      float4 a1 = ((const float4*)(x + (size_t)s1 * DIM))[l32];
      acc.x += a0.x + a1.x; acc.y += a0.y + a1.y;
      acc.z += a0.z + a1.z; acc.w += a0.w + a1.w;
    }
    if (e < end) {
      float4 a = ((const float4*)(x + (size_t)el[e] * DIM))[l32];
      acc.x += a.x; acc.y += a.y; acc.z += a.z; acc.w += a.w;
    }
    ((float4*)(s_out + (size_t)(nodeBase + v) * DIM))[l32] = acc;
  }
}

// ------- MFMA SAGE layer: h = relu([s*invc | x] @ W + bl), fused score ----
__global__ __launch_bounds__(256) void k_gemm_mfma(
    const float* __restrict__ x, float* __restrict__ s, const float* __restrict__ c,
    const short* __restrict__ whiF, const short* __restrict__ wloF,
    const float* __restrict__ bl, const float* __restrict__ pw,
    float* __restrict__ score)
{
  const int t = threadIdx.x;
  const int wv = t >> 6, l = t & 63;
  const int rowbase = blockIdx.x * 64 + wv * 16;
  const int lrow = l & 15, lk = l >> 4;      // lk 0..3
  const int row = rowbase + lrow;
  const float invc = 1.0f / fmaxf(c[row], 1.0f);
  f32x4 acc[8];
  #pragma unroll
  for (int nt = 0; nt < 8; ++nt) acc[nt] = (f32x4){0.f, 0.f, 0.f, 0.f};
  const float* srow = s + (size_t)row * DIM + lk * 8;
  const float* xrow = x + (size_t)row * DIM + lk * 8;
  const short8v* bh = (const short8v*)whiF;
  const short8v* bo = (const short8v*)wloF;

  #pragma unroll
  for (int kk = 0; kk < 8; ++kk) {
    const float* ap = (kk < 4) ? (srow + kk * 32) : (xrow + (kk - 4) * 32);
    float4 a0 = *(const float4*)ap;
    float4 a1 = *(const float4*)(ap + 4);
    float scl = (kk < 4) ? invc : 1.0f;
    float av[8] = { a0.x * scl, a0.y * scl, a0.z * scl, a0.w * scl,
                    a1.x * scl, a1.y * scl, a1.z * scl, a1.w * scl };
    short8v ahi, alo;
    #pragma unroll
    for (int j = 0; j < 8; ++j) {
      unsigned hb = bf16rne(av[j]);
      float hif = __uint_as_float(hb << 16);
      ahi[j] = (short)hb;
      alo[j] = (short)bf16rne(av[j] - hif);
    }
    #pragma unroll
    for (int nt = 0; nt < 8; ++nt) {
      int fi = (kk * 8 + nt) * 64 + l;
      short8v bhi = bh[fi];
      short8v blo = bo[fi];
      acc[nt] = __builtin_amdgcn_mfma_f32_16x16x32_bf16(ahi, bhi, acc[nt], 0, 0, 0);
      acc[nt] = __builtin_amdgcn_mfma_f32_16x16x32_bf16(alo, bhi, acc[nt], 0, 0, 0);
      acc[nt] = __builtin_amdgcn_mfma_f32_16x16x32_bf16(ahi, blo, acc[nt], 0, 0, 0);
    }
  }

  float sp0 = 0.f, sp1 = 0.f, sp2 = 0.f, sp3 = 0.f;
  const int mb = rowbase + lk * 4;
  #pragma unroll
  for (int nt = 0; nt < 8; ++nt) {
    int col = nt * 16 + lrow;
    float bb = bl[col], pv = pw[col];
    float h0 = fmaxf(acc[nt][0] + bb, 0.f);
    float h1 = fmaxf(acc[nt][1] + bb, 0.f);
    float h2 = fmaxf(acc[nt][2] + bb, 0.f);
    float h3 = fmaxf(acc[nt][3] + bb, 0.f);
    s[(size_t)(mb + 0) * DIM + col] = h0;
    s[(size_t)(mb + 1) * DIM + col] = h1;
    s[(size_t)(mb + 2) * DIM + col] = h2;
    s[(size_t)(mb + 3) * DIM + col] = h3;
    sp0 += h0 * pv; sp1 += h1 * pv; sp2 += h2 * pv; sp3 += h3 * pv;
  }
  #pragma unroll
  for (int off = 1; off <= 8; off <<= 1) {
    sp0 += __shfl_xor(sp0, off);
    sp1 += __shfl_xor(sp1, off);
    sp2 += __shfl_xor(sp2, off);
    sp3 += __shfl_xor(sp3, off);
  }
  if (lrow == 0) {
    score[mb + 0] = sp0;
    score[mb + 1] = sp1;
    score[mb + 2] = sp2;
    score[mb + 3] = sp3;
  }
}

// ------- fused: bitonic top-k + relabel edges + build next-stage CSR ------
__global__ __launch_bounds__(1024) void k_topk_fused(
    const float* __restrict__ score, const float* __restrict__ inv_norm_p,
    int npg, int k, int* __restrict__ sel_pos, float* __restrict__ sel_scale,
    int build_next, int write_eout,
    const int* __restrict__ ein_src, const int* __restrict__ ein_dst,
    int* __restrict__ eout_src, int* __restrict__ eout_dst,
    int* __restrict__ off_g, int* __restrict__ elist_g, float* __restrict__ c_out)
{
  __shared__ float key[1024];
  __shared__ int   idxs[1024];
  __shared__ int   nid[1024];
  __shared__ int   cnt[1024];
  __shared__ int   cur[1024];
  __shared__ int   wsum[16];
  const int t = threadIdx.x, g = blockIdx.x;
  const int base = g * npg;
  key[t] = (t < npg) ? score[base + t] : -3.402823466e38f;
  idxs[t] = t;
  nid[t] = -1;
  cnt[t] = 0;
  __syncthreads();
  for (int size = 2; size <= 1024; size <<= 1) {
    for (int stride = size >> 1; stride > 0; stride >>= 1) {
      int p = t ^ stride;
      if (p > t) {
        float ka = key[t], kb = key[p];
        int ia = idxs[t], ib = idxs[p];
        bool a_first = (ka > kb) || (ka == kb && ia < ib);
        bool desc = ((t & size) == 0);
        if (desc ? !a_first : a_first) {
          key[t] = kb; key[p] = ka; idxs[t] = ib; idxs[p] = ia;
        }
      }
      __syncthreads();
    }
  }
  if (t < k) {
    float inv = *inv_norm_p;
    int local = idxs[t];
    nid[local] = t;
    sel_pos[g * k + t] = base + local;
    sel_scale[g * k + t] = tanhf(key[t] * inv);
  }
  if (!build_next) return;
  __syncthreads();
  const int e0 = g * EPG;
  const int newBase = g * k;
  int lns[8], lnd[8];
  #pragma unroll
  for (int i = 0; i < 8; ++i) {
    int e = e0 + t + i * 1024;
    int sv = ein_src[e];
    int ns = -1, nd = -1;
    if (sv >= 0) {
      int dv = ein_dst[e];
      ns = nid[sv - base];
      nd = nid[dv - base];
      if (ns < 0 || nd < 0) ns = -1;
    }
    lns[i] = ns; lnd[i] = nd;
    if (write_eout) {
      eout_src[e] = (ns >= 0) ? (newBase + ns) : -1;
      eout_dst[e] = (ns >= 0) ? (newBase + nd) : -1;
    }
    if (ns >= 0) atomicAdd(&cnt[nd], 1);
  }
  __syncthreads();
  const int lane = t & 63, w = t >> 6;
  int cv = cnt[t];
  int x = cv;
  #pragma unroll
  for (int off = 1; off < 64; off <<= 1) {
    int y = __shfl_up(x, off);
    if (lane >= off) x += y;
  }
  if (lane == 63) wsum[w] = x;
  __syncthreads();
  if (t < 16) {
    int v = wsum[t];
    #pragma unroll
    for (int off2 = 1; off2 < 16; off2 <<= 1) {
      int y = __shfl_up(v, off2);
      if (t >= off2) v += y;
    }
    wsum[t] = v;
  }
  __syncthreads();
  int incl = x + (w ? wsum[w - 1] : 0);
  int excl = incl - cv;
  cur[t] = excl;
  off_g[g * 1025 + t] = excl;      // t>=k all hold total, so off[k] is correct
  if (t < k) c_out[newBase + t] = (float)cv;
  __syncthreads();
  int* elp = elist_g + g * EPG;
  #pragma unroll
  for (int i = 0; i < 8; ++i) {
    if (lns[i] >= 0) {
      int pos = atomicAdd(&cur[lnd[i]], 1);
      elp[pos] = newBase + lns[i];
    }
  }
}

// ------- fused pool + readout partial (float4 rows): block=(graph,chunk) --
__global__ __launch_bounds__(256) void k_pool_part(const float* __restrict__ h,
    const int* __restrict__ sel_pos, const float* __restrict__ sel_scale, int k,
    float* __restrict__ xo, float* __restrict__ pmax, float* __restrict__ psum)
{
  __shared__ float4 smx[256], ssm[256];
  const int b  = blockIdx.x >> 4;
  const int ch = blockIdx.x & (RCHUNK - 1);
  const int rpc = (k + RCHUNK - 1) / RCHUNK;
  const int r0 = ch * rpc;
  const int r1 = min(k, r0 + rpc);
  const int d4  = threadIdx.x & 31;      // float4 index in row
  const int sub = threadIdx.x >> 5;      // 8 rows in flight
  const float NEG = -3.402823466e38f;
  float4 mx = {NEG, NEG, NEG, NEG};
  float4 sm = {0.f, 0.f, 0.f, 0.f};
  for (int r = r0 + sub; r < r1; r += 8) {
    int j = b * k + r;
    float scv = sel_scale[j];
    float4 v = ((const float4*)(h + (size_t)sel_pos[j] * DIM))[d4];
    v.x *= scv; v.y *= scv; v.z *= scv; v.w *= scv;
    ((float4*)(xo + (size_t)j * DIM))[d4] = v;
    mx.x = fmaxf(mx.x, v.x); mx.y = fmaxf(mx.y, v.y);
    mx.z = fmaxf(mx.z, v.z); mx.w = fmaxf(mx.w, v.w);
    sm.x += v.x; sm.y += v.y; sm.z += v.z; sm.w += v.w;
  }
  smx[threadIdx.x] = mx; ssm[threadIdx.x] = sm;
  __syncthreads();
  if (sub < 4) {  // reduce 8 -> 1 via tree in LDS (3 steps)
    #pragma unroll
    for (int step = 4; step >= 1; step >>= 1) {
      if (sub < step) {
        float4 m2 = smx[(sub + step) * 32 + d4];
        float4 s2 = ssm[(sub + step) * 32 + d4];
        mx = smx[sub * 32 + d4]; sm = ssm[sub * 32 + d4];
        mx.x = fmaxf(mx.x, m2.x); mx.y = fmaxf(mx.y, m2.y);
        mx.z = fmaxf(mx.z, m2.z); mx.w = fmaxf(mx.w, m2.w);
        sm.x += s2.x; sm.y += s2.y; sm.z += s2.z; sm.w += s2.w;
        smx[sub * 32 + d4] = mx; ssm[sub * 32 + d4] = sm;
      }
      __syncthreads();
    }
  }
  if (sub == 0) {
    int o = (b * RCHUNK + ch) * 32 + d4;
    ((float4*)pmax)[o] = smx[d4];
    ((float4*)psum)[o] = ssm[d4];
  }
}

// ------- readout stage B: combine partials, accumulate TRANSPOSED rdT -----
__global__ __launch_bounds__(128) void k_readout_final(const float* __restrict__ pmax,
    const float* __restrict__ psum, int k, float* __restrict__ rdT, int add)
{
  int b = blockIdx.x, d = threadIdx.x;
  float mx = -3.402823466e38f, sm = 0.f;
  #pragma unroll
  for (int c = 0; c < RCHUNK; ++c) {
    int o = (b * RCHUNK + c) * 128 + d;
    mx = fmaxf(mx, pmax[o]);
    sm += psum[o];
  }
  float mean = sm / (float)k;
  int omx = d * 64 + b;
  int omn = (128 + d) * 64 + b;
  if (add) { rdT[omx] += mx; rdT[omn] += mean; }
  else     { rdT[omx]  = mx; rdT[omn]  = mean; }
}

// ------- MLP fc1 + BN1 + relu: 16 blocks, lane=graph, wave=feature --------
__global__ __launch_bounds__(512) void k_mlp_fc1(const float* __restrict__ rdT,
    const float* __restrict__ fc1_w, const float* __restrict__ fc1_b,
    const float* __restrict__ g1, const float* __restrict__ be1,
    float* __restrict__ y1n)
{
  __shared__ float W[8 * 256];       // 8 KB
  __shared__ float R[256 * 64];      // 64 KB
  const int t = threadIdx.x, b = blockIdx.x;
  ((float4*)W)[t] = ((const float4*)(fc1_w + (size_t)b * 8 * 256))[t];
  #pragma unroll
  for (int i = 0; i < 8; ++i)
    ((float4*)R)[t + i * 512] = ((const float4*)rdT)[t + i * 512];
  __syncthreads();
  const int g = t & 63, w = t >> 6;  // 8 waves, one feature each
  const float* wrow = W + w * 256;
  float acc = 0.f;
  #pragma unroll 4
  for (int k = 0; k < 256; ++k) acc += R[k * 64 + g] * wrow[k];
  int f = b * 8 + w;
  float y = acc + fc1_b[f];
  float s = y, s2 = y * y;
  #pragma unroll
  for (int off = 32; off; off >>= 1) {
    s  += __shfl_xor(s,  off);
    s2 += __shfl_xor(s2, off);
  }
  float mu = s * 0.015625f;
  float var = s2 * 0.015625f - mu * mu;
  float inv = 1.0f / sqrtf(var + 1e-5f);
  y1n[f * 64 + g] = fmaxf((y - mu) * inv * g1[f] + be1[f], 0.f);
}

// ------- MLP rest: fc2 + BN2 + relu + lin + sigmoid (1 block) -------------
__global__ __launch_bounds__(1024) void k_mlp_rest(const float* __restrict__ y1n,
    const float* __restrict__ fc2_w, const float* __restrict__ fc2_b,
    const float* __restrict__ g2, const float* __restrict__ be2,
    const float* __restrict__ lin_w, const float* __restrict__ lin_b,
    float* __restrict__ out)
{
  __shared__ float W2[64 * 128];     // 32 KB
  __shared__ float Y[128 * 64];      // 32 KB
  __shared__ float part[16 * 64];    // 4 KB
  const int t = threadIdx.x;
  #pragma unroll
  for (int i = 0; i < 2; ++i) {
    ((float4*)W2)[t + i * 1024] = ((const float4*)fc2_w)[t + i * 1024];
    ((float4*)Y) [t + i * 1024] = ((const float4*)y1n)[t + i * 1024];
  }
  __syncthreads();
  const int g = t & 63, w = t >> 6;  // 16 waves x 4 features
  float acc2[4] = {0.f, 0.f, 0.f, 0.f};
  const float* w20 = W2 + (w * 4 + 0) * 128;
  const float* w21 = W2 + (w * 4 + 1) * 128;
  const float* w22 = W2 + (w * 4 + 2) * 128;
  const float* w23 = W2 + (w * 4 + 3) * 128;
  #pragma unroll 4
  for (int k = 0; k < 128; ++k) {
    float yv = Y[k * 64 + g];
    acc2[0] += yv * w20[k];
    acc2[1] += yv * w21[k];
    acc2[2] += yv * w22[k];
    acc2[3] += yv * w23[k];
  }
  float pp = 0.f;
  #pragma unroll
  for (int j = 0; j < 4; ++j) {
    int m = w * 4 + j;
    float y = acc2[j] + fc2_b[m];
    float s = y, s2 = y * y;
    #pragma unroll
    for (int off = 32; off; off >>= 1) {
      s  += __shfl_xor(s,  off);
      s2 += __shfl_xor(s2, off);
    }
    float mu = s * 0.015625f;
    float var = s2 * 0.015625f - mu * mu;
    float inv = 1.0f / sqrtf(var + 1e-5f);
    float yn = fmaxf((y - mu) * inv * g2[m] + be2[m], 0.f);
    pp += yn * lin_w[m];
  }
  part[w * 64 + g] = pp;
  __syncthreads();
  if (w == 0) {
    float a = lin_b[0];
    #pragma unroll
    for (int c = 0; c < 16; ++c) a += part[c * 64 + g];
    out[g] = 1.0f / (1.0f + expf(-a));
  }
}

extern "C" void kernel_launch(void* const* d_in, const int* in_sizes, int n_in,
                              void* d_out, int out_size, void* d_ws, size_t ws_size,
                              hipStream_t stream) {
  const int*   node_idx = (const int*)  d_in[0];
  const int*   edge_idx = (const int*)  d_in[1];
  const float* emb      = (const float*)d_in[2];
  const float* w1l      = (const float*)d_in[3];
  const float* b1l      = (const float*)d_in[4];
  const float* w1r      = (const float*)d_in[5];
  const float* pool_w   = (const float*)d_in[6];
  const float* w2l      = (const float*)d_in[7];
  const float* b2l      = (const float*)d_in[8];
  const float* w2r      = (const float*)d_in[9];
  const float* fc1_w    = (const float*)d_in[10];
  const float* fc1_b    = (const float*)d_in[11];
  const float* bn1_g    = (const float*)d_in[12];
  const float* bn1_b    = (const float*)d_in[13];
  const float* fc2_w    = (const float*)d_in[14];
  const float* fc2_b    = (const float*)d_in[15];
  const float* bn2_g    = (const float*)d_in[16];
  const float* bn2_b    = (const float*)d_in[17];
  const float* lin_w    = (const float*)d_in[18];
  const float* lin_b    = (const float*)d_in[19];
  float* out = (float*)d_out;

  char* p = (char*)d_ws;
  auto alloc = [&](size_t bytes) -> void* {
    void* r = (void*)p;
    p += (bytes + 255) & ~(size_t)255;
    return r;
  };
  float* x_cur     = (float*)alloc((size_t)NNODE * DIM * 4);
  float* s_buf     = (float*)alloc((size_t)NNODE * DIM * 4);
  float* c_buf     = (float*)alloc((size_t)NNODE * 4);
  float* score     = (float*)alloc((size_t)NNODE * 4);
  int*   sel_pos   = (int*)  alloc((size_t)NGRAPH * 820 * 4);
  float* sel_scale = (float*)alloc((size_t)NGRAPH * 820 * 4);
  int*   src_cur   = (int*)  alloc((size_t)NEDGE * 4);
  int*   dst_cur   = (int*)  alloc((size_t)NEDGE * 4);
  int*   off_g     = (int*)  alloc((size_t)NGRAPH * 1025 * 4);
  int*   elist_g   = (int*)  alloc((size_t)NGRAPH * EPG * 4);
  float* rdT       = (float*)alloc((size_t)256 * 64 * 4);
  short* whiF      = (short*)alloc((size_t)2 * 32768 * 2);
  short* wloF      = (short*)alloc((size_t)2 * 32768 * 2);
  float* y1n       = (float*)alloc((size_t)128 * 64 * 4);
  float* pmax      = (float*)alloc((size_t)NGRAPH * RCHUNK * 128 * 4);
  float* psum      = (float*)alloc((size_t)NGRAPH * RCHUNK * 128 * 4);
  float* inv_norm  = (float*)alloc(256);

  k_gather<<<NNODE * 32 / 256, 256, 0, stream>>>(emb, node_idx, x_cur);
  k_norm<<<1, 64, 0, stream>>>(pool_w, inv_norm);
  k_prep_wfrag<<<256, 256, 0, stream>>>(w1l, w1r, w2l, w2r, whiF, wloF);
  k_csr0<<<NGRAPH, 1024, 0, stream>>>(edge_idx, off_g, elist_g, c_buf);

  const int Ks[3] = {820, 656, 525};
  int npg = NPG0;
  for (int stage = 0; stage < 3; ++stage) {
    const short* whi_s = whiF + (stage ? 32768 : 0);
    const short* wlo_s = wloF + (stage ? 32768 : 0);
    const float* bl    = stage ? b2l : b1l;
    int n = NGRAPH * npg;
    int k = Ks[stage];

    k_gather_agg<<<16 * NGRAPH, 256, 0, stream>>>(off_g, elist_g, x_cur, s_buf, npg);
    k_gemm_mfma<<<n / 64, 256, 0, stream>>>(x_cur, s_buf, c_buf, whi_s, wlo_s,
                                            bl, pool_w, score);
    const int* ein_s = (stage == 0) ? edge_idx          : src_cur;
    const int* ein_d = (stage == 0) ? (edge_idx + NEDGE) : dst_cur;
    k_topk_fused<<<NGRAPH, 1024, 0, stream>>>(score, inv_norm, npg, k,
        sel_pos, sel_scale,
        (stage < 2) ? 1 : 0, (stage == 0) ? 1 : 0,
        ein_s, ein_d, src_cur, dst_cur,
        off_g, elist_g, c_buf);
    k_pool_part<<<NGRAPH * RCHUNK, 256, 0, stream>>>(s_buf, sel_pos, sel_scale, k,
                                                     x_cur, pmax, psum);
    k_readout_final<<<NGRAPH, 128, 0, stream>>>(pmax, psum, k, rdT, stage == 0 ? 0 : 1);
    npg = k;
  }

  k_mlp_fc1<<<16, 512, 0, stream>>>(rdT, fc1_w, fc1_b, bn1_g, bn1_b, y1n);
  k_mlp_rest<<<1, 1024, 0, stream>>>(y1n, fc2_w, fc2_b, bn2_g, bn2_b,
                                     lin_w, lin_b, out);
}

// Round 9
// 277.335 us; speedup vs baseline: 4.4981x; 1.0700x over previous
//
#include <hip/hip_runtime.h>
#include <hip/hip_bf16.h>
#include <cstdint>
#include <cstddef>

#define NGRAPH 64
#define NPG0   1024
#define NNODE  65536     // NGRAPH*NPG0
#define NEDGE  524288
#define EPG    8192      // NEDGE/NGRAPH
#define DIM    128
#define RCHUNK 16        // readout partial chunks per graph

typedef __attribute__((ext_vector_type(8))) short short8v;   // 8 bf16
typedef __attribute__((ext_vector_type(4))) float f32x4;

__device__ __forceinline__ unsigned bf16rne(float f) {
  unsigned u = __float_as_uint(f);
  return (u + 0x7FFFu + ((u >> 16) & 1u)) >> 16;
}

// ---------------- gather x = emb[node_idx] ----------------
__global__ __launch_bounds__(256) void k_gather(const float* __restrict__ emb,
    const int* __restrict__ nid, float* __restrict__ x)
{
  int tid = blockIdx.x * 256 + threadIdx.x;
  int i = tid >> 5, lane = tid & 31;
  int row = nid[i];
  ((float4*)(x + (size_t)i * DIM))[lane] =
      ((const float4*)(emb + (size_t)row * DIM))[lane];
}

// ---------------- 1/||pool_w|| ----------------
__global__ __launch_bounds__(64) void k_norm(const float* __restrict__ pw,
    float* __restrict__ inv_norm)
{
  int t = threadIdx.x;
  float a = pw[t], b = pw[t + 64];
  float v = a * a + b * b;
  for (int off = 32; off; off >>= 1) v += __shfl_xor(v, off);
  if (t == 0) *inv_norm = 1.0f / sqrtf(v);
}

// ------- pre-swizzle weights into MFMA B-fragment layout, bf16 hi/lo ------
__global__ __launch_bounds__(256) void k_prep_wfrag(
    const float* __restrict__ w1l, const float* __restrict__ w1r,
    const float* __restrict__ w2l, const float* __restrict__ w2r,
    short* __restrict__ whiF, short* __restrict__ wloF)
{
  int id = blockIdx.x * 256 + threadIdx.x;    // 0..65535 (2 sets x 32768)
  int set = id >> 15;
  int r = id & 32767;
  int j  = r & 7;
  int l  = (r >> 3) & 63;
  int nt = (r >> 9) & 7;
  int kk = r >> 12;
  int k = kk * 32 + ((l >> 4) & 3) * 8 + j;
  int n = nt * 16 + (l & 15);
  const float* wl = set ? w2l : w1l;
  const float* wr = set ? w2r : w1r;
  float w = (k < 128) ? wl[n * 128 + k] : wr[n * 128 + (k - 128)];
  unsigned hb = bf16rne(w);
  float hif = __uint_as_float(hb << 16);
  unsigned lb = bf16rne(w - hif);
  whiF[id] = (short)hb;
  wloF[id] = (short)lb;
}

// ---------------- stage-0 CSR build straight from edge_idx ----------------
__global__ __launch_bounds__(1024) void k_csr0(const int* __restrict__ ei,
    int* __restrict__ off_g, int* __restrict__ elist_g, float* __restrict__ c_out)
{
  __shared__ int cnt[1024];
  __shared__ int cur[1024];
  __shared__ int wsum[16];
  const int t = threadIdx.x, g = blockIdx.x;
  const int nodeBase = g * NPG0;
  const int e0 = g * EPG;
  cnt[t] = 0;
  __syncthreads();
  int sv8[8], dl8[8];
  #pragma unroll
  for (int i = 0; i < 8; ++i) {
    int e = e0 + t + i * 1024;
    sv8[i] = ei[e];
    dl8[i] = ei[NEDGE + e] - nodeBase;
    atomicAdd(&cnt[dl8[i]], 1);
  }
  __syncthreads();
  const int lane = t & 63, w = t >> 6;
  int cv = cnt[t];
  int x = cv;
  #pragma unroll
  for (int off = 1; off < 64; off <<= 1) {
    int y = __shfl_up(x, off);
    if (lane >= off) x += y;
  }
  if (lane == 63) wsum[w] = x;
  __syncthreads();
  if (t < 16) {
    int v = wsum[t];
    #pragma unroll
    for (int off2 = 1; off2 < 16; off2 <<= 1) {
      int y = __shfl_up(v, off2);
      if (t >= off2) v += y;
    }
    wsum[t] = v;
  }
  __syncthreads();
  int incl = x + (w ? wsum[w - 1] : 0);
  int excl = incl - cv;
  cur[t] = excl;
  int* offp = off_g + g * 1025;
  offp[t] = excl;
  if (t == 1023) offp[1024] = incl;
  c_out[nodeBase + t] = (float)cv;
  __syncthreads();
  int* elp = elist_g + g * EPG;
  #pragma unroll
  for (int i = 0; i < 8; ++i) {
    int pos = atomicAdd(&cur[dl8[i]], 1);
    elp[pos] = sv8[i];
  }
}

// ------- FUSED aggregate + MFMA SAGE layer ---------------------------------
// One block = 64 consecutive ranked nodes of one graph.
// blockIdx = slice*64 + g  (XCD affinity: graph -> blockIdx%64 -> fixed XCD)
// Phase A: gather-sum neighbor rows into LDS sA[64][128] (full 512B rows).
// Phase B: h = relu([sA*invc | x] @ W + bl), write h + fused pool score.
__global__ __launch_bounds__(256) void k_agg_gemm(
    const int* __restrict__ off_g, const int* __restrict__ elist_g,
    const float* __restrict__ x, float* __restrict__ h_out,
    const short* __restrict__ whiF, const short* __restrict__ wloF,
    const float* __restrict__ bl, const float* __restrict__ pw,
    float* __restrict__ score, int npg)
{
  __shared__ float sA[64 * 128];   // 32 KB aggregate tile
  __shared__ float cntA[64];
  const int g     = blockIdx.x & 63;
  const int slice = blockIdx.x >> 6;
  const int nodeBase = g * npg;
  const int vbase = slice * 64;
  const int t = threadIdx.x;

  // ---- phase A: gather-sum, 8 groups x 32 lanes, 8 rows each ----
  {
    const int gr = t >> 5, l32 = t & 31;
    const int* off = off_g + g * 1025;
    const int* el  = elist_g + g * EPG;
    #pragma unroll
    for (int i = 0; i < 8; ++i) {
      int vb = gr * 8 + i;
      int v = vbase + vb;
      float4 acc = {0.f, 0.f, 0.f, 0.f};
      int cn = 0;
      if (v < npg) {
        int e = off[v], end = off[v + 1];
        cn = end - e;
        for (; e + 4 <= end; e += 4) {
          int s0 = el[e], s1 = el[e + 1], s2 = el[e + 2], s3 = el[e + 3];
          float4 a0 = ((const float4*)(x + (size_t)s0 * DIM))[l32];
          float4 a1 = ((const float4*)(x + (size_t)s1 * DIM))[l32];
          float4 a2 = ((const float4*)(x + (size_t)s2 * DIM))[l32];
          float4 a3 = ((const float4*)(x + (size_t)s3 * DIM))[l32];
          acc.x += (a0.x + a1.x) + (a2.x + a3.x);
          acc.y += (a0.y + a1.y) + (a2.y + a3.y);
          acc.z += (a0.z + a1.z) + (a2.z + a3.z);
          acc.w += (a0.w + a1.w) + (a2.w + a3.w);
        }
        for (; e + 2 <= end; e += 2) {
          int s0 = el[e], s1 = el[e + 1];
          float4 a0 = ((const float4*)(x + (size_t)s0 * DIM))[l32];
          float4 a1 = ((const float4*)(x + (size_t)s1 * DIM))[l32];
          acc.x += a0.x + a1.x; acc.y += a0.y + a1.y;
          acc.z += a0.z + a1.z; acc.w += a0.w + a1.w;
        }
        if (e < end) {
          float4 a = ((const float4*)(x + (size_t)el[e] * DIM))[l32];
          acc.x += a.x; acc.y += a.y; acc.z += a.z; acc.w += a.w;
        }
      }
      ((float4*)(sA + vb * 128))[l32] = acc;
      if (l32 == 0) cntA[vb] = (float)cn;
    }
  }
  __syncthreads();

  // ---- phase B: MFMA GEMM ----
  const int wv = t >> 6, l = t & 63;
  const int lrow = l & 15, lk = l >> 4;      // lk 0..3
  const int rb = wv * 16;                    // row-in-block base for A
  const int rowb = rb + lrow;                // A row in block
  const int rowg = nodeBase + min(vbase + rowb, npg - 1);  // clamped global
  const float invc = 1.0f / fmaxf(cntA[rowb], 1.0f);
  f32x4 acc[8];
  #pragma unroll
  for (int nt = 0; nt < 8; ++nt) acc[nt] = (f32x4){0.f, 0.f, 0.f, 0.f};
  const float* srow = sA + rowb * 128 + lk * 8;            // LDS
  const float* xrow = x + (size_t)rowg * DIM + lk * 8;     // global
  const short8v* bh = (const short8v*)whiF;
  const short8v* bo = (const short8v*)wloF;

  #pragma unroll
  for (int kk = 0; kk < 8; ++kk) {
    float av[8];
    if (kk < 4) {
      float4 a0 = *(const float4*)(srow + kk * 32);
      float4 a1 = *(const float4*)(srow + kk * 32 + 4);
      av[0] = a0.x * invc; av[1] = a0.y * invc;
      av[2] = a0.z * invc; av[3] = a0.w * invc;
      av[4] = a1.x * invc; av[5] = a1.y * invc;
      av[6] = a1.z * invc; av[7] = a1.w * invc;
    } else {
      float4 a0 = *(const float4*)(xrow + (kk - 4) * 32);
      float4 a1 = *(const float4*)(xrow + (kk - 4) * 32 + 4);
      av[0] = a0.x; av[1] = a0.y; av[2] = a0.z; av[3] = a0.w;
      av[4] = a1.x; av[5] = a1.y; av[6] = a1.z; av[7] = a1.w;
    }
    short8v ahi, alo;
    #pragma unroll
    for (int j = 0; j < 8; ++j) {
      unsigned hb = bf16rne(av[j]);
      float hif = __uint_as_float(hb << 16);
      ahi[j] = (short)hb;
      alo[j] = (short)bf16rne(av[j] - hif);
    }
    #pragma unroll
    for (int nt = 0; nt < 8; ++nt) {
      int fi = (kk * 8 + nt) * 64 + l;
      short8v bhi = bh[fi];
      short8v blo = bo[fi];
      acc[nt] = __builtin_amdgcn_mfma_f32_16x16x32_bf16(ahi, bhi, acc[nt], 0, 0, 0);
      acc[nt] = __builtin_amdgcn_mfma_f32_16x16x32_bf16(alo, bhi, acc[nt], 0, 0, 0);
      acc[nt] = __builtin_amdgcn_mfma_f32_16x16x32_bf16(ahi, blo, acc[nt], 0, 0, 0);
    }
  }

  // epilogue: bias + relu + guarded store + fused pool-score partials
  float sp0 = 0.f, sp1 = 0.f, sp2 = 0.f, sp3 = 0.f;
  const int mbv = vbase + rb + lk * 4;       // in-graph row base for C
  #pragma unroll
  for (int nt = 0; nt < 8; ++nt) {
    int col = nt * 16 + lrow;
    float bb = bl[col], pv = pw[col];
    float h0 = fmaxf(acc[nt][0] + bb, 0.f);
    float h1 = fmaxf(acc[nt][1] + bb, 0.f);
    float h2 = fmaxf(acc[nt][2] + bb, 0.f);
    float h3 = fmaxf(acc[nt][3] + bb, 0.f);
    if (mbv + 0 < npg) h_out[(size_t)(nodeBase + mbv + 0) * DIM + col] = h0;
    if (mbv + 1 < npg) h_out[(size_t)(nodeBase + mbv + 1) * DIM + col] = h1;
    if (mbv + 2 < npg) h_out[(size_t)(nodeBase + mbv + 2) * DIM + col] = h2;
    if (mbv + 3 < npg) h_out[(size_t)(nodeBase + mbv + 3) * DIM + col] = h3;
    sp0 += h0 * pv; sp1 += h1 * pv; sp2 += h2 * pv; sp3 += h3 * pv;
  }
  #pragma unroll
  for (int off = 1; off <= 8; off <<= 1) {
    sp0 += __shfl_xor(sp0, off);
    sp1 += __shfl_xor(sp1, off);
    sp2 += __shfl_xor(sp2, off);
    sp3 += __shfl_xor(sp3, off);
  }
  if (lrow == 0) {
    if (mbv + 0 < npg) score[nodeBase + mbv + 0] = sp0;
    if (mbv + 1 < npg) score[nodeBase + mbv + 1] = sp1;
    if (mbv + 2 < npg) score[nodeBase + mbv + 2] = sp2;
    if (mbv + 3 < npg) score[nodeBase + mbv + 3] = sp3;
  }
}

// ------- fused: bitonic top-k + relabel edges + build next-stage CSR ------
__global__ __launch_bounds__(1024) void k_topk_fused(
    const float* __restrict__ score, const float* __restrict__ inv_norm_p,
    int npg, int k, int* __restrict__ sel_pos, float* __restrict__ sel_scale,
    int build_next, int write_eout,
    const int* __restrict__ ein_src, const int* __restrict__ ein_dst,
    int* __restrict__ eout_src, int* __restrict__ eout_dst,
    int* __restrict__ off_g, int* __restrict__ elist_g, float* __restrict__ c_out)
{
  __shared__ float key[1024];
  __shared__ int   idxs[1024];
  __shared__ int   nid[1024];
  __shared__ int   cnt[1024];
  __shared__ int   cur[1024];
  __shared__ int   wsum[16];
  const int t = threadIdx.x, g = blockIdx.x;
  const int base = g * npg;
  key[t] = (t < npg) ? score[base + t] : -3.402823466e38f;
  idxs[t] = t;
  nid[t] = -1;
  cnt[t] = 0;
  __syncthreads();
  for (int size = 2; size <= 1024; size <<= 1) {
    for (int stride = size >> 1; stride > 0; stride >>= 1) {
      int p = t ^ stride;
      if (p > t) {
        float ka = key[t], kb = key[p];
        int ia = idxs[t], ib = idxs[p];
        bool a_first = (ka > kb) || (ka == kb && ia < ib);
        bool desc = ((t & size) == 0);
        if (desc ? !a_first : a_first) {
          key[t] = kb; key[p] = ka; idxs[t] = ib; idxs[p] = ia;
        }
      }
      __syncthreads();
    }
  }
  if (t < k) {
    float inv = *inv_norm_p;
    int local = idxs[t];
    nid[local] = t;
    sel_pos[g * k + t] = base + local;
    sel_scale[g * k + t] = tanhf(key[t] * inv);
  }
  if (!build_next) return;
  __syncthreads();
  const int e0 = g * EPG;
  const int newBase = g * k;
  int lns[8], lnd[8];
  #pragma unroll
  for (int i = 0; i < 8; ++i) {
    int e = e0 + t + i * 1024;
    int sv = ein_src[e];
    int ns = -1, nd = -1;
    if (sv >= 0) {
      int dv = ein_dst[e];
      ns = nid[sv - base];
      nd = nid[dv - base];
      if (ns < 0 || nd < 0) ns = -1;
    }
    lns[i] = ns; lnd[i] = nd;
    if (write_eout) {
      eout_src[e] = (ns >= 0) ? (newBase + ns) : -1;
      eout_dst[e] = (ns >= 0) ? (newBase + nd) : -1;
    }
    if (ns >= 0) atomicAdd(&cnt[nd], 1);
  }
  __syncthreads();
  const int lane = t & 63, w = t >> 6;
  int cv = cnt[t];
  int x = cv;
  #pragma unroll
  for (int off = 1; off < 64; off <<= 1) {
    int y = __shfl_up(x, off);
    if (lane >= off) x += y;
  }
  if (lane == 63) wsum[w] = x;
  __syncthreads();
  if (t < 16) {
    int v = wsum[t];
    #pragma unroll
    for (int off2 = 1; off2 < 16; off2 <<= 1) {
      int y = __shfl_up(v, off2);
      if (t >= off2) v += y;
    }
    wsum[t] = v;
  }
  __syncthreads();
  int incl = x + (w ? wsum[w - 1] : 0);
  int excl = incl - cv;
  cur[t] = excl;
  off_g[g * 1025 + t] = excl;      // t>=k all hold total, so off[k] is correct
  if (t < k) c_out[newBase + t] = (float)cv;
  __syncthreads();
  int* elp = elist_g + g * EPG;
  #pragma unroll
  for (int i = 0; i < 8; ++i) {
    if (lns[i] >= 0) {
      int pos = atomicAdd(&cur[lnd[i]], 1);
      elp[pos] = newBase + lns[i];
    }
  }
}

// ------- fused pool + readout partial (float4 rows): block=(graph,chunk) --
__global__ __launch_bounds__(256) void k_pool_part(const float* __restrict__ h,
    const int* __restrict__ sel_pos, const float* __restrict__ sel_scale, int k,
    float* __restrict__ xo, float* __restrict__ pmax, float* __restrict__ psum)
{
  __shared__ float4 smx[256], ssm[256];
  const int b  = blockIdx.x >> 4;
  const int ch = blockIdx.x & (RCHUNK - 1);
  const int rpc = (k + RCHUNK - 1) / RCHUNK;
  const int r0 = ch * rpc;
  const int r1 = min(k, r0 + rpc);
  const int d4  = threadIdx.x & 31;      // float4 index in row
  const int sub = threadIdx.x >> 5;      // 8 rows in flight
  const float NEG = -3.402823466e38f;
  float4 mx = {NEG, NEG, NEG, NEG};
  float4 sm = {0.f, 0.f, 0.f, 0.f};
  for (int r = r0 + sub; r < r1; r += 8) {
    int j = b * k + r;
    float scv = sel_scale[j];
    float4 v = ((const float4*)(h + (size_t)sel_pos[j] * DIM))[d4];
    v.x *= scv; v.y *= scv; v.z *= scv; v.w *= scv;
    ((float4*)(xo + (size_t)j * DIM))[d4] = v;
    mx.x = fmaxf(mx.x, v.x); mx.y = fmaxf(mx.y, v.y);
    mx.z = fmaxf(mx.z, v.z); mx.w = fmaxf(mx.w, v.w);
    sm.x += v.x; sm.y += v.y; sm.z += v.z; sm.w += v.w;
  }
  smx[threadIdx.x] = mx; ssm[threadIdx.x] = sm;
  __syncthreads();
  if (sub < 4) {  // reduce 8 -> 1 via tree in LDS (3 steps)
    #pragma unroll
    for (int step = 4; step >= 1; step >>= 1) {
      if (sub < step) {
        float4 m2 = smx[(sub + step) * 32 + d4];
        float4 s2 = ssm[(sub + step) * 32 + d4];
        mx = smx[sub * 32 + d4]; sm = ssm[sub * 32 + d4];
        mx.x = fmaxf(mx.x, m2.x); mx.y = fmaxf(mx.y, m2.y);
        mx.z = fmaxf(mx.z, m2.z); mx.w = fmaxf(mx.w, m2.w);
        sm.x += s2.x; sm.y += s2.y; sm.z += s2.z; sm.w += s2.w;
        smx[sub * 32 + d4] = mx; ssm[sub * 32 + d4] = sm;
      }
      __syncthreads();
    }
  }
  if (sub == 0) {
    int o = (b * RCHUNK + ch) * 32 + d4;
    ((float4*)pmax)[o] = smx[d4];
    ((float4*)psum)[o] = ssm[d4];
  }
}

// ------- readout stage B: combine partials, accumulate TRANSPOSED rdT -----
__global__ __launch_bounds__(128) void k_readout_final(const float* __restrict__ pmax,
    const float* __restrict__ psum, int k, float* __restrict__ rdT, int add)
{
  int b = blockIdx.x, d = threadIdx.x;
  float mx = -3.402823466e38f, sm = 0.f;
  #pragma unroll
  for (int c = 0; c < RCHUNK; ++c) {
    int o = (b * RCHUNK + c) * 128 + d;
    mx = fmaxf(mx, pmax[o]);
    sm += psum[o];
  }
  float mean = sm / (float)k;
  int omx = d * 64 + b;
  int omn = (128 + d) * 64 + b;
  if (add) { rdT[omx] += mx; rdT[omn] += mean; }
  else     { rdT[omx]  = mx; rdT[omn]  = mean; }
}

// ------- MLP fc1 + BN1 + relu: 16 blocks, lane=graph, wave=feature --------
__global__ __launch_bounds__(512) void k_mlp_fc1(const float* __restrict__ rdT,
    const float* __restrict__ fc1_w, const float* __restrict__ fc1_b,
    const float* __restrict__ g1, const float* __restrict__ be1,
    float* __restrict__ y1n)
{
  __shared__ float W[8 * 256];       // 8 KB
  __shared__ float R[256 * 64];      // 64 KB
  const int t = threadIdx.x, b = blockIdx.x;
  ((float4*)W)[t] = ((const float4*)(fc1_w + (size_t)b * 8 * 256))[t];
  #pragma unroll
  for (int i = 0; i < 8; ++i)
    ((float4*)R)[t + i * 512] = ((const float4*)rdT)[t + i * 512];
  __syncthreads();
  const int g = t & 63, w = t >> 6;  // 8 waves, one feature each
  const float* wrow = W + w * 256;
  float acc = 0.f;
  #pragma unroll 4
  for (int k = 0; k < 256; ++k) acc += R[k * 64 + g] * wrow[k];
  int f = b * 8 + w;
  float y = acc + fc1_b[f];
  float s = y, s2 = y * y;
  #pragma unroll
  for (int off = 32; off; off >>= 1) {
    s  += __shfl_xor(s,  off);
    s2 += __shfl_xor(s2, off);
  }
  float mu = s * 0.015625f;
  float var = s2 * 0.015625f - mu * mu;
  float inv = 1.0f / sqrtf(var + 1e-5f);
  y1n[f * 64 + g] = fmaxf((y - mu) * inv * g1[f] + be1[f], 0.f);
}

// ------- MLP rest: fc2 + BN2 + relu + lin + sigmoid (1 block) -------------
__global__ __launch_bounds__(1024) void k_mlp_rest(const float* __restrict__ y1n,
    const float* __restrict__ fc2_w, const float* __restrict__ fc2_b,
    const float* __restrict__ g2, const float* __restrict__ be2,
    const float* __restrict__ lin_w, const float* __restrict__ lin_b,
    float* __restrict__ out)
{
  __shared__ float W2[64 * 128];     // 32 KB
  __shared__ float Y[128 * 64];      // 32 KB
  __shared__ float part[16 * 64];    // 4 KB
  const int t = threadIdx.x;
  #pragma unroll
  for (int i = 0; i < 2; ++i) {
    ((float4*)W2)[t + i * 1024] = ((const float4*)fc2_w)[t + i * 1024];
    ((float4*)Y) [t + i * 1024] = ((const float4*)y1n)[t + i * 1024];
  }
  __syncthreads();
  const int g = t & 63, w = t >> 6;  // 16 waves x 4 features
  float acc2[4] = {0.f, 0.f, 0.f, 0.f};
  const float* w20 = W2 + (w * 4 + 0) * 128;
  const float* w21 = W2 + (w * 4 + 1) * 128;
  const float* w22 = W2 + (w * 4 + 2) * 128;
  const float* w23 = W2 + (w * 4 + 3) * 128;
  #pragma unroll 4
  for (int k = 0; k < 128; ++k) {
    float yv = Y[k * 64 + g];
    acc2[0] += yv * w20[k];
    acc2[1] += yv * w21[k];
    acc2[2] += yv * w22[k];
    acc2[3] += yv * w23[k];
  }
  float pp = 0.f;
  #pragma unroll
  for (int j = 0; j < 4; ++j) {
    int m = w * 4 + j;
    float y = acc2[j] + fc2_b[m];
    float s = y, s2 = y * y;
    #pragma unroll
    for (int off = 32; off; off >>= 1) {
      s  += __shfl_xor(s,  off);
      s2 += __shfl_xor(s2, off);
    }
    float mu = s * 0.015625f;
    float var = s2 * 0.015625f - mu * mu;
    float inv = 1.0f / sqrtf(var + 1e-5f);
    float yn = fmaxf((y - mu) * inv * g2[m] + be2[m], 0.f);
    pp += yn * lin_w[m];
  }
  part[w * 64 + g] = pp;
  __syncthreads();
  if (w == 0) {
    float a = lin_b[0];
    #pragma unroll
    for (int c = 0; c < 16; ++c) a += part[c * 64 + g];
    out[g] = 1.0f / (1.0f + expf(-a));
  }
}

extern "C" void kernel_launch(void* const* d_in, const int* in_sizes, int n_in,
                              void* d_out, int out_size, void* d_ws, size_t ws_size,
                              hipStream_t stream) {
  const int*   node_idx = (const int*)  d_in[0];
  const int*   edge_idx = (const int*)  d_in[1];
  const float* emb      = (const float*)d_in[2];
  const float* w1l      = (const float*)d_in[3];
  const float* b1l      = (const float*)d_in[4];
  const float* w1r      = (const float*)d_in[5];
  const float* pool_w   = (const float*)d_in[6];
  const float* w2l      = (const float*)d_in[7];
  const float* b2l      = (const float*)d_in[8];
  const float* w2r      = (const float*)d_in[9];
  const float* fc1_w    = (const float*)d_in[10];
  const float* fc1_b    = (const float*)d_in[11];
  const float* bn1_g    = (const float*)d_in[12];
  const float* bn1_b    = (const float*)d_in[13];
  const float* fc2_w    = (const float*)d_in[14];
  const float* fc2_b    = (const float*)d_in[15];
  const float* bn2_g    = (const float*)d_in[16];
  const float* bn2_b    = (const float*)d_in[17];
  const float* lin_w    = (const float*)d_in[18];
  const float* lin_b    = (const float*)d_in[19];
  float* out = (float*)d_out;

  char* p = (char*)d_ws;
  auto alloc = [&](size_t bytes) -> void* {
    void* r = (void*)p;
    p += (bytes + 255) & ~(size_t)255;
    return r;
  };
  float* x_cur     = (float*)alloc((size_t)NNODE * DIM * 4);
  float* s_buf     = (float*)alloc((size_t)NNODE * DIM * 4);
  float* c_buf     = (float*)alloc((size_t)NNODE * 4);
  float* score     = (float*)alloc((size_t)NNODE * 4);
  int*   sel_pos   = (int*)  alloc((size_t)NGRAPH * 820 * 4);
  float* sel_scale = (float*)alloc((size_t)NGRAPH * 820 * 4);
  int*   src_cur   = (int*)  alloc((size_t)NEDGE * 4);
  int*   dst_cur   = (int*)  alloc((size_t)NEDGE * 4);
  int*   off_g     = (int*)  alloc((size_t)NGRAPH * 1025 * 4);
  int*   elist_g   = (int*)  alloc((size_t)NGRAPH * EPG * 4);
  float* rdT       = (float*)alloc((size_t)256 * 64 * 4);
  short* whiF      = (short*)alloc((size_t)2 * 32768 * 2);
  short* wloF      = (short*)alloc((size_t)2 * 32768 * 2);
  float* y1n       = (float*)alloc((size_t)128 * 64 * 4);
  float* pmax      = (float*)alloc((size_t)NGRAPH * RCHUNK * 128 * 4);
  float* psum      = (float*)alloc((size_t)NGRAPH * RCHUNK * 128 * 4);
  float* inv_norm  = (float*)alloc(256);

  k_gather<<<NNODE * 32 / 256, 256, 0, stream>>>(emb, node_idx, x_cur);
  k_norm<<<1, 64, 0, stream>>>(pool_w, inv_norm);
  k_prep_wfrag<<<256, 256, 0, stream>>>(w1l, w1r, w2l, w2r, whiF, wloF);
  k_csr0<<<NGRAPH, 1024, 0, stream>>>(edge_idx, off_g, elist_g, c_buf);

  const int Ks[3] = {820, 656, 525};
  int npg = NPG0;
  for (int stage = 0; stage < 3; ++stage) {
    const short* whi_s = whiF + (stage ? 32768 : 0);
    const short* wlo_s = wloF + (stage ? 32768 : 0);
    const float* bl    = stage ? b2l : b1l;
    int k = Ks[stage];
    int slices = (npg + 63) >> 6;

    k_agg_gemm<<<slices * 64, 256, 0, stream>>>(off_g, elist_g, x_cur, s_buf,
                                                whi_s, wlo_s, bl, pool_w,
                                                score, npg);
    const int* ein_s = (stage == 0) ? edge_idx          : src_cur;
    const int* ein_d = (stage == 0) ? (edge_idx + NEDGE) : dst_cur;
    k_topk_fused<<<NGRAPH, 1024, 0, stream>>>(score, inv_norm, npg, k,
        sel_pos, sel_scale,
        (stage < 2) ? 1 : 0, (stage == 0) ? 1 : 0,
        ein_s, ein_d, src_cur, dst_cur,
        off_g, elist_g, c_buf);
    k_pool_part<<<NGRAPH * RCHUNK, 256, 0, stream>>>(s_buf, sel_pos, sel_scale, k,
                                                     x_cur, pmax, psum);
    k_readout_final<<<NGRAPH, 128, 0, stream>>>(pmax, psum, k, rdT, stage == 0 ? 0 : 1);
    npg = k;
  }

  k_mlp_fc1<<<16, 512, 0, stream>>>(rdT, fc1_w, fc1_b, bn1_g, bn1_b, y1n);
  k_mlp_rest<<<1, 1024, 0, stream>>>(y1n, fc2_w, fc2_b, bn2_g, bn2_b,
                                     lin_w, lin_b, out);
}